// Round 9
// baseline (1257.955 us; speedup 1.0000x reference)
//
#include <hip/hip_runtime.h>
#include <hip/hip_bf16.h>
#include <math.h>

#define Cdim 512
#define Hn   8
#define HDim 64
#define Ld   4
#define Tn   1024
#define Bn   2
#define NTOK 2048   // B*T
#define FF   2048   // 4*C
#define Vn   32000

typedef __bf16 bf16_t;
typedef __bf16 bf16x8 __attribute__((ext_vector_type(8)));
typedef __bf16 bf16x4 __attribute__((ext_vector_type(4)));
typedef float  f32x4  __attribute__((ext_vector_type(4)));

// ---------------- fused dual embedding (enc+dec), wave per row, f32 out ----------------
__global__ __launch_bounds__(256) void embed2_k(const int* __restrict__ enc_inp,
    const int* __restrict__ dec_inp, const float* __restrict__ tok,
    const float* __restrict__ pos, float* __restrict__ x_enc, float* __restrict__ x_dec)
{
    int wid = threadIdx.x >> 6, lane = threadIdx.x & 63;
    int row = blockIdx.x * 4 + wid;
    const int* inp = (row < NTOK) ? enc_inp : dec_inp;
    float* x       = (row < NTOK) ? x_enc   : x_dec;
    int bt = row & (NTOK - 1);
    int t = bt & (Tn - 1);
    long toff = (long)inp[bt] * Cdim;
    f32x4 a = *(const f32x4*)&tok[toff + lane * 8];
    f32x4 c = *(const f32x4*)&tok[toff + lane * 8 + 4];
    a += *(const f32x4*)&pos[(long)t * Cdim + lane * 8];
    c += *(const f32x4*)&pos[(long)t * Cdim + lane * 8 + 4];
    *(f32x4*)&x[(long)bt * Cdim + lane * 8] = a;
    *(f32x4*)&x[(long)bt * Cdim + lane * 8 + 4] = c;
}

// ------- batched tiled transpose+convert: f32 [R,Cc] -> bf16 [Cc,R] over z sources/layers -------
struct Ptr3 { const float* p[3]; };
__global__ __launch_bounds__(256) void tcvt_b_k(Ptr3 srcs, bf16_t* __restrict__ dst,
    int R, int Cc, int lps, long dstStride)
{
    int z = blockIdx.z; int s = z / lps, l = z - s * lps;
    const float* in = srcs.p[s] + (long)l * R * Cc;
    bf16_t* op = dst + (long)z * dstStride;
    __shared__ float t[64][65];
    int r0 = blockIdx.y * 64, c0 = blockIdx.x * 64;
    int tx = threadIdx.x & 63, ty = threadIdx.x >> 6;
    #pragma unroll
    for (int i = 0; i < 16; i++)
        t[ty + i * 4][tx] = in[(long)(r0 + ty + i * 4) * Cc + c0 + tx];
    __syncthreads();
    #pragma unroll
    for (int i = 0; i < 16; i++) {
        int cc = ty + i * 4;
        op[(long)(c0 + cc) * R + r0 + tx] = (bf16_t)t[tx][cc];
    }
}

// ------- fused QKV weight prep: 9 (set,part) sources in one launch -------
struct QkvSrc { const float* p[9]; };
__global__ __launch_bounds__(256) void tcvt_qkv_k(QkvSrc srcs, bf16_t* __restrict__ outp)
{
    int z = blockIdx.z;
    int si = z >> 5, zb = (z >> 3) & 3, zh = z & 7;
    int set = si / 3, part = si - set * 3;
    const float* in = srcs.p[si] + (long)zb * (Hn * Cdim * HDim) + (long)zh * (Cdim * HDim);
    bf16_t* op = outp + ((long)set * Ld + zb) * (1536L * Cdim)
                      + (long)part * 512 * Cdim + (long)zh * 64 * Cdim;
    __shared__ float t[64][65];
    int r0 = blockIdx.y * 64;
    int tx = threadIdx.x & 63, ty = threadIdx.x >> 6;
    #pragma unroll
    for (int i = 0; i < 16; i++)
        t[ty + i * 4][tx] = in[(long)(r0 + ty + i * 4) * HDim + tx];
    __syncthreads();
    #pragma unroll
    for (int i = 0; i < 16; i++) {
        int cc = ty + i * 4;
        op[(long)cc * Cdim + r0 + tx] = (bf16_t)t[tx][cc];
    }
}

// ================= bf16 MFMA GEMM, double-buffered K pipeline =================
// 256 threads = 4 waves (2x2). Chunk-XOR LDS swizzle (conflict-free reads).
// ALN: A/A2 are f32; block computes per-row mean/rstd (deterministic in-block
// pre-pass), staging applies (x-mu)*rstd*gamma[k]+beta[k] -> bf16 -> ds_write
// into the same swizzled layout (reg-staged, double-buffered).
// COAL: coalesced epilogue via per-wave LDS bounce. VOUT: scatter V^T.
template<int BM, int BN, int BK, bool ALN, bool BIAS, bool RELU, bool RES, bool OBF,
         bool VOUT, int SWZM, bool XOUT, bool COAL>
__global__ __launch_bounds__(256) void mgemm_k(
    const void* __restrict__ Av, const void* __restrict__ A2v, int aSplit,
    const float* __restrict__ gamma, const float* __restrict__ beta,
    const bf16_t* __restrict__ Bt, const float* __restrict__ bias,
    const float* __restrict__ res, void* __restrict__ Cout,
    bf16_t* __restrict__ xout, bf16_t* __restrict__ vtout, int vSplit,
    int K, int lda, int ldb, int ldc)
{
    constexpr int MR = BM / 32;
    constexpr int NR = BN / 32;
    constexpr int KK = BK / 32;
    constexpr int LPR = BK / 8;
    __shared__ bf16_t As0[BM * BK];
    __shared__ bf16_t As1[BM * BK];
    __shared__ bf16_t Bs0[BN * BK];
    __shared__ bf16_t Bs1[BN * BK];
    __shared__ float cws[COAL ? 4 * 16 * 36 : 1];
    __shared__ float mS[ALN ? BM : 1];
    __shared__ float rS[ALN ? BM : 1];

    int tid = threadIdx.x;
    int wv = tid >> 6, lane = tid & 63;
    int bm, bn;
    if constexpr (SWZM > 0) {
        int lin = blockIdx.y * gridDim.x + blockIdx.x;
        int tot = gridDim.x * gridDim.y;
        int chunk = tot >> 3;
        int e = (lin & 7) * chunk + (lin >> 3);
        bm = (e % SWZM) * BM;
        bn = (e / SWZM) * BN;
    } else {
        bm = blockIdx.y * BM; bn = blockIdx.x * BN;
    }
    const void* Abv = (bn < aSplit) ? Av : A2v;
    int wr = wv >> 1, wc = wv & 1;

    f32x4 acc[MR][NR];
    #pragma unroll
    for (int i = 0; i < MR; i++)
        #pragma unroll
        for (int j = 0; j < NR; j++)
            acc[i][j] = (f32x4){0.f, 0.f, 0.f, 0.f};

    constexpr int RPW = 512 / BK;
    constexpr int RPP = 2048 / BK;
    const int sr  = lane / LPR;
    const int sc8 = ((lane % LPR) ^ (sr & (LPR - 1))) * 8;
    const int r16 = lane & 15, g4 = lane >> 4;

    const float* Af = (const float*)Abv;
    if constexpr (ALN) {
        // ---- per-row stats pre-pass (rows bm..bm+BM-1 over K cols) ----
        constexpr int TPR = 256 / BM;         // threads per row (2 or 4)
        int rowI = tid / TPR, sub = tid % TPR;
        int cpt = K / TPR;
        const float* rp = Af + (long)(bm + rowI) * lda + sub * cpt;
        float s = 0.f, s2 = 0.f;
        for (int c = 0; c < cpt; c += 4) {
            f32x4 v = *(const f32x4*)&rp[c];
            s  += v[0] + v[1] + v[2] + v[3];
            s2 += v[0]*v[0] + v[1]*v[1] + v[2]*v[2] + v[3]*v[3];
        }
        s  += __shfl_xor(s, 1, 64);  s2 += __shfl_xor(s2, 1, 64);
        if (TPR == 4) { s += __shfl_xor(s, 2, 64); s2 += __shfl_xor(s2, 2, 64); }
        if (sub == 0) {
            float invK = 1.f / (float)K;
            float mu = s * invK;
            float var = s2 * invK - mu * mu;
            mS[rowI] = mu;
            rS[rowI] = rsqrtf(var + 1e-5f);
        }
        __syncthreads();
    }

    auto stageA = [&](int k0, bf16_t (&Asb)[BM * BK]) {   // non-ALN path
        const bf16_t* Ab = (const bf16_t*)Abv;
        #pragma unroll
        for (int p = 0; p < BM * BK / 2048; p++) {
            int rb = p * RPP + wv * RPW;
            const bf16_t* g = Ab + (long)(bm + rb + sr) * lda + (k0 + sc8);
            __builtin_amdgcn_global_load_lds(
                (const __attribute__((address_space(1))) void*)g,
                (__attribute__((address_space(3))) void*)&Asb[rb * BK],
                16, 0, 0);
        }
    };
    auto stageB = [&](int k0, bf16_t (&Bsb)[BN * BK]) {
        #pragma unroll
        for (int p = 0; p < BN * BK / 2048; p++) {
            int rb = p * RPP + wv * RPW;
            const bf16_t* g = Bt + (long)(bn + rb + sr) * ldb + (k0 + sc8);
            __builtin_amdgcn_global_load_lds(
                (const __attribute__((address_space(1))) void*)g,
                (__attribute__((address_space(3))) void*)&Bsb[rb * BK],
                16, 0, 0);
        }
    };
    // ALN reg-staging: lane handles chunk cI = tid&7 (8 cols), row tid>>3 within 32-row pass
    const int aRow = tid >> 3, aCI = tid & 7;
    auto aload = [&](int k0, f32x4 (&ar)[BM / 32][2]) {
        #pragma unroll
        for (int p = 0; p < BM / 32; p++) {
            const float* g = Af + (long)(bm + p * 32 + aRow) * lda + k0 + aCI * 8;
            ar[p][0] = *(const f32x4*)g;
            ar[p][1] = *(const f32x4*)(g + 4);
        }
    };
    auto awrite = [&](bf16_t (&Asb)[BM * BK], f32x4 (&ar)[BM / 32][2], int k0) {
        f32x4 gm0 = *(const f32x4*)&gamma[k0 + aCI * 8];
        f32x4 gm1 = *(const f32x4*)&gamma[k0 + aCI * 8 + 4];
        f32x4 bt0 = *(const f32x4*)&beta[k0 + aCI * 8];
        f32x4 bt1 = *(const f32x4*)&beta[k0 + aCI * 8 + 4];
        #pragma unroll
        for (int p = 0; p < BM / 32; p++) {
            int row = p * 32 + aRow;
            float mu = mS[row], rs = rS[row];
            bf16x8 o;
            #pragma unroll
            for (int k = 0; k < 4; k++) {
                o[k]     = (bf16_t)((ar[p][0][k] - mu) * rs * gm0[k] + bt0[k]);
                o[4 + k] = (bf16_t)((ar[p][1][k] - mu) * rs * gm1[k] + bt1[k]);
            }
            *(bf16x8*)&Asb[row * BK + ((aCI ^ (row & 7)) * 8)] = o;
        }
    };
    auto compute = [&](bf16_t (&Asb)[BM * BK], bf16_t (&Bsb)[BN * BK]) {
        #pragma unroll
        for (int kk = 0; kk < KK; kk++) {
            bf16x8 bkk[NR];
            #pragma unroll
            for (int j = 0; j < NR; j++) {
                int row = wc * (BN / 2) + j * 16 + r16;
                bkk[j] = *(const bf16x8*)&Bsb[row * BK + (((kk * 4 + g4) ^ (row & (LPR - 1))) * 8)];
            }
            #pragma unroll
            for (int i = 0; i < MR; i++) {
                int row = wr * (BM / 2) + i * 16 + r16;
                bf16x8 a = *(const bf16x8*)&Asb[row * BK + (((kk * 4 + g4) ^ (row & (LPR - 1))) * 8)];
                #pragma unroll
                for (int j = 0; j < NR; j++)
                    acc[i][j] = __builtin_amdgcn_mfma_f32_16x16x32_bf16(a, bkk[j], acc[i][j], 0, 0, 0);
            }
        }
    };

    int nIt = K / BK;
    if constexpr (ALN) {
        f32x4 ar[BM / 32][2];
        aload(0, ar); stageB(0, Bs0); awrite(As0, ar, 0);
        __syncthreads();
        for (int it = 0; it < nIt; it += 2) {
            if (it + 1 < nIt) { aload((it + 1) * BK, ar); stageB((it + 1) * BK, Bs1); }
            compute(As0, Bs0);
            if (it + 1 < nIt) awrite(As1, ar, (it + 1) * BK);
            __syncthreads();
            if (it + 2 < nIt) { aload((it + 2) * BK, ar); stageB((it + 2) * BK, Bs0); }
            if (it + 1 < nIt) compute(As1, Bs1);
            if (it + 2 < nIt) awrite(As0, ar, (it + 2) * BK);
            __syncthreads();
        }
    } else {
        stageA(0, As0); stageB(0, Bs0);
        for (int it = 0; it < nIt; it += 2) {
            __syncthreads();
            if (it + 1 < nIt) { stageA((it + 1) * BK, As1); stageB((it + 1) * BK, Bs1); }
            compute(As0, Bs0);
            __syncthreads();
            if (it + 2 < nIt) { stageA((it + 2) * BK, As0); stageB((it + 2) * BK, Bs0); }
            if (it + 1 < nIt) compute(As1, Bs1);
        }
    }

    if constexpr (COAL) {
        // ---- coalesced epilogue via per-wave LDS bounce ----
        #pragma unroll
        for (int i = 0; i < MR; i++) {
            int gr0 = bm + wr * (BM / 2) + i * 16;
            #pragma unroll
            for (int hh = 0; hh < NR / 2; hh++) {
                #pragma unroll
                for (int jj = 0; jj < 2; jj++) {
                    int j = hh * 2 + jj;
                    int gc = bn + wc * (BN / 2) + j * 16 + r16;
                    float bv = BIAS ? bias[gc] : 0.f;
                    #pragma unroll
                    for (int q = 0; q < 4; q++) {
                        float v = acc[i][j][q];
                        if (BIAS) v += bv;
                        if (RELU) v = fmaxf(v, 0.f);
                        cws[(wv * 16 + g4 * 4 + q) * 36 + jj * 16 + r16] = v;
                    }
                }
                int gcb = bn + wc * (BN / 2) + hh * 32;
                if constexpr (OBF) {
                    int row = lane >> 2, c8 = (lane & 3) * 8;
                    f32x4 v0 = *(f32x4*)&cws[(wv * 16 + row) * 36 + c8];
                    f32x4 v1 = *(f32x4*)&cws[(wv * 16 + row) * 36 + c8 + 4];
                    long oidx = (long)(gr0 + row) * ldc + gcb + c8;
                    bf16x8 o;
                    #pragma unroll
                    for (int k = 0; k < 4; k++) { o[k] = (bf16_t)v0[k]; o[4 + k] = (bf16_t)v1[k]; }
                    *(bf16x8*)&((bf16_t*)Cout)[oidx] = o;
                } else {
                    #pragma unroll
                    for (int ps = 0; ps < 2; ps++) {
                        int row = (lane >> 3) + 8 * ps, c4 = (lane & 7) * 4;
                        f32x4 v = *(f32x4*)&cws[(wv * 16 + row) * 36 + c4];
                        long oidx = (long)(gr0 + row) * ldc + gcb + c4;
                        if (RES) v += *(const f32x4*)&res[oidx];
                        *(f32x4*)&((float*)Cout)[oidx] = v;
                        if (XOUT) {
                            bf16x4 o;
                            #pragma unroll
                            for (int k = 0; k < 4; k++) o[k] = (bf16_t)v[k];
                            *(bf16x4*)&xout[oidx] = o;
                        }
                    }
                }
            }
        }
    } else {
        // ---- scalar epilogue (VOUT scatter path) ----
        #pragma unroll
        for (int i = 0; i < MR; i++) {
            #pragma unroll
            for (int j = 0; j < NR; j++) {
                int gr = bm + wr * (BM / 2) + i * 16 + g4 * 4;
                int gc = bn + wc * (BN / 2) + j * 16 + r16;
                float bv = BIAS ? bias[gc] : 0.f;
                #pragma unroll
                for (int q = 0; q < 4; q++) {
                    float v = acc[i][j][q];
                    if (BIAS) v += bv;
                    if (RELU) v = fmaxf(v, 0.f);
                    if (VOUT && gc >= vSplit) {
                        int row = gr + q;
                        int b = row >> 10, t = row & (Tn - 1);
                        vtout[((long)b * 512 + (gc - vSplit)) * Tn + t] = (bf16_t)v;
                    } else {
                        long oidx = (long)(gr + q) * ldc + gc;
                        if (RES)  v += res[oidx];
                        if (OBF) ((bf16_t*)Cout)[oidx] = (bf16_t)v;
                        else     ((float*) Cout)[oidx] = v;
                        if (XOUT) xout[oidx] = (bf16_t)v;
                    }
                }
            }
        }
    }
}

// ================= fused flash attention (8 waves, KV-split, dbuf LDS, 1 barrier/iter) =========
template<bool CAUSAL, bool HASMASK>
__global__ __launch_bounds__(512, 2) void flash_k(
    const bf16_t* __restrict__ qkv, const bf16_t* __restrict__ vt,
    const int* __restrict__ mask, bf16_t* __restrict__ ao)
{
    __shared__ bf16_t Kl[2][2][64][72];
    __shared__ bf16_t Vl[2][2][64][72];
    __shared__ bf16_t Pl[8][16][72];

    int qt = blockIdx.x, bh = blockIdx.y;
    int b = bh >> 3, h = bh & 7;
    int tid = threadIdx.x, wv = tid >> 6, lane = tid & 63;
    int wg = wv >> 2, wq4 = wv & 3;
    int r16 = lane & 15, g4 = lane >> 4;
    int gtid = tid & 255;

    const bf16_t* qb = qkv + ((long)(b * Tn + qt * 64 + wq4 * 16 + r16)) * 1536 + h * 64;
    bf16x8 aq0 = *(const bf16x8*)&qb[g4 * 8];
    bf16x8 aq1 = *(const bf16x8*)&qb[32 + g4 * 8];

    f32x4 acc[4];
    #pragma unroll
    for (int j = 0; j < 4; j++) acc[j] = (f32x4){0.f, 0.f, 0.f, 0.f};
    float m_[4], l_[4];
    #pragma unroll
    for (int q = 0; q < 4; q++) { m_[q] = -1e30f; l_[q] = 0.f; }

    int lastT = CAUSAL ? qt : (Tn / 64 - 1);
    int niter = CAUSAL ? (qt / 2 + 1) : (Tn / 128);
    int krow = gtid >> 3, kcol = (gtid & 7) * 8;

    bf16x8 kr[2], vr[2];
    int mv = 0;
    {
        int t0 = wg;
        if (t0 <= lastT) {
            int s0 = t0 * 64;
            #pragma unroll
            for (int i = 0; i < 2; i++)
                kr[i] = *(const bf16x8*)&qkv[((long)(b * Tn + s0 + krow + i * 32)) * 1536 + 512 + h * 64 + kcol];
            #pragma unroll
            for (int i = 0; i < 2; i++)
                vr[i] = *(const bf16x8*)&vt[((long)(bh * 64 + krow + i * 32)) * Tn + s0 + kcol];
            if (HASMASK) mv = mask[b * Tn + s0 + lane];
        }
    }

    for (int it = 0; it < niter; it++) {
        int cur = it & 1;
        int t = 2 * it + wg;
        bool active = t <= lastT;
        if (active) {
            #pragma unroll
            for (int i = 0; i < 2; i++) *(bf16x8*)&Kl[cur][wg][krow + i * 32][kcol] = kr[i];
            #pragma unroll
            for (int i = 0; i < 2; i++) *(bf16x8*)&Vl[cur][wg][krow + i * 32][kcol] = vr[i];
        }
        int mv_use = mv;
        __syncthreads();
        int tn = t + 2;
        if (it + 1 < niter && tn <= lastT) {
            int sn = tn * 64;
            #pragma unroll
            for (int i = 0; i < 2; i++)
                kr[i] = *(const bf16x8*)&qkv[((long)(b * Tn + sn + krow + i * 32)) * 1536 + 512 + h * 64 + kcol];
            #pragma unroll
            for (int i = 0; i < 2; i++)
                vr[i] = *(const bf16x8*)&vt[((long)(bh * 64 + krow + i * 32)) * Tn + sn + kcol];
            if (HASMASK) mv = mask[b * Tn + sn + lane];
        }
        if (!active) continue;

        f32x4 scv[4];
        __builtin_amdgcn_s_setprio(1);
        #pragma unroll
        for (int j = 0; j < 4; j++) {
            scv[j] = (f32x4){0.f, 0.f, 0.f, 0.f};
            bf16x8 bk0 = *(const bf16x8*)&Kl[cur][wg][j * 16 + r16][g4 * 8];
            bf16x8 bk1 = *(const bf16x8*)&Kl[cur][wg][j * 16 + r16][32 + g4 * 8];
            scv[j] = __builtin_amdgcn_mfma_f32_16x16x32_bf16(aq0, bk0, scv[j], 0, 0, 0);
            scv[j] = __builtin_amdgcn_mfma_f32_16x16x32_bf16(aq1, bk1, scv[j], 0, 0, 0);
        }
        __builtin_amdgcn_s_setprio(0);

        bool diag = CAUSAL && (t == qt);
        #pragma unroll
        for (int j = 0; j < 4; j++) {
            int col = j * 16 + r16;
            int mm = 1;
            if (HASMASK) mm = __shfl(mv_use, col, 64);
            #pragma unroll
            for (int q = 0; q < 4; q++) {
                float v = scv[j][q] * 0.125f;
                if (diag && col > wq4 * 16 + g4 * 4 + q) v = -1e30f;
                if (HASMASK && mm == 0) v = -1e30f;
                scv[j][q] = v;
            }
        }

        float pmax[4];
        #pragma unroll
        for (int q = 0; q < 4; q++) {
            float v = fmaxf(fmaxf(scv[0][q], scv[1][q]), fmaxf(scv[2][q], scv[3][q]));
            v = fmaxf(v, __shfl_xor(v, 1, 64));
            v = fmaxf(v, __shfl_xor(v, 2, 64));
            v = fmaxf(v, __shfl_xor(v, 4, 64));
            v = fmaxf(v, __shfl_xor(v, 8, 64));
            pmax[q] = v;
        }
        bool skip = __all(pmax[0] <= m_[0] + 8.f && pmax[1] <= m_[1] + 8.f &&
                          pmax[2] <= m_[2] + 8.f && pmax[3] <= m_[3] + 8.f);
        if (!skip) {
            #pragma unroll
            for (int q = 0; q < 4; q++) {
                float mnew = fmaxf(m_[q], pmax[q]);
                float rf = __expf(m_[q] - mnew);
                l_[q] *= rf;
                #pragma unroll
                for (int j = 0; j < 4; j++) acc[j][q] *= rf;
                m_[q] = mnew;
            }
        }
        #pragma unroll
        for (int q = 0; q < 4; q++) {
            float rs = 0.f;
            #pragma unroll
            for (int j = 0; j < 4; j++) {
                float pv = __expf(scv[j][q] - m_[q]);
                scv[j][q] = pv;
                rs += pv;
            }
            rs += __shfl_xor(rs, 1, 64);
            rs += __shfl_xor(rs, 2, 64);
            rs += __shfl_xor(rs, 4, 64);
            rs += __shfl_xor(rs, 8, 64);
            l_[q] += rs;
        }

        #pragma unroll
        for (int j = 0; j < 4; j++)
            #pragma unroll
            for (int q = 0; q < 4; q++)
                Pl[wv][g4 * 4 + q][j * 16 + r16] = (bf16_t)scv[j][q];
        asm volatile("s_waitcnt lgkmcnt(0)" ::: "memory");
        __builtin_amdgcn_sched_barrier(0);

        __builtin_amdgcn_s_setprio(1);
        #pragma unroll
        for (int c = 0; c < 2; c++) {
            bf16x8 pa = *(const bf16x8*)&Pl[wv][r16][c * 32 + g4 * 8];
            #pragma unroll
            for (int j = 0; j < 4; j++) {
                bf16x8 bv = *(const bf16x8*)&Vl[cur][wg][j * 16 + r16][c * 32 + g4 * 8];
                acc[j] = __builtin_amdgcn_mfma_f32_16x16x32_bf16(pa, bv, acc[j], 0, 0, 0);
            }
        }
        __builtin_amdgcn_s_setprio(0);
    }

    float* accS = (float*)&Kl[0][0][0][0];
    float* mlS  = accS + 64 * 64;
    __syncthreads();
    if (wg == 1) {
        #pragma unroll
        for (int j = 0; j < 4; j++)
            #pragma unroll
            for (int q = 0; q < 4; q++)
                accS[(wq4 * 16 + g4 * 4 + q) * 64 + j * 16 + r16] = acc[j][q];
        if (r16 == 0)
            #pragma unroll
            for (int q = 0; q < 4; q++) {
                mlS[(wq4 * 16 + g4 * 4 + q) * 2 + 0] = m_[q];
                mlS[(wq4 * 16 + g4 * 4 + q) * 2 + 1] = l_[q];
            }
    }
    __syncthreads();
    if (wg == 0) {
        bf16_t* aob = ao + ((long)(b * Tn + qt * 64 + wq4 * 16 + g4 * 4)) * Cdim + h * 64;
        #pragma unroll
        for (int q = 0; q < 4; q++) {
            int row = wq4 * 16 + g4 * 4 + q;
            float mB = mlS[row * 2], lB = mlS[row * 2 + 1];
            float mS2 = fmaxf(m_[q], mB);
            float fA = __expf(m_[q] - mS2), fB = __expf(mB - mS2);
            float lS = l_[q] * fA + lB * fB;
            float inv = 1.f / lS;
            #pragma unroll
            for (int j = 0; j < 4; j++) {
                float o = (acc[j][q] * fA + accS[row * 64 + j * 16 + r16] * fB) * inv;
                aob[(long)q * Cdim + j * 16 + r16] = (bf16_t)o;
            }
        }
    }
}

// ================================ host orchestration ================================
// QKV projection with fused LN on A (A=f32 q-source, A2=f32 kv-source), then flash, out-proj.
static void run_attn(hipStream_t stream, const float* xq, const float* xkv,
    const float* lng, const float* lnb,
    const bf16_t* wqkv, const float* bo, const bf16_t* wo_t,
    float* xres, const int* mask, bool causal,
    bf16_t* qkv, bf16_t* vt, bf16_t* ao)
{
    dim3 blk(256);
    mgemm_k<64,128,64,true,false,false,false,true,true,0,false,false><<<dim3(12, 32, 1), blk, 0, stream>>>(
        xq, xkv, 512, lng, lnb, wqkv, nullptr, nullptr, qkv, nullptr, vt, 1024,
        Cdim, Cdim, Cdim, 1536);
    if (causal)
        flash_k<true,false><<<dim3(Tn / 64, Bn * Hn), dim3(512), 0, stream>>>(qkv, vt, nullptr, ao);
    else
        flash_k<false,true><<<dim3(Tn / 64, Bn * Hn), dim3(512), 0, stream>>>(qkv, vt, mask, ao);
    mgemm_k<64,64,64,false,true,false,true,false,false,0,false,true><<<dim3(8, 32, 1), blk, 0, stream>>>(
        ao, ao, 1 << 30, nullptr, nullptr, wo_t, bo, xres, xres, nullptr, nullptr, 1 << 30,
        Cdim, Cdim, Cdim, Cdim);
}

extern "C" void kernel_launch(void* const* d_in, const int* in_sizes, int n_in,
                              void* d_out, int out_size, void* d_ws, size_t ws_size,
                              hipStream_t stream)
{
    (void)in_sizes; (void)n_in; (void)out_size; (void)ws_size;
    const int*   enc_inp  = (const int*)d_in[0];
    const int*   dec_inp  = (const int*)d_in[1];
    const int*   enc_mask = (const int*)d_in[2];
    const float* tok_emb  = (const float*)d_in[3];
    const float* pos_emb  = (const float*)d_in[4];
    const float* e_wq  = (const float*)d_in[5];
    const float* e_wk  = (const float*)d_in[6];
    const float* e_wv  = (const float*)d_in[7];
    const float* e_wo  = (const float*)d_in[8];
    const float* e_bo  = (const float*)d_in[9];
    const float* dsa_wq = (const float*)d_in[10];
    const float* dsa_wk = (const float*)d_in[11];
    const float* dsa_wv = (const float*)d_in[12];
    const float* dsa_wo = (const float*)d_in[13];
    const float* dsa_bo = (const float*)d_in[14];
    const float* dca_wq = (const float*)d_in[15];
    const float* dca_wk = (const float*)d_in[16];
    const float* dca_wv = (const float*)d_in[17];
    const float* dca_wo = (const float*)d_in[18];
    const float* dca_bo = (const float*)d_in[19];
    const float* e_ln1_g = (const float*)d_in[20];
    const float* e_ln1_b = (const float*)d_in[21];
    const float* e_ln2_g = (const float*)d_in[22];
    const float* e_ln2_b = (const float*)d_in[23];
    const float* d_ln1_g = (const float*)d_in[24];
    const float* d_ln1_b = (const float*)d_in[25];
    const float* d_ln2_g = (const float*)d_in[26];
    const float* d_ln2_b = (const float*)d_in[27];
    const float* d_ln3_g = (const float*)d_in[28];
    const float* d_ln3_b = (const float*)d_in[29];
    const float* e_w1 = (const float*)d_in[30];
    const float* e_b1 = (const float*)d_in[31];
    const float* e_w2 = (const float*)d_in[32];
    const float* e_b2 = (const float*)d_in[33];
    const float* d_w1 = (const float*)d_in[34];
    const float* d_b1 = (const float*)d_in[35];
    const float* d_w2 = (const float*)d_in[36];
    const float* d_b2 = (const float*)d_in[37];
    const float* out_w = (const float*)d_in[38];
    const float* out_b = (const float*)d_in[39];
    float* out = (float*)d_out;

    // -------- workspace carve (bytes) --------
    char* p = (char*)d_ws;
    auto takeB = [&](size_t bytes) { char* r = p; p += (bytes + 255) & ~(size_t)255; return r; };
    float*  x_enc = (float*)takeB(1048576ull * 4);
    float*  x_dec = (float*)takeB(1048576ull * 4);
    bf16_t* qkv   = (bf16_t*)takeB(3145728ull * 2);
    bf16_t* vt    = (bf16_t*)takeB(1048576ull * 2);
    bf16_t* ao    = (bf16_t*)takeB(1048576ull * 2);
    bf16_t* xdb   = (bf16_t*)takeB(1048576ull * 2);
    bf16_t* mid   = (bf16_t*)takeB(4194304ull * 2);
    bf16_t* wqkv_t = (bf16_t*)takeB(12ull * 786432 * 2);
    bf16_t* wo_t   = (bf16_t*)takeB(12ull * 262144 * 2);
    bf16_t* w1_t   = (bf16_t*)takeB(8ull * 1048576 * 2);
    bf16_t* w2_t   = (bf16_t*)takeB(8ull * 1048576 * 2);
    bf16_t* outw_t = (bf16_t*)takeB(16384000ull * 2);

    dim3 blk(256);
    const long LQKV = 1536L * Cdim;

    // ================= weight prep (5 launches) =================
    QkvSrc qs;
    qs.p[0] = e_wq;   qs.p[1] = e_wk;   qs.p[2] = e_wv;
    qs.p[3] = dsa_wq; qs.p[4] = dsa_wk; qs.p[5] = dsa_wv;
    qs.p[6] = dca_wq; qs.p[7] = dca_wk; qs.p[8] = dca_wv;
    tcvt_qkv_k<<<dim3(1, 8, 288), blk, 0, stream>>>(qs, wqkv_t);
    Ptr3 pw;
    pw.p[0] = e_wo; pw.p[1] = dsa_wo; pw.p[2] = dca_wo;
    tcvt_b_k<<<dim3(8, 8, 12), blk, 0, stream>>>(pw, wo_t, Cdim, Cdim, 4, (long)Cdim * Cdim);
    pw.p[0] = e_w1; pw.p[1] = d_w1; pw.p[2] = nullptr;
    tcvt_b_k<<<dim3(32, 8, 8), blk, 0, stream>>>(pw, w1_t, Cdim, FF, 4, (long)Cdim * FF);
    pw.p[0] = e_w2; pw.p[1] = d_w2; pw.p[2] = nullptr;
    tcvt_b_k<<<dim3(8, 32, 8), blk, 0, stream>>>(pw, w2_t, FF, Cdim, 4, (long)FF * Cdim);
    pw.p[0] = out_w; pw.p[1] = nullptr; pw.p[2] = nullptr;
    tcvt_b_k<<<dim3(500, 8, 1), blk, 0, stream>>>(pw, outw_t, Cdim, Vn, 1, 0);

    // ================= embeddings (one launch) =================
    embed2_k<<<2 * NTOK / 4, blk, 0, stream>>>(enc_inp, dec_inp, tok_emb, pos_emb, x_enc, x_dec);

    // ================= encoder =================
    for (int l = 0; l < Ld; l++) {
        run_attn(stream, x_enc, x_enc, e_ln1_g + l * Cdim, e_ln1_b + l * Cdim,
                 wqkv_t + (long)l * LQKV, e_bo + l * Cdim, wo_t + (long)l * Cdim * Cdim,
                 x_enc, enc_mask, /*causal=*/false, qkv, vt, ao);
        mgemm_k<128,128,64,true,true,true,false,true,false,0,false,true><<<dim3(16, 16, 1), blk, 0, stream>>>(
            x_enc, x_enc, 1 << 30, e_ln2_g + l * Cdim, e_ln2_b + l * Cdim,
            w1_t + (long)l * Cdim * FF, e_b1 + l * FF, nullptr, mid,
            nullptr, nullptr, 1 << 30, Cdim, Cdim, Cdim, FF);
        mgemm_k<64,64,64,false,true,false,true,false,false,0,false,true><<<dim3(8, 32, 1), blk, 0, stream>>>(
            mid, mid, 1 << 30, nullptr, nullptr, w2_t + (long)l * FF * Cdim, e_b2 + l * Cdim,
            x_enc, x_enc, nullptr, nullptr, 1 << 30, FF, FF, FF, Cdim);
    }
    // x_enc now holds enc_out

    // ================= decoder =================
    for (int l = 0; l < Ld; l++) {
        // causal self-attention (ln1 fused into QKV)
        run_attn(stream, x_dec, x_dec, d_ln1_g + l * Cdim, d_ln1_b + l * Cdim,
                 wqkv_t + (long)(Ld + l) * LQKV, dsa_bo + l * Cdim,
                 wo_t + (long)(Ld + l) * Cdim * Cdim,
                 x_dec, nullptr, /*causal=*/true, qkv, vt, ao);
        // cross-attention: A=x_dec, A2=enc_out, shared ln2 params fused into QKV
        run_attn(stream, x_dec, x_enc, d_ln2_g + l * Cdim, d_ln2_b + l * Cdim,
                 wqkv_t + (long)(2 * Ld + l) * LQKV, dca_bo + l * Cdim,
                 wo_t + (long)(2 * Ld + l) * Cdim * Cdim,
                 x_dec, enc_mask, /*causal=*/false, qkv, vt, ao);
        // FFN (ln3 fused into FFN1)
        mgemm_k<128,128,64,true,true,true,false,true,false,0,false,true><<<dim3(16, 16, 1), blk, 0, stream>>>(
            x_dec, x_dec, 1 << 30, d_ln3_g + l * Cdim, d_ln3_b + l * Cdim,
            w1_t + (long)(Ld + l) * Cdim * FF, d_b1 + l * FF, nullptr, mid,
            nullptr, nullptr, 1 << 30, Cdim, Cdim, Cdim, FF);
        if (l < Ld - 1)
            mgemm_k<64,64,64,false,true,false,true,false,false,0,false,true><<<dim3(8, 32, 1), blk, 0, stream>>>(
                mid, mid, 1 << 30, nullptr, nullptr, w2_t + (long)(Ld + l) * FF * Cdim, d_b2 + l * Cdim,
                x_dec, x_dec, nullptr, nullptr, 1 << 30, FF, FF, FF, Cdim);
        else  // last layer: also emit bf16 copy for logits GEMM
            mgemm_k<64,64,64,false,true,false,true,false,false,0,true,true><<<dim3(8, 32, 1), blk, 0, stream>>>(
                mid, mid, 1 << 30, nullptr, nullptr, w2_t + (long)(Ld + l) * FF * Cdim, d_b2 + l * Cdim,
                x_dec, x_dec, xdb, nullptr, 1 << 30, FF, FF, FF, Cdim);
    }

    // ================= final logits (f32 out, 128x128, coalesced, XCD-swizzled) ==========
    mgemm_k<128,128,64,false,true,false,false,false,false,16,false,true><<<dim3(250, 16, 1), blk, 0, stream>>>(
        xdb, xdb, 1 << 30, nullptr, nullptr, outw_t, out_b, nullptr, out, nullptr, nullptr, 1 << 30,
        Cdim, Cdim, Cdim, Vn);
}

// Round 10
// 1044.876 us; speedup vs baseline: 1.2039x; 1.2039x over previous
//
#include <hip/hip_runtime.h>
#include <hip/hip_bf16.h>
#include <math.h>

#define Cdim 512
#define Hn   8
#define HDim 64
#define Ld   4
#define Tn   1024
#define Bn   2
#define NTOK 2048   // B*T
#define FF   2048   // 4*C
#define Vn   32000

typedef __bf16 bf16_t;
typedef __bf16 bf16x8 __attribute__((ext_vector_type(8)));
typedef __bf16 bf16x4 __attribute__((ext_vector_type(4)));
typedef float  f32x4  __attribute__((ext_vector_type(4)));

// ---------------- layernorm: one wave per row, 4 rows/block, no barriers ----------------
__device__ __forceinline__ void ln_wave(const float* __restrict__ xr,
    const float* __restrict__ g, const float* __restrict__ bb,
    bf16_t* __restrict__ yr, int lane)
{
    f32x4 a = *(const f32x4*)&xr[lane * 8];
    f32x4 c = *(const f32x4*)&xr[lane * 8 + 4];
    float s = a[0] + a[1] + a[2] + a[3] + c[0] + c[1] + c[2] + c[3];
    #pragma unroll
    for (int o = 1; o < 64; o <<= 1) s += __shfl_xor(s, o, 64);
    float mean = s * (1.f / Cdim);
    float d[8], qv = 0.f;
    #pragma unroll
    for (int k = 0; k < 4; k++) { d[k] = a[k] - mean; d[4 + k] = c[k] - mean; }
    #pragma unroll
    for (int k = 0; k < 8; k++) qv += d[k] * d[k];
    #pragma unroll
    for (int o = 1; o < 64; o <<= 1) qv += __shfl_xor(qv, o, 64);
    float inv = rsqrtf(qv * (1.f / Cdim) + 1e-5f);
    f32x4 g0 = *(const f32x4*)&g[lane * 8],  g1 = *(const f32x4*)&g[lane * 8 + 4];
    f32x4 b0 = *(const f32x4*)&bb[lane * 8], b1 = *(const f32x4*)&bb[lane * 8 + 4];
    bf16x8 o;
    #pragma unroll
    for (int k = 0; k < 4; k++) {
        o[k]     = (bf16_t)(d[k]     * inv * g0[k] + b0[k]);
        o[4 + k] = (bf16_t)(d[4 + k] * inv * g1[k] + b1[k]);
    }
    *(bf16x8*)&yr[lane * 8] = o;
}

__global__ __launch_bounds__(256) void ln_k(const float* __restrict__ x,
    const float* __restrict__ g, const float* __restrict__ bb, bf16_t* __restrict__ y)
{
    int wid = threadIdx.x >> 6, lane = threadIdx.x & 63;
    int row = blockIdx.x * 4 + wid;
    ln_wave(x + (long)row * Cdim, g, bb, y + (long)row * Cdim, lane);
}

// two-source LN (cross-attention): rows < NTOK from x1->y1, else x2->y2 (same g,b)
__global__ __launch_bounds__(256) void ln2_k(const float* __restrict__ x1,
    const float* __restrict__ x2, const float* __restrict__ g,
    const float* __restrict__ bb, bf16_t* __restrict__ y1, bf16_t* __restrict__ y2)
{
    int wid = threadIdx.x >> 6, lane = threadIdx.x & 63;
    int row = blockIdx.x * 4 + wid;
    const float* x = (row < NTOK) ? x1 : x2;
    bf16_t*      y = (row < NTOK) ? y1 : y2;
    int r = row & (NTOK - 1);
    ln_wave(x + (long)r * Cdim, g, bb, y + (long)r * Cdim, lane);
}

// ---------------- fused embedding + first-layer LN (wave per row) ----------------
__global__ __launch_bounds__(256) void embed_ln_k(const int* __restrict__ inp,
    const float* __restrict__ tok, const float* __restrict__ pos,
    const float* __restrict__ g, const float* __restrict__ bb,
    float* __restrict__ x, bf16_t* __restrict__ y)
{
    int wid = threadIdx.x >> 6, lane = threadIdx.x & 63;
    int bt = blockIdx.x * 4 + wid;
    int t = bt & (Tn - 1);
    long toff = (long)inp[bt] * Cdim;
    f32x4 a = *(const f32x4*)&tok[toff + lane * 8];
    f32x4 c = *(const f32x4*)&tok[toff + lane * 8 + 4];
    f32x4 pa = *(const f32x4*)&pos[(long)t * Cdim + lane * 8];
    f32x4 pc = *(const f32x4*)&pos[(long)t * Cdim + lane * 8 + 4];
    a += pa; c += pc;
    float* xr = x + (long)bt * Cdim;
    *(f32x4*)&xr[lane * 8] = a;
    *(f32x4*)&xr[lane * 8 + 4] = c;
    float s = a[0] + a[1] + a[2] + a[3] + c[0] + c[1] + c[2] + c[3];
    #pragma unroll
    for (int o = 1; o < 64; o <<= 1) s += __shfl_xor(s, o, 64);
    float mean = s * (1.f / Cdim);
    float d[8], qv = 0.f;
    #pragma unroll
    for (int k = 0; k < 4; k++) { d[k] = a[k] - mean; d[4 + k] = c[k] - mean; }
    #pragma unroll
    for (int k = 0; k < 8; k++) qv += d[k] * d[k];
    #pragma unroll
    for (int o = 1; o < 64; o <<= 1) qv += __shfl_xor(qv, o, 64);
    float inv = rsqrtf(qv * (1.f / Cdim) + 1e-5f);
    f32x4 g0 = *(const f32x4*)&g[lane * 8],  g1 = *(const f32x4*)&g[lane * 8 + 4];
    f32x4 b0 = *(const f32x4*)&bb[lane * 8], b1 = *(const f32x4*)&bb[lane * 8 + 4];
    bf16x8 o;
    #pragma unroll
    for (int k = 0; k < 4; k++) {
        o[k]     = (bf16_t)(d[k]     * inv * g0[k] + b0[k]);
        o[4 + k] = (bf16_t)(d[4 + k] * inv * g1[k] + b1[k]);
    }
    *(bf16x8*)&y[(long)bt * Cdim + lane * 8] = o;
}

// ------- batched tiled transpose+convert: f32 [R,Cc] -> bf16 [Cc,R] over z sources/layers -------
struct Ptr3 { const float* p[3]; };
__global__ __launch_bounds__(256) void tcvt_b_k(Ptr3 srcs, bf16_t* __restrict__ dst,
    int R, int Cc, int lps, long dstStride)
{
    int z = blockIdx.z; int s = z / lps, l = z - s * lps;
    const float* in = srcs.p[s] + (long)l * R * Cc;
    bf16_t* op = dst + (long)z * dstStride;
    __shared__ float t[64][65];
    int r0 = blockIdx.y * 64, c0 = blockIdx.x * 64;
    int tx = threadIdx.x & 63, ty = threadIdx.x >> 6;
    #pragma unroll
    for (int i = 0; i < 16; i++)
        t[ty + i * 4][tx] = in[(long)(r0 + ty + i * 4) * Cc + c0 + tx];
    __syncthreads();
    #pragma unroll
    for (int i = 0; i < 16; i++) {
        int cc = ty + i * 4;
        op[(long)(c0 + cc) * R + r0 + tx] = (bf16_t)t[tx][cc];
    }
}

// ------- fused QKV weight prep: 9 (set,part) sources in one launch -------
struct QkvSrc { const float* p[9]; };
__global__ __launch_bounds__(256) void tcvt_qkv_k(QkvSrc srcs, bf16_t* __restrict__ outp)
{
    int z = blockIdx.z;
    int si = z >> 5, zb = (z >> 3) & 3, zh = z & 7;
    int set = si / 3, part = si - set * 3;
    const float* in = srcs.p[si] + (long)zb * (Hn * Cdim * HDim) + (long)zh * (Cdim * HDim);
    bf16_t* op = outp + ((long)set * Ld + zb) * (1536L * Cdim)
                      + (long)part * 512 * Cdim + (long)zh * 64 * Cdim;
    __shared__ float t[64][65];
    int r0 = blockIdx.y * 64;
    int tx = threadIdx.x & 63, ty = threadIdx.x >> 6;
    #pragma unroll
    for (int i = 0; i < 16; i++)
        t[ty + i * 4][tx] = in[(long)(r0 + ty + i * 4) * HDim + tx];
    __syncthreads();
    #pragma unroll
    for (int i = 0; i < 16; i++) {
        int cc = ty + i * 4;
        op[(long)cc * Cdim + r0 + tx] = (bf16_t)t[tx][cc];
    }
}

// ================= bf16 MFMA GEMM, double-buffered K pipeline =================
// 256 threads = 4 waves (2x2). Chunk-XOR LDS swizzle (conflict-free reads).
// Separate As0/As1/Bs0/Bs1 arrays so in-flight global_load_lds of the next
// tile provably doesn't alias current ds_reads -> stage latency hides.
template<int BM, int BN, int BK, bool BIAS, bool RELU, bool RES, bool OBF,
         bool VOUT, int SWZM, bool XOUT, bool COAL>
__global__ __launch_bounds__(256) void mgemm_k(
    const bf16_t* __restrict__ A, const bf16_t* __restrict__ A2, int aSplit,
    const bf16_t* __restrict__ Bt, const float* __restrict__ bias,
    const float* __restrict__ res, void* __restrict__ Cout,
    bf16_t* __restrict__ xout, bf16_t* __restrict__ vtout, int vSplit,
    int K, int lda, int ldb, int ldc)
{
    constexpr int MR = BM / 32;
    constexpr int NR = BN / 32;
    constexpr int KK = BK / 32;
    constexpr int LPR = BK / 8;
    __shared__ bf16_t As0[BM * BK];
    __shared__ bf16_t As1[BM * BK];
    __shared__ bf16_t Bs0[BN * BK];
    __shared__ bf16_t Bs1[BN * BK];
    __shared__ float cws[COAL ? 4 * 16 * 36 : 1];

    int tid = threadIdx.x;
    int wv = tid >> 6, lane = tid & 63;
    int bm, bn;
    if constexpr (SWZM > 0) {
        int lin = blockIdx.y * gridDim.x + blockIdx.x;
        int tot = gridDim.x * gridDim.y;
        int chunk = tot >> 3;
        int e = (lin & 7) * chunk + (lin >> 3);
        bm = (e % SWZM) * BM;
        bn = (e / SWZM) * BN;
    } else {
        bm = blockIdx.y * BM; bn = blockIdx.x * BN;
    }
    const bf16_t* Ab = (bn < aSplit) ? A : A2;
    int wr = wv >> 1, wc = wv & 1;

    f32x4 acc[MR][NR];
    #pragma unroll
    for (int i = 0; i < MR; i++)
        #pragma unroll
        for (int j = 0; j < NR; j++)
            acc[i][j] = (f32x4){0.f, 0.f, 0.f, 0.f};

    constexpr int RPW = 512 / BK;
    constexpr int RPP = 2048 / BK;
    const int sr  = lane / LPR;
    const int sc8 = ((lane % LPR) ^ (sr & (LPR - 1))) * 8;
    const int r16 = lane & 15, g4 = lane >> 4;

    auto stage = [&](int k0, bf16_t (&Asb)[BM * BK], bf16_t (&Bsb)[BN * BK]) {
        #pragma unroll
        for (int p = 0; p < BM * BK / 2048; p++) {
            int rb = p * RPP + wv * RPW;
            const bf16_t* g = Ab + (long)(bm + rb + sr) * lda + (k0 + sc8);
            __builtin_amdgcn_global_load_lds(
                (const __attribute__((address_space(1))) void*)g,
                (__attribute__((address_space(3))) void*)&Asb[rb * BK],
                16, 0, 0);
        }
        #pragma unroll
        for (int p = 0; p < BN * BK / 2048; p++) {
            int rb = p * RPP + wv * RPW;
            const bf16_t* g = Bt + (long)(bn + rb + sr) * ldb + (k0 + sc8);
            __builtin_amdgcn_global_load_lds(
                (const __attribute__((address_space(1))) void*)g,
                (__attribute__((address_space(3))) void*)&Bsb[rb * BK],
                16, 0, 0);
        }
    };
    auto compute = [&](bf16_t (&Asb)[BM * BK], bf16_t (&Bsb)[BN * BK]) {
        #pragma unroll
        for (int kk = 0; kk < KK; kk++) {
            bf16x8 bkk[NR];
            #pragma unroll
            for (int j = 0; j < NR; j++) {
                int row = wc * (BN / 2) + j * 16 + r16;
                bkk[j] = *(const bf16x8*)&Bsb[row * BK + (((kk * 4 + g4) ^ (row & (LPR - 1))) * 8)];
            }
            #pragma unroll
            for (int i = 0; i < MR; i++) {
                int row = wr * (BM / 2) + i * 16 + r16;
                bf16x8 a = *(const bf16x8*)&Asb[row * BK + (((kk * 4 + g4) ^ (row & (LPR - 1))) * 8)];
                #pragma unroll
                for (int j = 0; j < NR; j++)
                    acc[i][j] = __builtin_amdgcn_mfma_f32_16x16x32_bf16(a, bkk[j], acc[i][j], 0, 0, 0);
            }
        }
    };

    int nIt = K / BK;
    stage(0, As0, Bs0);
    for (int it = 0; it < nIt; it += 2) {
        __syncthreads();                               // As0/Bs0 staged; prior reads done
        if (it + 1 < nIt) stage((it + 1) * BK, As1, Bs1);
        compute(As0, Bs0);
        __syncthreads();                               // As1/Bs1 staged; As0 reads done
        if (it + 2 < nIt) stage((it + 2) * BK, As0, Bs0);
        if (it + 1 < nIt) compute(As1, Bs1);
    }

    if constexpr (COAL) {
        // ---- coalesced epilogue via per-wave LDS bounce ----
        #pragma unroll
        for (int i = 0; i < MR; i++) {
            int gr0 = bm + wr * (BM / 2) + i * 16;
            #pragma unroll
            for (int hh = 0; hh < NR / 2; hh++) {
                #pragma unroll
                for (int jj = 0; jj < 2; jj++) {
                    int j = hh * 2 + jj;
                    int gc = bn + wc * (BN / 2) + j * 16 + r16;
                    float bv = BIAS ? bias[gc] : 0.f;
                    #pragma unroll
                    for (int q = 0; q < 4; q++) {
                        float v = acc[i][j][q];
                        if (BIAS) v += bv;
                        if (RELU) v = fmaxf(v, 0.f);
                        cws[(wv * 16 + g4 * 4 + q) * 36 + jj * 16 + r16] = v;
                    }
                }
                int gcb = bn + wc * (BN / 2) + hh * 32;
                if constexpr (OBF) {
                    int row = lane >> 2, c8 = (lane & 3) * 8;
                    f32x4 v0 = *(f32x4*)&cws[(wv * 16 + row) * 36 + c8];
                    f32x4 v1 = *(f32x4*)&cws[(wv * 16 + row) * 36 + c8 + 4];
                    long oidx = (long)(gr0 + row) * ldc + gcb + c8;
                    bf16x8 o;
                    #pragma unroll
                    for (int k = 0; k < 4; k++) { o[k] = (bf16_t)v0[k]; o[4 + k] = (bf16_t)v1[k]; }
                    *(bf16x8*)&((bf16_t*)Cout)[oidx] = o;
                } else {
                    #pragma unroll
                    for (int ps = 0; ps < 2; ps++) {
                        int row = (lane >> 3) + 8 * ps, c4 = (lane & 7) * 4;
                        f32x4 v = *(f32x4*)&cws[(wv * 16 + row) * 36 + c4];
                        long oidx = (long)(gr0 + row) * ldc + gcb + c4;
                        if (RES) v += *(const f32x4*)&res[oidx];
                        *(f32x4*)&((float*)Cout)[oidx] = v;
                        if (XOUT) {
                            bf16x4 o;
                            #pragma unroll
                            for (int k = 0; k < 4; k++) o[k] = (bf16_t)v[k];
                            *(bf16x4*)&xout[oidx] = o;
                        }
                    }
                }
            }
        }
    } else {
        // ---- scalar epilogue (VOUT scatter path) ----
        #pragma unroll
        for (int i = 0; i < MR; i++) {
            #pragma unroll
            for (int j = 0; j < NR; j++) {
                int gr = bm + wr * (BM / 2) + i * 16 + g4 * 4;
                int gc = bn + wc * (BN / 2) + j * 16 + r16;
                float bv = BIAS ? bias[gc] : 0.f;
                #pragma unroll
                for (int q = 0; q < 4; q++) {
                    float v = acc[i][j][q];
                    if (BIAS) v += bv;
                    if (RELU) v = fmaxf(v, 0.f);
                    if (VOUT && gc >= vSplit) {
                        int row = gr + q;
                        int b = row >> 10, t = row & (Tn - 1);
                        vtout[((long)b * 512 + (gc - vSplit)) * Tn + t] = (bf16_t)v;
                    } else {
                        long oidx = (long)(gr + q) * ldc + gc;
                        if (RES)  v += res[oidx];
                        if (OBF) ((bf16_t*)Cout)[oidx] = (bf16_t)v;
                        else     ((float*) Cout)[oidx] = v;
                        if (XOUT) xout[oidx] = (bf16_t)v;
                    }
                }
            }
        }
    }
}

// ================= fused flash attention (8 waves, KV-split, dbuf LDS, 1 barrier/iter) =========
template<bool CAUSAL, bool HASMASK>
__global__ __launch_bounds__(512, 2) void flash_k(
    const bf16_t* __restrict__ qkv, const bf16_t* __restrict__ vt,
    const int* __restrict__ mask, bf16_t* __restrict__ ao)
{
    __shared__ bf16_t Kl[2][2][64][72];
    __shared__ bf16_t Vl[2][2][64][72];
    __shared__ bf16_t Pl[8][16][72];

    int qt = blockIdx.x, bh = blockIdx.y;
    int b = bh >> 3, h = bh & 7;
    int tid = threadIdx.x, wv = tid >> 6, lane = tid & 63;
    int wg = wv >> 2, wq4 = wv & 3;
    int r16 = lane & 15, g4 = lane >> 4;
    int gtid = tid & 255;

    const bf16_t* qb = qkv + ((long)(b * Tn + qt * 64 + wq4 * 16 + r16)) * 1536 + h * 64;
    bf16x8 aq0 = *(const bf16x8*)&qb[g4 * 8];
    bf16x8 aq1 = *(const bf16x8*)&qb[32 + g4 * 8];

    f32x4 acc[4];
    #pragma unroll
    for (int j = 0; j < 4; j++) acc[j] = (f32x4){0.f, 0.f, 0.f, 0.f};
    float m_[4], l_[4];
    #pragma unroll
    for (int q = 0; q < 4; q++) { m_[q] = -1e30f; l_[q] = 0.f; }

    int lastT = CAUSAL ? qt : (Tn / 64 - 1);
    int niter = CAUSAL ? (qt / 2 + 1) : (Tn / 128);
    int krow = gtid >> 3, kcol = (gtid & 7) * 8;

    bf16x8 kr[2], vr[2];
    int mv = 0;
    {
        int t0 = wg;
        if (t0 <= lastT) {
            int s0 = t0 * 64;
            #pragma unroll
            for (int i = 0; i < 2; i++)
                kr[i] = *(const bf16x8*)&qkv[((long)(b * Tn + s0 + krow + i * 32)) * 1536 + 512 + h * 64 + kcol];
            #pragma unroll
            for (int i = 0; i < 2; i++)
                vr[i] = *(const bf16x8*)&vt[((long)(bh * 64 + krow + i * 32)) * Tn + s0 + kcol];
            if (HASMASK) mv = mask[b * Tn + s0 + lane];
        }
    }

    for (int it = 0; it < niter; it++) {
        int cur = it & 1;
        int t = 2 * it + wg;
        bool active = t <= lastT;
        if (active) {
            #pragma unroll
            for (int i = 0; i < 2; i++) *(bf16x8*)&Kl[cur][wg][krow + i * 32][kcol] = kr[i];
            #pragma unroll
            for (int i = 0; i < 2; i++) *(bf16x8*)&Vl[cur][wg][krow + i * 32][kcol] = vr[i];
        }
        int mv_use = mv;
        __syncthreads();
        int tn = t + 2;
        if (it + 1 < niter && tn <= lastT) {
            int sn = tn * 64;
            #pragma unroll
            for (int i = 0; i < 2; i++)
                kr[i] = *(const bf16x8*)&qkv[((long)(b * Tn + sn + krow + i * 32)) * 1536 + 512 + h * 64 + kcol];
            #pragma unroll
            for (int i = 0; i < 2; i++)
                vr[i] = *(const bf16x8*)&vt[((long)(bh * 64 + krow + i * 32)) * Tn + sn + kcol];
            if (HASMASK) mv = mask[b * Tn + sn + lane];
        }
        if (!active) continue;

        f32x4 scv[4];
        __builtin_amdgcn_s_setprio(1);
        #pragma unroll
        for (int j = 0; j < 4; j++) {
            scv[j] = (f32x4){0.f, 0.f, 0.f, 0.f};
            bf16x8 bk0 = *(const bf16x8*)&Kl[cur][wg][j * 16 + r16][g4 * 8];
            bf16x8 bk1 = *(const bf16x8*)&Kl[cur][wg][j * 16 + r16][32 + g4 * 8];
            scv[j] = __builtin_amdgcn_mfma_f32_16x16x32_bf16(aq0, bk0, scv[j], 0, 0, 0);
            scv[j] = __builtin_amdgcn_mfma_f32_16x16x32_bf16(aq1, bk1, scv[j], 0, 0, 0);
        }
        __builtin_amdgcn_s_setprio(0);

        bool diag = CAUSAL && (t == qt);
        #pragma unroll
        for (int j = 0; j < 4; j++) {
            int col = j * 16 + r16;
            int mm = 1;
            if (HASMASK) mm = __shfl(mv_use, col, 64);
            #pragma unroll
            for (int q = 0; q < 4; q++) {
                float v = scv[j][q] * 0.125f;
                if (diag && col > wq4 * 16 + g4 * 4 + q) v = -1e30f;
                if (HASMASK && mm == 0) v = -1e30f;
                scv[j][q] = v;
            }
        }

        float pmax[4];
        #pragma unroll
        for (int q = 0; q < 4; q++) {
            float v = fmaxf(fmaxf(scv[0][q], scv[1][q]), fmaxf(scv[2][q], scv[3][q]));
            v = fmaxf(v, __shfl_xor(v, 1, 64));
            v = fmaxf(v, __shfl_xor(v, 2, 64));
            v = fmaxf(v, __shfl_xor(v, 4, 64));
            v = fmaxf(v, __shfl_xor(v, 8, 64));
            pmax[q] = v;
        }
        bool skip = __all(pmax[0] <= m_[0] + 8.f && pmax[1] <= m_[1] + 8.f &&
                          pmax[2] <= m_[2] + 8.f && pmax[3] <= m_[3] + 8.f);
        if (!skip) {
            #pragma unroll
            for (int q = 0; q < 4; q++) {
                float mnew = fmaxf(m_[q], pmax[q]);
                float rf = __expf(m_[q] - mnew);
                l_[q] *= rf;
                #pragma unroll
                for (int j = 0; j < 4; j++) acc[j][q] *= rf;
                m_[q] = mnew;
            }
        }
        #pragma unroll
        for (int q = 0; q < 4; q++) {
            float rs = 0.f;
            #pragma unroll
            for (int j = 0; j < 4; j++) {
                float pv = __expf(scv[j][q] - m_[q]);
                scv[j][q] = pv;
                rs += pv;
            }
            rs += __shfl_xor(rs, 1, 64);
            rs += __shfl_xor(rs, 2, 64);
            rs += __shfl_xor(rs, 4, 64);
            rs += __shfl_xor(rs, 8, 64);
            l_[q] += rs;
        }

        #pragma unroll
        for (int j = 0; j < 4; j++)
            #pragma unroll
            for (int q = 0; q < 4; q++)
                Pl[wv][g4 * 4 + q][j * 16 + r16] = (bf16_t)scv[j][q];
        asm volatile("s_waitcnt lgkmcnt(0)" ::: "memory");
        __builtin_amdgcn_sched_barrier(0);

        __builtin_amdgcn_s_setprio(1);
        #pragma unroll
        for (int c = 0; c < 2; c++) {
            bf16x8 pa = *(const bf16x8*)&Pl[wv][r16][c * 32 + g4 * 8];
            #pragma unroll
            for (int j = 0; j < 4; j++) {
                bf16x8 bv = *(const bf16x8*)&Vl[cur][wg][j * 16 + r16][c * 32 + g4 * 8];
                acc[j] = __builtin_amdgcn_mfma_f32_16x16x32_bf16(pa, bv, acc[j], 0, 0, 0);
            }
        }
        __builtin_amdgcn_s_setprio(0);
    }

    float* accS = (float*)&Kl[0][0][0][0];
    float* mlS  = accS + 64 * 64;
    __syncthreads();
    if (wg == 1) {
        #pragma unroll
        for (int j = 0; j < 4; j++)
            #pragma unroll
            for (int q = 0; q < 4; q++)
                accS[(wq4 * 16 + g4 * 4 + q) * 64 + j * 16 + r16] = acc[j][q];
        if (r16 == 0)
            #pragma unroll
            for (int q = 0; q < 4; q++) {
                mlS[(wq4 * 16 + g4 * 4 + q) * 2 + 0] = m_[q];
                mlS[(wq4 * 16 + g4 * 4 + q) * 2 + 1] = l_[q];
            }
    }
    __syncthreads();
    if (wg == 0) {
        bf16_t* aob = ao + ((long)(b * Tn + qt * 64 + wq4 * 16 + g4 * 4)) * Cdim + h * 64;
        #pragma unroll
        for (int q = 0; q < 4; q++) {
            int row = wq4 * 16 + g4 * 4 + q;
            float mB = mlS[row * 2], lB = mlS[row * 2 + 1];
            float mS = fmaxf(m_[q], mB);
            float fA = __expf(m_[q] - mS), fB = __expf(mB - mS);
            float lS = l_[q] * fA + lB * fB;
            float inv = 1.f / lS;
            #pragma unroll
            for (int j = 0; j < 4; j++) {
                float o = (acc[j][q] * fA + accS[row * 64 + j * 16 + r16] * fB) * inv;
                aob[(long)q * Cdim + j * 16 + r16] = (bf16_t)o;
            }
        }
    }
}

// ================================ host orchestration ================================
static void run_attn(hipStream_t stream, const bf16_t* hq, const bf16_t* hkv,
    const bf16_t* wqkv, const float* bo, const bf16_t* wo_t,
    float* xres, const int* mask, bool causal,
    bf16_t* qkv, bf16_t* vt, bf16_t* ao)
{
    dim3 blk(256);
    // fused qkv projection: N=1536 (cols<512 read hq, else hkv); v-part -> vt
    mgemm_k<64,128,64,false,false,false,true,true,0,false,false><<<dim3(12, 32, 1), blk, 0, stream>>>(
        hq, hkv, 512, wqkv, nullptr, nullptr, qkv, nullptr, vt, 1024,
        Cdim, Cdim, Cdim, 1536);
    if (causal)
        flash_k<true,false><<<dim3(Tn / 64, Bn * Hn), dim3(512), 0, stream>>>(qkv, vt, nullptr, ao);
    else
        flash_k<false,true><<<dim3(Tn / 64, Bn * Hn), dim3(512), 0, stream>>>(qkv, vt, mask, ao);
    // out projection + bias + residual (f32, in place on xres) — coalesced epilogue
    mgemm_k<64,64,64,true,false,true,false,false,0,false,true><<<dim3(8, 32, 1), blk, 0, stream>>>(
        ao, ao, 1 << 30, wo_t, bo, xres, xres, nullptr, nullptr, 1 << 30,
        Cdim, Cdim, Cdim, Cdim);
}

extern "C" void kernel_launch(void* const* d_in, const int* in_sizes, int n_in,
                              void* d_out, int out_size, void* d_ws, size_t ws_size,
                              hipStream_t stream)
{
    (void)in_sizes; (void)n_in; (void)out_size; (void)ws_size;
    const int*   enc_inp  = (const int*)d_in[0];
    const int*   dec_inp  = (const int*)d_in[1];
    const int*   enc_mask = (const int*)d_in[2];
    const float* tok_emb  = (const float*)d_in[3];
    const float* pos_emb  = (const float*)d_in[4];
    const float* e_wq  = (const float*)d_in[5];
    const float* e_wk  = (const float*)d_in[6];
    const float* e_wv  = (const float*)d_in[7];
    const float* e_wo  = (const float*)d_in[8];
    const float* e_bo  = (const float*)d_in[9];
    const float* dsa_wq = (const float*)d_in[10];
    const float* dsa_wk = (const float*)d_in[11];
    const float* dsa_wv = (const float*)d_in[12];
    const float* dsa_wo = (const float*)d_in[13];
    const float* dsa_bo = (const float*)d_in[14];
    const float* dca_wq = (const float*)d_in[15];
    const float* dca_wk = (const float*)d_in[16];
    const float* dca_wv = (const float*)d_in[17];
    const float* dca_wo = (const float*)d_in[18];
    const float* dca_bo = (const float*)d_in[19];
    const float* e_ln1_g = (const float*)d_in[20];
    const float* e_ln1_b = (const float*)d_in[21];
    const float* e_ln2_g = (const float*)d_in[22];
    const float* e_ln2_b = (const float*)d_in[23];
    const float* d_ln1_g = (const float*)d_in[24];
    const float* d_ln1_b = (const float*)d_in[25];
    const float* d_ln2_g = (const float*)d_in[26];
    const float* d_ln2_b = (const float*)d_in[27];
    const float* d_ln3_g = (const float*)d_in[28];
    const float* d_ln3_b = (const float*)d_in[29];
    const float* e_w1 = (const float*)d_in[30];
    const float* e_b1 = (const float*)d_in[31];
    const float* e_w2 = (const float*)d_in[32];
    const float* e_b2 = (const float*)d_in[33];
    const float* d_w1 = (const float*)d_in[34];
    const float* d_b1 = (const float*)d_in[35];
    const float* d_w2 = (const float*)d_in[36];
    const float* d_b2 = (const float*)d_in[37];
    const float* out_w = (const float*)d_in[38];
    const float* out_b = (const float*)d_in[39];
    float* out = (float*)d_out;

    // -------- workspace carve (bytes) --------
    char* p = (char*)d_ws;
    auto takeB = [&](size_t bytes) { char* r = p; p += (bytes + 255) & ~(size_t)255; return r; };
    float*  x_enc = (float*)takeB(1048576ull * 4);
    float*  x_dec = (float*)takeB(1048576ull * 4);
    bf16_t* h     = (bf16_t*)takeB(1048576ull * 2);
    bf16_t* hk    = (bf16_t*)takeB(1048576ull * 2);
    bf16_t* qkv   = (bf16_t*)takeB(3145728ull * 2);
    bf16_t* vt    = (bf16_t*)takeB(1048576ull * 2);
    bf16_t* ao    = (bf16_t*)takeB(1048576ull * 2);
    bf16_t* xdb   = (bf16_t*)takeB(1048576ull * 2);
    bf16_t* mid   = (bf16_t*)takeB(4194304ull * 2);
    bf16_t* wqkv_t = (bf16_t*)takeB(12ull * 786432 * 2);
    bf16_t* wo_t   = (bf16_t*)takeB(12ull * 262144 * 2);
    bf16_t* w1_t   = (bf16_t*)takeB(8ull * 1048576 * 2);
    bf16_t* w2_t   = (bf16_t*)takeB(8ull * 1048576 * 2);
    bf16_t* outw_t = (bf16_t*)takeB(16384000ull * 2);

    dim3 blk(256);
    const long LQKV = 1536L * Cdim;

    // ================= weight prep (5 launches) =================
    QkvSrc qs;
    qs.p[0] = e_wq;   qs.p[1] = e_wk;   qs.p[2] = e_wv;
    qs.p[3] = dsa_wq; qs.p[4] = dsa_wk; qs.p[5] = dsa_wv;
    qs.p[6] = dca_wq; qs.p[7] = dca_wk; qs.p[8] = dca_wv;
    tcvt_qkv_k<<<dim3(1, 8, 288), blk, 0, stream>>>(qs, wqkv_t);
    Ptr3 pw;
    pw.p[0] = e_wo; pw.p[1] = dsa_wo; pw.p[2] = dca_wo;
    tcvt_b_k<<<dim3(8, 8, 12), blk, 0, stream>>>(pw, wo_t, Cdim, Cdim, 4, (long)Cdim * Cdim);
    pw.p[0] = e_w1; pw.p[1] = d_w1; pw.p[2] = nullptr;
    tcvt_b_k<<<dim3(32, 8, 8), blk, 0, stream>>>(pw, w1_t, Cdim, FF, 4, (long)Cdim * FF);
    pw.p[0] = e_w2; pw.p[1] = d_w2; pw.p[2] = nullptr;
    tcvt_b_k<<<dim3(8, 32, 8), blk, 0, stream>>>(pw, w2_t, FF, Cdim, 4, (long)FF * Cdim);
    pw.p[0] = out_w; pw.p[1] = nullptr; pw.p[2] = nullptr;
    tcvt_b_k<<<dim3(500, 8, 1), blk, 0, stream>>>(pw, outw_t, Cdim, Vn, 1, 0);

    // ================= encoder =================
    embed_ln_k<<<NTOK / 4, blk, 0, stream>>>(enc_inp, tok_emb, pos_emb, e_ln1_g, e_ln1_b, x_enc, h);
    for (int l = 0; l < Ld; l++) {
        if (l) ln_k<<<NTOK / 4, blk, 0, stream>>>(x_enc, e_ln1_g + l * Cdim, e_ln1_b + l * Cdim, h);
        run_attn(stream, h, h,
                 wqkv_t + (long)l * LQKV, e_bo + l * Cdim, wo_t + (long)l * Cdim * Cdim,
                 x_enc, enc_mask, /*causal=*/false, qkv, vt, ao);
        ln_k<<<NTOK / 4, blk, 0, stream>>>(x_enc, e_ln2_g + l * Cdim, e_ln2_b + l * Cdim, h);
        mgemm_k<128,128,64,true,true,false,true,false,0,false,true><<<dim3(16, 16, 1), blk, 0, stream>>>(
            h, h, 1 << 30, w1_t + (long)l * Cdim * FF, e_b1 + l * FF, nullptr, mid,
            nullptr, nullptr, 1 << 30, Cdim, Cdim, Cdim, FF);
        mgemm_k<64,64,64,true,false,true,false,false,0,false,true><<<dim3(8, 32, 1), blk, 0, stream>>>(
            mid, mid, 1 << 30, w2_t + (long)l * FF * Cdim, e_b2 + l * Cdim, x_enc, x_enc,
            nullptr, nullptr, 1 << 30, FF, FF, FF, Cdim);
    }
    // x_enc now holds enc_out

    // ================= decoder =================
    embed_ln_k<<<NTOK / 4, blk, 0, stream>>>(dec_inp, tok_emb, pos_emb, d_ln1_g, d_ln1_b, x_dec, h);
    for (int l = 0; l < Ld; l++) {
        // causal self-attention
        if (l) ln_k<<<NTOK / 4, blk, 0, stream>>>(x_dec, d_ln1_g + l * Cdim, d_ln1_b + l * Cdim, h);
        run_attn(stream, h, h,
                 wqkv_t + (long)(Ld + l) * LQKV, dsa_bo + l * Cdim,
                 wo_t + (long)(Ld + l) * Cdim * Cdim,
                 x_dec, nullptr, /*causal=*/true, qkv, vt, ao);
        // cross-attention (same LN applied to x and enc_out) — one fused launch
        ln2_k<<<2 * NTOK / 4, blk, 0, stream>>>(x_dec, x_enc,
            d_ln2_g + l * Cdim, d_ln2_b + l * Cdim, h, hk);
        run_attn(stream, h, hk,
                 wqkv_t + (long)(2 * Ld + l) * LQKV, dca_bo + l * Cdim,
                 wo_t + (long)(2 * Ld + l) * Cdim * Cdim,
                 x_dec, enc_mask, /*causal=*/false, qkv, vt, ao);
        // FFN
        ln_k<<<NTOK / 4, blk, 0, stream>>>(x_dec, d_ln3_g + l * Cdim, d_ln3_b + l * Cdim, h);
        mgemm_k<128,128,64,true,true,false,true,false,0,false,true><<<dim3(16, 16, 1), blk, 0, stream>>>(
            h, h, 1 << 30, w1_t + (long)(Ld + l) * Cdim * FF, d_b1 + l * FF, nullptr, mid,
            nullptr, nullptr, 1 << 30, Cdim, Cdim, Cdim, FF);
        if (l < Ld - 1)
            mgemm_k<64,64,64,true,false,true,false,false,0,false,true><<<dim3(8, 32, 1), blk, 0, stream>>>(
                mid, mid, 1 << 30, w2_t + (long)(Ld + l) * FF * Cdim, d_b2 + l * Cdim, x_dec, x_dec,
                nullptr, nullptr, 1 << 30, FF, FF, FF, Cdim);
        else  // last layer: also emit bf16 copy for logits GEMM
            mgemm_k<64,64,64,true,false,true,false,false,0,true,true><<<dim3(8, 32, 1), blk, 0, stream>>>(
                mid, mid, 1 << 30, w2_t + (long)(Ld + l) * FF * Cdim, d_b2 + l * Cdim, x_dec, x_dec,
                xdb, nullptr, 1 << 30, FF, FF, FF, Cdim);
    }

    // ================= final logits (f32 out, 64x128 tile, coalesced, XCD-swizzled) ==========
    mgemm_k<64,128,64,true,false,false,false,false,32,false,true><<<dim3(250, 32, 1), blk, 0, stream>>>(
        xdb, xdb, 1 << 30, outw_t, out_b, nullptr, out, nullptr, nullptr, 1 << 30,
        Cdim, Cdim, Cdim, Vn);
}

// Round 11
// 1029.857 us; speedup vs baseline: 1.2215x; 1.0146x over previous
//
#include <hip/hip_runtime.h>
#include <hip/hip_bf16.h>
#include <math.h>

#define Cdim 512
#define Hn   8
#define HDim 64
#define Ld   4
#define Tn   1024
#define Bn   2
#define NTOK 2048   // B*T
#define FF   2048   // 4*C
#define Vn   32000

typedef __bf16 bf16_t;
typedef __bf16 bf16x8 __attribute__((ext_vector_type(8)));
typedef __bf16 bf16x4 __attribute__((ext_vector_type(4)));
typedef float  f32x4  __attribute__((ext_vector_type(4)));

// ---------------- layernorm: one wave per row, 4 rows/block, no barriers ----------------
__device__ __forceinline__ void ln_wave(const float* __restrict__ xr,
    const float* __restrict__ g, const float* __restrict__ bb,
    bf16_t* __restrict__ yr, int lane)
{
    f32x4 a = *(const f32x4*)&xr[lane * 8];
    f32x4 c = *(const f32x4*)&xr[lane * 8 + 4];
    float s = a[0] + a[1] + a[2] + a[3] + c[0] + c[1] + c[2] + c[3];
    #pragma unroll
    for (int o = 1; o < 64; o <<= 1) s += __shfl_xor(s, o, 64);
    float mean = s * (1.f / Cdim);
    float d[8], qv = 0.f;
    #pragma unroll
    for (int k = 0; k < 4; k++) { d[k] = a[k] - mean; d[4 + k] = c[k] - mean; }
    #pragma unroll
    for (int k = 0; k < 8; k++) qv += d[k] * d[k];
    #pragma unroll
    for (int o = 1; o < 64; o <<= 1) qv += __shfl_xor(qv, o, 64);
    float inv = rsqrtf(qv * (1.f / Cdim) + 1e-5f);
    f32x4 g0 = *(const f32x4*)&g[lane * 8],  g1 = *(const f32x4*)&g[lane * 8 + 4];
    f32x4 b0 = *(const f32x4*)&bb[lane * 8], b1 = *(const f32x4*)&bb[lane * 8 + 4];
    bf16x8 o;
    #pragma unroll
    for (int k = 0; k < 4; k++) {
        o[k]     = (bf16_t)(d[k]     * inv * g0[k] + b0[k]);
        o[4 + k] = (bf16_t)(d[4 + k] * inv * g1[k] + b1[k]);
    }
    *(bf16x8*)&yr[lane * 8] = o;
}

__global__ __launch_bounds__(256) void ln_k(const float* __restrict__ x,
    const float* __restrict__ g, const float* __restrict__ bb, bf16_t* __restrict__ y)
{
    int wid = threadIdx.x >> 6, lane = threadIdx.x & 63;
    int row = blockIdx.x * 4 + wid;
    ln_wave(x + (long)row * Cdim, g, bb, y + (long)row * Cdim, lane);
}

// two-source LN (cross-attention): rows < NTOK from x1->y1, else x2->y2 (same g,b)
__global__ __launch_bounds__(256) void ln2_k(const float* __restrict__ x1,
    const float* __restrict__ x2, const float* __restrict__ g,
    const float* __restrict__ bb, bf16_t* __restrict__ y1, bf16_t* __restrict__ y2)
{
    int wid = threadIdx.x >> 6, lane = threadIdx.x & 63;
    int row = blockIdx.x * 4 + wid;
    const float* x = (row < NTOK) ? x1 : x2;
    bf16_t*      y = (row < NTOK) ? y1 : y2;
    int r = row & (NTOK - 1);
    ln_wave(x + (long)r * Cdim, g, bb, y + (long)r * Cdim, lane);
}

// ---------------- fused embedding + first-layer LN (wave per row) ----------------
__global__ __launch_bounds__(256) void embed_ln_k(const int* __restrict__ inp,
    const float* __restrict__ tok, const float* __restrict__ pos,
    const float* __restrict__ g, const float* __restrict__ bb,
    float* __restrict__ x, bf16_t* __restrict__ y)
{
    int wid = threadIdx.x >> 6, lane = threadIdx.x & 63;
    int bt = blockIdx.x * 4 + wid;
    int t = bt & (Tn - 1);
    long toff = (long)inp[bt] * Cdim;
    f32x4 a = *(const f32x4*)&tok[toff + lane * 8];
    f32x4 c = *(const f32x4*)&tok[toff + lane * 8 + 4];
    f32x4 pa = *(const f32x4*)&pos[(long)t * Cdim + lane * 8];
    f32x4 pc = *(const f32x4*)&pos[(long)t * Cdim + lane * 8 + 4];
    a += pa; c += pc;
    float* xr = x + (long)bt * Cdim;
    *(f32x4*)&xr[lane * 8] = a;
    *(f32x4*)&xr[lane * 8 + 4] = c;
    float s = a[0] + a[1] + a[2] + a[3] + c[0] + c[1] + c[2] + c[3];
    #pragma unroll
    for (int o = 1; o < 64; o <<= 1) s += __shfl_xor(s, o, 64);
    float mean = s * (1.f / Cdim);
    float d[8], qv = 0.f;
    #pragma unroll
    for (int k = 0; k < 4; k++) { d[k] = a[k] - mean; d[4 + k] = c[k] - mean; }
    #pragma unroll
    for (int k = 0; k < 8; k++) qv += d[k] * d[k];
    #pragma unroll
    for (int o = 1; o < 64; o <<= 1) qv += __shfl_xor(qv, o, 64);
    float inv = rsqrtf(qv * (1.f / Cdim) + 1e-5f);
    f32x4 g0 = *(const f32x4*)&g[lane * 8],  g1 = *(const f32x4*)&g[lane * 8 + 4];
    f32x4 b0 = *(const f32x4*)&bb[lane * 8], b1 = *(const f32x4*)&bb[lane * 8 + 4];
    bf16x8 o;
    #pragma unroll
    for (int k = 0; k < 4; k++) {
        o[k]     = (bf16_t)(d[k]     * inv * g0[k] + b0[k]);
        o[4 + k] = (bf16_t)(d[4 + k] * inv * g1[k] + b1[k]);
    }
    *(bf16x8*)&y[(long)bt * Cdim + lane * 8] = o;
}

// ------- batched tiled transpose+convert: f32 [R,Cc] -> bf16 [Cc,R] over z sources/layers -------
struct Ptr3 { const float* p[3]; };
__global__ __launch_bounds__(256) void tcvt_b_k(Ptr3 srcs, bf16_t* __restrict__ dst,
    int R, int Cc, int lps, long dstStride)
{
    int z = blockIdx.z; int s = z / lps, l = z - s * lps;
    const float* in = srcs.p[s] + (long)l * R * Cc;
    bf16_t* op = dst + (long)z * dstStride;
    __shared__ float t[64][65];
    int r0 = blockIdx.y * 64, c0 = blockIdx.x * 64;
    int tx = threadIdx.x & 63, ty = threadIdx.x >> 6;
    #pragma unroll
    for (int i = 0; i < 16; i++)
        t[ty + i * 4][tx] = in[(long)(r0 + ty + i * 4) * Cc + c0 + tx];
    __syncthreads();
    #pragma unroll
    for (int i = 0; i < 16; i++) {
        int cc = ty + i * 4;
        op[(long)(c0 + cc) * R + r0 + tx] = (bf16_t)t[tx][cc];
    }
}

// ------- fused QKV weight prep: 9 (set,part) sources in one launch -------
struct QkvSrc { const float* p[9]; };
__global__ __launch_bounds__(256) void tcvt_qkv_k(QkvSrc srcs, bf16_t* __restrict__ outp)
{
    int z = blockIdx.z;
    int si = z >> 5, zb = (z >> 3) & 3, zh = z & 7;
    int set = si / 3, part = si - set * 3;
    const float* in = srcs.p[si] + (long)zb * (Hn * Cdim * HDim) + (long)zh * (Cdim * HDim);
    bf16_t* op = outp + ((long)set * Ld + zb) * (1536L * Cdim)
                      + (long)part * 512 * Cdim + (long)zh * 64 * Cdim;
    __shared__ float t[64][65];
    int r0 = blockIdx.y * 64;
    int tx = threadIdx.x & 63, ty = threadIdx.x >> 6;
    #pragma unroll
    for (int i = 0; i < 16; i++)
        t[ty + i * 4][tx] = in[(long)(r0 + ty + i * 4) * HDim + tx];
    __syncthreads();
    #pragma unroll
    for (int i = 0; i < 16; i++) {
        int cc = ty + i * 4;
        op[(long)cc * Cdim + r0 + tx] = (bf16_t)t[tx][cc];
    }
}

// ================= bf16 MFMA GEMM, double-buffered K pipeline =================
// 256 threads = 4 waves (2x2). Chunk-XOR LDS swizzle (conflict-free reads).
// Separate As0/As1/Bs0/Bs1 arrays so in-flight global_load_lds of the next
// tile provably doesn't alias current ds_reads -> stage latency hides.
template<int BM, int BN, int BK, bool BIAS, bool RELU, bool RES, bool OBF,
         bool VOUT, int SWZM, bool XOUT, bool COAL>
__global__ __launch_bounds__(256) void mgemm_k(
    const bf16_t* __restrict__ A, const bf16_t* __restrict__ A2, int aSplit,
    const bf16_t* __restrict__ Bt, const float* __restrict__ bias,
    const float* __restrict__ res, void* __restrict__ Cout,
    bf16_t* __restrict__ xout, bf16_t* __restrict__ vtout, int vSplit,
    int K, int lda, int ldb, int ldc)
{
    constexpr int MR = BM / 32;
    constexpr int NR = BN / 32;
    constexpr int KK = BK / 32;
    constexpr int LPR = BK / 8;
    __shared__ bf16_t As0[BM * BK];
    __shared__ bf16_t As1[BM * BK];
    __shared__ bf16_t Bs0[BN * BK];
    __shared__ bf16_t Bs1[BN * BK];
    __shared__ float cws[COAL ? 4 * 16 * 36 : 1];

    int tid = threadIdx.x;
    int wv = tid >> 6, lane = tid & 63;
    int bm, bn;
    if constexpr (SWZM > 0) {
        int lin = blockIdx.y * gridDim.x + blockIdx.x;
        int tot = gridDim.x * gridDim.y;
        int chunk = tot >> 3;
        int e = (lin & 7) * chunk + (lin >> 3);
        bm = (e % SWZM) * BM;
        bn = (e / SWZM) * BN;
    } else {
        bm = blockIdx.y * BM; bn = blockIdx.x * BN;
    }
    const bf16_t* Ab = (bn < aSplit) ? A : A2;
    int wr = wv >> 1, wc = wv & 1;

    f32x4 acc[MR][NR];
    #pragma unroll
    for (int i = 0; i < MR; i++)
        #pragma unroll
        for (int j = 0; j < NR; j++)
            acc[i][j] = (f32x4){0.f, 0.f, 0.f, 0.f};

    constexpr int RPW = 512 / BK;
    constexpr int RPP = 2048 / BK;
    const int sr  = lane / LPR;
    const int sc8 = ((lane % LPR) ^ (sr & (LPR - 1))) * 8;
    const int r16 = lane & 15, g4 = lane >> 4;

    auto stage = [&](int k0, bf16_t (&Asb)[BM * BK], bf16_t (&Bsb)[BN * BK]) {
        #pragma unroll
        for (int p = 0; p < BM * BK / 2048; p++) {
            int rb = p * RPP + wv * RPW;
            const bf16_t* g = Ab + (long)(bm + rb + sr) * lda + (k0 + sc8);
            __builtin_amdgcn_global_load_lds(
                (const __attribute__((address_space(1))) void*)g,
                (__attribute__((address_space(3))) void*)&Asb[rb * BK],
                16, 0, 0);
        }
        #pragma unroll
        for (int p = 0; p < BN * BK / 2048; p++) {
            int rb = p * RPP + wv * RPW;
            const bf16_t* g = Bt + (long)(bn + rb + sr) * ldb + (k0 + sc8);
            __builtin_amdgcn_global_load_lds(
                (const __attribute__((address_space(1))) void*)g,
                (__attribute__((address_space(3))) void*)&Bsb[rb * BK],
                16, 0, 0);
        }
    };
    auto compute = [&](bf16_t (&Asb)[BM * BK], bf16_t (&Bsb)[BN * BK]) {
        #pragma unroll
        for (int kk = 0; kk < KK; kk++) {
            bf16x8 bkk[NR];
            #pragma unroll
            for (int j = 0; j < NR; j++) {
                int row = wc * (BN / 2) + j * 16 + r16;
                bkk[j] = *(const bf16x8*)&Bsb[row * BK + (((kk * 4 + g4) ^ (row & (LPR - 1))) * 8)];
            }
            #pragma unroll
            for (int i = 0; i < MR; i++) {
                int row = wr * (BM / 2) + i * 16 + r16;
                bf16x8 a = *(const bf16x8*)&Asb[row * BK + (((kk * 4 + g4) ^ (row & (LPR - 1))) * 8)];
                #pragma unroll
                for (int j = 0; j < NR; j++)
                    acc[i][j] = __builtin_amdgcn_mfma_f32_16x16x32_bf16(a, bkk[j], acc[i][j], 0, 0, 0);
            }
        }
    };

    int nIt = K / BK;
    stage(0, As0, Bs0);
    for (int it = 0; it < nIt; it += 2) {
        __syncthreads();                               // As0/Bs0 staged; prior reads done
        if (it + 1 < nIt) stage((it + 1) * BK, As1, Bs1);
        compute(As0, Bs0);
        __syncthreads();                               // As1/Bs1 staged; As0 reads done
        if (it + 2 < nIt) stage((it + 2) * BK, As0, Bs0);
        if (it + 1 < nIt) compute(As1, Bs1);
    }

    if constexpr (COAL) {
        // ---- coalesced epilogue via per-wave LDS bounce ----
        #pragma unroll
        for (int i = 0; i < MR; i++) {
            int gr0 = bm + wr * (BM / 2) + i * 16;
            #pragma unroll
            for (int hh = 0; hh < NR / 2; hh++) {
                #pragma unroll
                for (int jj = 0; jj < 2; jj++) {
                    int j = hh * 2 + jj;
                    int gc = bn + wc * (BN / 2) + j * 16 + r16;
                    float bv = BIAS ? bias[gc] : 0.f;
                    #pragma unroll
                    for (int q = 0; q < 4; q++) {
                        float v = acc[i][j][q];
                        if (BIAS) v += bv;
                        if (RELU) v = fmaxf(v, 0.f);
                        cws[(wv * 16 + g4 * 4 + q) * 36 + jj * 16 + r16] = v;
                    }
                }
                int gcb = bn + wc * (BN / 2) + hh * 32;
                if constexpr (OBF) {
                    int row = lane >> 2, c8 = (lane & 3) * 8;
                    f32x4 v0 = *(f32x4*)&cws[(wv * 16 + row) * 36 + c8];
                    f32x4 v1 = *(f32x4*)&cws[(wv * 16 + row) * 36 + c8 + 4];
                    long oidx = (long)(gr0 + row) * ldc + gcb + c8;
                    bf16x8 o;
                    #pragma unroll
                    for (int k = 0; k < 4; k++) { o[k] = (bf16_t)v0[k]; o[4 + k] = (bf16_t)v1[k]; }
                    *(bf16x8*)&((bf16_t*)Cout)[oidx] = o;
                } else {
                    #pragma unroll
                    for (int ps = 0; ps < 2; ps++) {
                        int row = (lane >> 3) + 8 * ps, c4 = (lane & 7) * 4;
                        f32x4 v = *(f32x4*)&cws[(wv * 16 + row) * 36 + c4];
                        long oidx = (long)(gr0 + row) * ldc + gcb + c4;
                        if (RES) v += *(const f32x4*)&res[oidx];
                        *(f32x4*)&((float*)Cout)[oidx] = v;
                        if (XOUT) {
                            bf16x4 o;
                            #pragma unroll
                            for (int k = 0; k < 4; k++) o[k] = (bf16_t)v[k];
                            *(bf16x4*)&xout[oidx] = o;
                        }
                    }
                }
            }
        }
    } else {
        // ---- scalar epilogue (VOUT scatter path) ----
        #pragma unroll
        for (int i = 0; i < MR; i++) {
            #pragma unroll
            for (int j = 0; j < NR; j++) {
                int gr = bm + wr * (BM / 2) + i * 16 + g4 * 4;
                int gc = bn + wc * (BN / 2) + j * 16 + r16;
                float bv = BIAS ? bias[gc] : 0.f;
                #pragma unroll
                for (int q = 0; q < 4; q++) {
                    float v = acc[i][j][q];
                    if (BIAS) v += bv;
                    if (RELU) v = fmaxf(v, 0.f);
                    if (VOUT && gc >= vSplit) {
                        int row = gr + q;
                        int b = row >> 10, t = row & (Tn - 1);
                        vtout[((long)b * 512 + (gc - vSplit)) * Tn + t] = (bf16_t)v;
                    } else {
                        long oidx = (long)(gr + q) * ldc + gc;
                        if (RES)  v += res[oidx];
                        if (OBF) ((bf16_t*)Cout)[oidx] = (bf16_t)v;
                        else     ((float*) Cout)[oidx] = v;
                        if (XOUT) xout[oidx] = (bf16_t)v;
                    }
                }
            }
        }
    }
}

// ======= fused flash attention: QBLK=32, 256 thr (2 q-subtiles x 2 KV groups) =======
// grid (T/32, B*H) = 512 blocks; LDS 46 KB -> 2 blocks/CU (independent barrier
// domains overlap softmax with MFMA; causal imbalance averages). Single-buffer
// K/V LDS with register prefetch (T14); waves wv: wg=wv>>1 KV-parity group,
// wq=wv&1 q-subtile. Staging half (tid>>7) == its KV group.
template<bool CAUSAL, bool HASMASK>
__global__ __launch_bounds__(256, 3) void flash_k(
    const bf16_t* __restrict__ qkv, const bf16_t* __restrict__ vt,
    const int* __restrict__ mask, bf16_t* __restrict__ ao)
{
    __shared__ bf16_t Kl[2][64][72];
    __shared__ bf16_t Vl[2][64][72];
    __shared__ bf16_t Pl[4][16][72];

    int qx = blockIdx.x, bh = blockIdx.y;
    int b = bh >> 3, h = bh & 7;
    int tid = threadIdx.x, wv = tid >> 6, lane = tid & 63;
    int wg = wv >> 1, wq = wv & 1;
    int r16 = lane & 15, g4 = lane >> 4;

    const bf16_t* qb = qkv + ((long)(b * Tn + qx * 32 + wq * 16 + r16)) * 1536 + h * 64;
    bf16x8 aq0 = *(const bf16x8*)&qb[g4 * 8];
    bf16x8 aq1 = *(const bf16x8*)&qb[32 + g4 * 8];

    f32x4 acc[4];
    #pragma unroll
    for (int j = 0; j < 4; j++) acc[j] = (f32x4){0.f, 0.f, 0.f, 0.f};
    float m_[4], l_[4];
    #pragma unroll
    for (int q = 0; q < 4; q++) { m_[q] = -1e30f; l_[q] = 0.f; }

    int lastT = CAUSAL ? (qx >> 1) : (Tn / 64 - 1);
    int niter = CAUSAL ? ((qx >> 2) + 1) : (Tn / 128);
    int st = tid & 127;
    int srow = st >> 3, scol = (st & 7) * 8;      // 16 rows/pass, 4 passes

    // prologue prefetch (group's tile t0 = wg)
    bf16x8 kr[4], vr[4];
    int mv = 0;
    {
        int t0 = wg;
        if (t0 <= lastT) {
            int s0 = t0 * 64;
            #pragma unroll
            for (int i = 0; i < 4; i++)
                kr[i] = *(const bf16x8*)&qkv[((long)(b * Tn + s0 + srow + i * 16)) * 1536 + 512 + h * 64 + scol];
            #pragma unroll
            for (int i = 0; i < 4; i++)
                vr[i] = *(const bf16x8*)&vt[((long)(bh * 64 + srow + i * 16)) * Tn + s0 + scol];
            if (HASMASK) mv = mask[b * Tn + s0 + lane];
        }
    }

    for (int it = 0; it < niter; it++) {
        int t = 2 * it + wg;
        bool active = t <= lastT;
        if (active) {
            #pragma unroll
            for (int i = 0; i < 4; i++) *(bf16x8*)&Kl[wg][srow + i * 16][scol] = kr[i];
            #pragma unroll
            for (int i = 0; i < 4; i++) *(bf16x8*)&Vl[wg][srow + i * 16][scol] = vr[i];
        }
        int mv_use = mv;
        __syncthreads();                      // tiles visible
        // ---- prefetch next tile into regs (in flight across compute) ----
        int tn = t + 2;
        if (it + 1 < niter && tn <= lastT) {
            int sn = tn * 64;
            #pragma unroll
            for (int i = 0; i < 4; i++)
                kr[i] = *(const bf16x8*)&qkv[((long)(b * Tn + sn + srow + i * 16)) * 1536 + 512 + h * 64 + scol];
            #pragma unroll
            for (int i = 0; i < 4; i++)
                vr[i] = *(const bf16x8*)&vt[((long)(bh * 64 + srow + i * 16)) * Tn + sn + scol];
            if (HASMASK) mv = mask[b * Tn + sn + lane];
        }
        if (active) {
            // ---- QK^T: 8 MFMA ----
            f32x4 scv[4];
            __builtin_amdgcn_s_setprio(1);
            #pragma unroll
            for (int j = 0; j < 4; j++) {
                scv[j] = (f32x4){0.f, 0.f, 0.f, 0.f};
                bf16x8 bk0 = *(const bf16x8*)&Kl[wg][j * 16 + r16][g4 * 8];
                bf16x8 bk1 = *(const bf16x8*)&Kl[wg][j * 16 + r16][32 + g4 * 8];
                scv[j] = __builtin_amdgcn_mfma_f32_16x16x32_bf16(aq0, bk0, scv[j], 0, 0, 0);
                scv[j] = __builtin_amdgcn_mfma_f32_16x16x32_bf16(aq1, bk1, scv[j], 0, 0, 0);
            }
            __builtin_amdgcn_s_setprio(0);

            // ---- scale + mask ----
            bool diag = CAUSAL && (t == lastT);
            #pragma unroll
            for (int j = 0; j < 4; j++) {
                int col = j * 16 + r16;
                int mm = 1;
                if (HASMASK) mm = __shfl(mv_use, col, 64);
                #pragma unroll
                for (int q = 0; q < 4; q++) {
                    float v = scv[j][q] * 0.125f;
                    if (diag && col > (qx & 1) * 32 + wq * 16 + g4 * 4 + q) v = -1e30f;
                    if (HASMASK && mm == 0) v = -1e30f;
                    scv[j][q] = v;
                }
            }

            // ---- online softmax with defer-max (THR=8) ----
            float pmax[4];
            #pragma unroll
            for (int q = 0; q < 4; q++) {
                float v = fmaxf(fmaxf(scv[0][q], scv[1][q]), fmaxf(scv[2][q], scv[3][q]));
                v = fmaxf(v, __shfl_xor(v, 1, 64));
                v = fmaxf(v, __shfl_xor(v, 2, 64));
                v = fmaxf(v, __shfl_xor(v, 4, 64));
                v = fmaxf(v, __shfl_xor(v, 8, 64));
                pmax[q] = v;
            }
            bool skip = __all(pmax[0] <= m_[0] + 8.f && pmax[1] <= m_[1] + 8.f &&
                              pmax[2] <= m_[2] + 8.f && pmax[3] <= m_[3] + 8.f);
            if (!skip) {
                #pragma unroll
                for (int q = 0; q < 4; q++) {
                    float mnew = fmaxf(m_[q], pmax[q]);
                    float rf = __expf(m_[q] - mnew);
                    l_[q] *= rf;
                    #pragma unroll
                    for (int j = 0; j < 4; j++) acc[j][q] *= rf;
                    m_[q] = mnew;
                }
            }
            #pragma unroll
            for (int q = 0; q < 4; q++) {
                float rs = 0.f;
                #pragma unroll
                for (int j = 0; j < 4; j++) {
                    float pv = __expf(scv[j][q] - m_[q]);
                    scv[j][q] = pv;
                    rs += pv;
                }
                rs += __shfl_xor(rs, 1, 64);
                rs += __shfl_xor(rs, 2, 64);
                rs += __shfl_xor(rs, 4, 64);
                rs += __shfl_xor(rs, 8, 64);
                l_[q] += rs;
            }

            // ---- P -> per-wave LDS (C/D layout -> A-frag layout) ----
            #pragma unroll
            for (int j = 0; j < 4; j++)
                #pragma unroll
                for (int q = 0; q < 4; q++)
                    Pl[wv][g4 * 4 + q][j * 16 + r16] = (bf16_t)scv[j][q];
            asm volatile("s_waitcnt lgkmcnt(0)" ::: "memory");
            __builtin_amdgcn_sched_barrier(0);

            // ---- PV: 8 MFMA ----
            __builtin_amdgcn_s_setprio(1);
            #pragma unroll
            for (int c = 0; c < 2; c++) {
                bf16x8 pa = *(const bf16x8*)&Pl[wv][r16][c * 32 + g4 * 8];
                #pragma unroll
                for (int j = 0; j < 4; j++) {
                    bf16x8 bv = *(const bf16x8*)&Vl[wg][j * 16 + r16][c * 32 + g4 * 8];
                    acc[j] = __builtin_amdgcn_mfma_f32_16x16x32_bf16(pa, bv, acc[j], 0, 0, 0);
                }
            }
            __builtin_amdgcn_s_setprio(0);
        }
        __syncthreads();                      // all reads done before next write
    }

    // ---- merge group 1 state into group 0 via LDS, write output ----
    float* accS = (float*)&Kl[0][0][0];       // 32x64 f32 = 8 KB (fits in Kl[0])
    float* mlS  = accS + 32 * 64;
    if (wg == 1) {
        #pragma unroll
        for (int j = 0; j < 4; j++)
            #pragma unroll
            for (int q = 0; q < 4; q++)
                accS[(wq * 16 + g4 * 4 + q) * 64 + j * 16 + r16] = acc[j][q];
        if (r16 == 0)
            #pragma unroll
            for (int q = 0; q < 4; q++) {
                mlS[(wq * 16 + g4 * 4 + q) * 2 + 0] = m_[q];
                mlS[(wq * 16 + g4 * 4 + q) * 2 + 1] = l_[q];
            }
    }
    __syncthreads();
    if (wg == 0) {
        bf16_t* aob = ao + ((long)(b * Tn + qx * 32 + wq * 16 + g4 * 4)) * Cdim + h * 64;
        #pragma unroll
        for (int q = 0; q < 4; q++) {
            int row = wq * 16 + g4 * 4 + q;
            float mB = mlS[row * 2], lB = mlS[row * 2 + 1];
            float mS = fmaxf(m_[q], mB);
            float fA = __expf(m_[q] - mS), fB = __expf(mB - mS);
            float lS = l_[q] * fA + lB * fB;
            float inv = 1.f / lS;
            #pragma unroll
            for (int j = 0; j < 4; j++) {
                float o = (acc[j][q] * fA + accS[row * 64 + j * 16 + r16] * fB) * inv;
                aob[(long)q * Cdim + j * 16 + r16] = (bf16_t)o;
            }
        }
    }
}

// ================================ host orchestration ================================
static void run_attn(hipStream_t stream, const bf16_t* hq, const bf16_t* hkv,
    const bf16_t* wqkv, const float* bo, const bf16_t* wo_t,
    float* xres, const int* mask, bool causal,
    bf16_t* qkv, bf16_t* vt, bf16_t* ao)
{
    dim3 blk(256);
    // fused qkv projection: N=1536 (cols<512 read hq, else hkv); v-part -> vt
    mgemm_k<64,128,64,false,false,false,true,true,0,false,false><<<dim3(12, 32, 1), blk, 0, stream>>>(
        hq, hkv, 512, wqkv, nullptr, nullptr, qkv, nullptr, vt, 1024,
        Cdim, Cdim, Cdim, 1536);
    if (causal)
        flash_k<true,false><<<dim3(Tn / 32, Bn * Hn), dim3(256), 0, stream>>>(qkv, vt, nullptr, ao);
    else
        flash_k<false,true><<<dim3(Tn / 32, Bn * Hn), dim3(256), 0, stream>>>(qkv, vt, mask, ao);
    // out projection + bias + residual (f32, in place on xres) — coalesced epilogue
    mgemm_k<64,64,64,true,false,true,false,false,0,false,true><<<dim3(8, 32, 1), blk, 0, stream>>>(
        ao, ao, 1 << 30, wo_t, bo, xres, xres, nullptr, nullptr, 1 << 30,
        Cdim, Cdim, Cdim, Cdim);
}

extern "C" void kernel_launch(void* const* d_in, const int* in_sizes, int n_in,
                              void* d_out, int out_size, void* d_ws, size_t ws_size,
                              hipStream_t stream)
{
    (void)in_sizes; (void)n_in; (void)out_size; (void)ws_size;
    const int*   enc_inp  = (const int*)d_in[0];
    const int*   dec_inp  = (const int*)d_in[1];
    const int*   enc_mask = (const int*)d_in[2];
    const float* tok_emb  = (const float*)d_in[3];
    const float* pos_emb  = (const float*)d_in[4];
    const float* e_wq  = (const float*)d_in[5];
    const float* e_wk  = (const float*)d_in[6];
    const float* e_wv  = (const float*)d_in[7];
    const float* e_wo  = (const float*)d_in[8];
    const float* e_bo  = (const float*)d_in[9];
    const float* dsa_wq = (const float*)d_in[10];
    const float* dsa_wk = (const float*)d_in[11];
    const float* dsa_wv = (const float*)d_in[12];
    const float* dsa_wo = (const float*)d_in[13];
    const float* dsa_bo = (const float*)d_in[14];
    const float* dca_wq = (const float*)d_in[15];
    const float* dca_wk = (const float*)d_in[16];
    const float* dca_wv = (const float*)d_in[17];
    const float* dca_wo = (const float*)d_in[18];
    const float* dca_bo = (const float*)d_in[19];
    const float* e_ln1_g = (const float*)d_in[20];
    const float* e_ln1_b = (const float*)d_in[21];
    const float* e_ln2_g = (const float*)d_in[22];
    const float* e_ln2_b = (const float*)d_in[23];
    const float* d_ln1_g = (const float*)d_in[24];
    const float* d_ln1_b = (const float*)d_in[25];
    const float* d_ln2_g = (const float*)d_in[26];
    const float* d_ln2_b = (const float*)d_in[27];
    const float* d_ln3_g = (const float*)d_in[28];
    const float* d_ln3_b = (const float*)d_in[29];
    const float* e_w1 = (const float*)d_in[30];
    const float* e_b1 = (const float*)d_in[31];
    const float* e_w2 = (const float*)d_in[32];
    const float* e_b2 = (const float*)d_in[33];
    const float* d_w1 = (const float*)d_in[34];
    const float* d_b1 = (const float*)d_in[35];
    const float* d_w2 = (const float*)d_in[36];
    const float* d_b2 = (const float*)d_in[37];
    const float* out_w = (const float*)d_in[38];
    const float* out_b = (const float*)d_in[39];
    float* out = (float*)d_out;

    // -------- workspace carve (bytes) --------
    char* p = (char*)d_ws;
    auto takeB = [&](size_t bytes) { char* r = p; p += (bytes + 255) & ~(size_t)255; return r; };
    float*  x_enc = (float*)takeB(1048576ull * 4);
    float*  x_dec = (float*)takeB(1048576ull * 4);
    bf16_t* h     = (bf16_t*)takeB(1048576ull * 2);
    bf16_t* hk    = (bf16_t*)takeB(1048576ull * 2);
    bf16_t* qkv   = (bf16_t*)takeB(3145728ull * 2);
    bf16_t* vt    = (bf16_t*)takeB(1048576ull * 2);
    bf16_t* ao    = (bf16_t*)takeB(1048576ull * 2);
    bf16_t* xdb   = (bf16_t*)takeB(1048576ull * 2);
    bf16_t* mid   = (bf16_t*)takeB(4194304ull * 2);
    bf16_t* wqkv_t = (bf16_t*)takeB(12ull * 786432 * 2);
    bf16_t* wo_t   = (bf16_t*)takeB(12ull * 262144 * 2);
    bf16_t* w1_t   = (bf16_t*)takeB(8ull * 1048576 * 2);
    bf16_t* w2_t   = (bf16_t*)takeB(8ull * 1048576 * 2);
    bf16_t* outw_t = (bf16_t*)takeB(16384000ull * 2);

    dim3 blk(256);
    const long LQKV = 1536L * Cdim;

    // ================= weight prep (5 launches) =================
    QkvSrc qs;
    qs.p[0] = e_wq;   qs.p[1] = e_wk;   qs.p[2] = e_wv;
    qs.p[3] = dsa_wq; qs.p[4] = dsa_wk; qs.p[5] = dsa_wv;
    qs.p[6] = dca_wq; qs.p[7] = dca_wk; qs.p[8] = dca_wv;
    tcvt_qkv_k<<<dim3(1, 8, 288), blk, 0, stream>>>(qs, wqkv_t);
    Ptr3 pw;
    pw.p[0] = e_wo; pw.p[1] = dsa_wo; pw.p[2] = dca_wo;
    tcvt_b_k<<<dim3(8, 8, 12), blk, 0, stream>>>(pw, wo_t, Cdim, Cdim, 4, (long)Cdim * Cdim);
    pw.p[0] = e_w1; pw.p[1] = d_w1; pw.p[2] = nullptr;
    tcvt_b_k<<<dim3(32, 8, 8), blk, 0, stream>>>(pw, w1_t, Cdim, FF, 4, (long)Cdim * FF);
    pw.p[0] = e_w2; pw.p[1] = d_w2; pw.p[2] = nullptr;
    tcvt_b_k<<<dim3(8, 32, 8), blk, 0, stream>>>(pw, w2_t, FF, Cdim, 4, (long)FF * Cdim);
    pw.p[0] = out_w; pw.p[1] = nullptr; pw.p[2] = nullptr;
    tcvt_b_k<<<dim3(500, 8, 1), blk, 0, stream>>>(pw, outw_t, Cdim, Vn, 1, 0);

    // ================= encoder =================
    embed_ln_k<<<NTOK / 4, blk, 0, stream>>>(enc_inp, tok_emb, pos_emb, e_ln1_g, e_ln1_b, x_enc, h);
    for (int l = 0; l < Ld; l++) {
        if (l) ln_k<<<NTOK / 4, blk, 0, stream>>>(x_enc, e_ln1_g + l * Cdim, e_ln1_b + l * Cdim, h);
        run_attn(stream, h, h,
                 wqkv_t + (long)l * LQKV, e_bo + l * Cdim, wo_t + (long)l * Cdim * Cdim,
                 x_enc, enc_mask, /*causal=*/false, qkv, vt, ao);
        ln_k<<<NTOK / 4, blk, 0, stream>>>(x_enc, e_ln2_g + l * Cdim, e_ln2_b + l * Cdim, h);
        mgemm_k<128,128,64,true,true,false,true,false,0,false,true><<<dim3(16, 16, 1), blk, 0, stream>>>(
            h, h, 1 << 30, w1_t + (long)l * Cdim * FF, e_b1 + l * FF, nullptr, mid,
            nullptr, nullptr, 1 << 30, Cdim, Cdim, Cdim, FF);
        mgemm_k<64,64,64,true,false,true,false,false,0,false,true><<<dim3(8, 32, 1), blk, 0, stream>>>(
            mid, mid, 1 << 30, w2_t + (long)l * FF * Cdim, e_b2 + l * Cdim, x_enc, x_enc,
            nullptr, nullptr, 1 << 30, FF, FF, FF, Cdim);
    }
    // x_enc now holds enc_out

    // ================= decoder =================
    embed_ln_k<<<NTOK / 4, blk, 0, stream>>>(dec_inp, tok_emb, pos_emb, d_ln1_g, d_ln1_b, x_dec, h);
    for (int l = 0; l < Ld; l++) {
        // causal self-attention
        if (l) ln_k<<<NTOK / 4, blk, 0, stream>>>(x_dec, d_ln1_g + l * Cdim, d_ln1_b + l * Cdim, h);
        run_attn(stream, h, h,
                 wqkv_t + (long)(Ld + l) * LQKV, dsa_bo + l * Cdim,
                 wo_t + (long)(Ld + l) * Cdim * Cdim,
                 x_dec, nullptr, /*causal=*/true, qkv, vt, ao);
        // cross-attention (same LN applied to x and enc_out) — one fused launch
        ln2_k<<<2 * NTOK / 4, blk, 0, stream>>>(x_dec, x_enc,
            d_ln2_g + l * Cdim, d_ln2_b + l * Cdim, h, hk);
        run_attn(stream, h, hk,
                 wqkv_t + (long)(2 * Ld + l) * LQKV, dca_bo + l * Cdim,
                 wo_t + (long)(2 * Ld + l) * Cdim * Cdim,
                 x_dec, enc_mask, /*causal=*/false, qkv, vt, ao);
        // FFN
        ln_k<<<NTOK / 4, blk, 0, stream>>>(x_dec, d_ln3_g + l * Cdim, d_ln3_b + l * Cdim, h);
        mgemm_k<128,128,64,true,true,false,true,false,0,false,true><<<dim3(16, 16, 1), blk, 0, stream>>>(
            h, h, 1 << 30, w1_t + (long)(Ld + l) * Cdim * FF, d_b1 + l * FF, nullptr, mid,
            nullptr, nullptr, 1 << 30, Cdim, Cdim, Cdim, FF);
        if (l < Ld - 1)
            mgemm_k<64,64,64,true,false,true,false,false,0,false,true><<<dim3(8, 32, 1), blk, 0, stream>>>(
                mid, mid, 1 << 30, w2_t + (long)(Ld + l) * FF * Cdim, d_b2 + l * Cdim, x_dec, x_dec,
                nullptr, nullptr, 1 << 30, FF, FF, FF, Cdim);
        else  // last layer: also emit bf16 copy for logits GEMM
            mgemm_k<64,64,64,true,false,true,false,false,0,true,true><<<dim3(8, 32, 1), blk, 0, stream>>>(
                mid, mid, 1 << 30, w2_t + (long)(Ld + l) * FF * Cdim, d_b2 + l * Cdim, x_dec, x_dec,
                xdb, nullptr, 1 << 30, FF, FF, FF, Cdim);
    }

    // ================= final logits (f32 out, 128x128, coalesced, XCD-swizzled) ==========
    mgemm_k<128,128,64,true,false,false,false,false,16,false,true><<<dim3(250, 16, 1), blk, 0, stream>>>(
        xdb, xdb, 1 << 30, outw_t, out_b, nullptr, out, nullptr, nullptr, 1 << 30,
        Cdim, Cdim, Cdim, Vn);
}

// Round 12
// 1012.550 us; speedup vs baseline: 1.2424x; 1.0171x over previous
//
#include <hip/hip_runtime.h>
#include <hip/hip_bf16.h>
#include <math.h>

#define Cdim 512
#define Hn   8
#define HDim 64
#define Ld   4
#define Tn   1024
#define Bn   2
#define NTOK 2048   // B*T
#define FF   2048   // 4*C
#define Vn   32000

typedef __bf16 bf16_t;
typedef __bf16 bf16x8 __attribute__((ext_vector_type(8)));
typedef __bf16 bf16x4 __attribute__((ext_vector_type(4)));
typedef float  f32x4  __attribute__((ext_vector_type(4)));

// ---------------- layernorm: one wave per row, 4 rows/block, no barriers ----------------
__device__ __forceinline__ void ln_wave(const float* __restrict__ xr,
    const float* __restrict__ g, const float* __restrict__ bb,
    bf16_t* __restrict__ yr, int lane)
{
    f32x4 a = *(const f32x4*)&xr[lane * 8];
    f32x4 c = *(const f32x4*)&xr[lane * 8 + 4];
    float s = a[0] + a[1] + a[2] + a[3] + c[0] + c[1] + c[2] + c[3];
    #pragma unroll
    for (int o = 1; o < 64; o <<= 1) s += __shfl_xor(s, o, 64);
    float mean = s * (1.f / Cdim);
    float d[8], qv = 0.f;
    #pragma unroll
    for (int k = 0; k < 4; k++) { d[k] = a[k] - mean; d[4 + k] = c[k] - mean; }
    #pragma unroll
    for (int k = 0; k < 8; k++) qv += d[k] * d[k];
    #pragma unroll
    for (int o = 1; o < 64; o <<= 1) qv += __shfl_xor(qv, o, 64);
    float inv = rsqrtf(qv * (1.f / Cdim) + 1e-5f);
    f32x4 g0 = *(const f32x4*)&g[lane * 8],  g1 = *(const f32x4*)&g[lane * 8 + 4];
    f32x4 b0 = *(const f32x4*)&bb[lane * 8], b1 = *(const f32x4*)&bb[lane * 8 + 4];
    bf16x8 o;
    #pragma unroll
    for (int k = 0; k < 4; k++) {
        o[k]     = (bf16_t)(d[k]     * inv * g0[k] + b0[k]);
        o[4 + k] = (bf16_t)(d[4 + k] * inv * g1[k] + b1[k]);
    }
    *(bf16x8*)&yr[lane * 8] = o;
}

__global__ __launch_bounds__(256) void ln_k(const float* __restrict__ x,
    const float* __restrict__ g, const float* __restrict__ bb, bf16_t* __restrict__ y)
{
    int wid = threadIdx.x >> 6, lane = threadIdx.x & 63;
    int row = blockIdx.x * 4 + wid;
    ln_wave(x + (long)row * Cdim, g, bb, y + (long)row * Cdim, lane);
}

// two-source LN (cross-attention): rows < NTOK from x1->y1, else x2->y2 (same g,b)
__global__ __launch_bounds__(256) void ln2_k(const float* __restrict__ x1,
    const float* __restrict__ x2, const float* __restrict__ g,
    const float* __restrict__ bb, bf16_t* __restrict__ y1, bf16_t* __restrict__ y2)
{
    int wid = threadIdx.x >> 6, lane = threadIdx.x & 63;
    int row = blockIdx.x * 4 + wid;
    const float* x = (row < NTOK) ? x1 : x2;
    bf16_t*      y = (row < NTOK) ? y1 : y2;
    int r = row & (NTOK - 1);
    ln_wave(x + (long)r * Cdim, g, bb, y + (long)r * Cdim, lane);
}

// ---------------- fused embedding + first-layer LN (wave per row) ----------------
__global__ __launch_bounds__(256) void embed_ln_k(const int* __restrict__ inp,
    const float* __restrict__ tok, const float* __restrict__ pos,
    const float* __restrict__ g, const float* __restrict__ bb,
    float* __restrict__ x, bf16_t* __restrict__ y)
{
    int wid = threadIdx.x >> 6, lane = threadIdx.x & 63;
    int bt = blockIdx.x * 4 + wid;
    int t = bt & (Tn - 1);
    long toff = (long)inp[bt] * Cdim;
    f32x4 a = *(const f32x4*)&tok[toff + lane * 8];
    f32x4 c = *(const f32x4*)&tok[toff + lane * 8 + 4];
    f32x4 pa = *(const f32x4*)&pos[(long)t * Cdim + lane * 8];
    f32x4 pc = *(const f32x4*)&pos[(long)t * Cdim + lane * 8 + 4];
    a += pa; c += pc;
    float* xr = x + (long)bt * Cdim;
    *(f32x4*)&xr[lane * 8] = a;
    *(f32x4*)&xr[lane * 8 + 4] = c;
    float s = a[0] + a[1] + a[2] + a[3] + c[0] + c[1] + c[2] + c[3];
    #pragma unroll
    for (int o = 1; o < 64; o <<= 1) s += __shfl_xor(s, o, 64);
    float mean = s * (1.f / Cdim);
    float d[8], qv = 0.f;
    #pragma unroll
    for (int k = 0; k < 4; k++) { d[k] = a[k] - mean; d[4 + k] = c[k] - mean; }
    #pragma unroll
    for (int k = 0; k < 8; k++) qv += d[k] * d[k];
    #pragma unroll
    for (int o = 1; o < 64; o <<= 1) qv += __shfl_xor(qv, o, 64);
    float inv = rsqrtf(qv * (1.f / Cdim) + 1e-5f);
    f32x4 g0 = *(const f32x4*)&g[lane * 8],  g1 = *(const f32x4*)&g[lane * 8 + 4];
    f32x4 b0 = *(const f32x4*)&bb[lane * 8], b1 = *(const f32x4*)&bb[lane * 8 + 4];
    bf16x8 o;
    #pragma unroll
    for (int k = 0; k < 4; k++) {
        o[k]     = (bf16_t)(d[k]     * inv * g0[k] + b0[k]);
        o[4 + k] = (bf16_t)(d[4 + k] * inv * g1[k] + b1[k]);
    }
    *(bf16x8*)&y[(long)bt * Cdim + lane * 8] = o;
}

// ------- batched tiled transpose+convert: f32 [R,Cc] -> bf16 [Cc,R] over z sources/layers -------
struct Ptr3 { const float* p[3]; };
__global__ __launch_bounds__(256) void tcvt_b_k(Ptr3 srcs, bf16_t* __restrict__ dst,
    int R, int Cc, int lps, long dstStride)
{
    int z = blockIdx.z; int s = z / lps, l = z - s * lps;
    const float* in = srcs.p[s] + (long)l * R * Cc;
    bf16_t* op = dst + (long)z * dstStride;
    __shared__ float t[64][65];
    int r0 = blockIdx.y * 64, c0 = blockIdx.x * 64;
    int tx = threadIdx.x & 63, ty = threadIdx.x >> 6;
    #pragma unroll
    for (int i = 0; i < 16; i++)
        t[ty + i * 4][tx] = in[(long)(r0 + ty + i * 4) * Cc + c0 + tx];
    __syncthreads();
    #pragma unroll
    for (int i = 0; i < 16; i++) {
        int cc = ty + i * 4;
        op[(long)(c0 + cc) * R + r0 + tx] = (bf16_t)t[tx][cc];
    }
}

// ------- fused QKV weight prep: 9 (set,part) sources in one launch -------
struct QkvSrc { const float* p[9]; };
__global__ __launch_bounds__(256) void tcvt_qkv_k(QkvSrc srcs, bf16_t* __restrict__ outp)
{
    int z = blockIdx.z;
    int si = z >> 5, zb = (z >> 3) & 3, zh = z & 7;
    int set = si / 3, part = si - set * 3;
    const float* in = srcs.p[si] + (long)zb * (Hn * Cdim * HDim) + (long)zh * (Cdim * HDim);
    bf16_t* op = outp + ((long)set * Ld + zb) * (1536L * Cdim)
                      + (long)part * 512 * Cdim + (long)zh * 64 * Cdim;
    __shared__ float t[64][65];
    int r0 = blockIdx.y * 64;
    int tx = threadIdx.x & 63, ty = threadIdx.x >> 6;
    #pragma unroll
    for (int i = 0; i < 16; i++)
        t[ty + i * 4][tx] = in[(long)(r0 + ty + i * 4) * HDim + tx];
    __syncthreads();
    #pragma unroll
    for (int i = 0; i < 16; i++) {
        int cc = ty + i * 4;
        op[(long)cc * Cdim + r0 + tx] = (bf16_t)t[tx][cc];
    }
}

// ================= bf16 MFMA GEMM, double-buffered K pipeline =================
// 256 threads = 4 waves (2x2). Chunk-XOR LDS swizzle (conflict-free at BK=64;
// 4-way at BK=32 — used only where occupancy matters more than LDS throughput).
// Separate As0/As1/Bs0/Bs1 arrays so in-flight global_load_lds of the next
// tile provably doesn't alias current ds_reads -> stage latency hides.
template<int BM, int BN, int BK, bool BIAS, bool RELU, bool RES, bool OBF,
         bool VOUT, int SWZM, bool XOUT, bool COAL>
__global__ __launch_bounds__(256) void mgemm_k(
    const bf16_t* __restrict__ A, const bf16_t* __restrict__ A2, int aSplit,
    const bf16_t* __restrict__ Bt, const float* __restrict__ bias,
    const float* __restrict__ res, void* __restrict__ Cout,
    bf16_t* __restrict__ xout, bf16_t* __restrict__ vtout, int vSplit,
    int K, int lda, int ldb, int ldc)
{
    constexpr int MR = BM / 32;
    constexpr int NR = BN / 32;
    constexpr int KK = BK / 32;
    constexpr int LPR = BK / 8;
    __shared__ bf16_t As0[BM * BK];
    __shared__ bf16_t As1[BM * BK];
    __shared__ bf16_t Bs0[BN * BK];
    __shared__ bf16_t Bs1[BN * BK];
    __shared__ float cws[COAL ? 4 * 16 * 36 : 1];

    int tid = threadIdx.x;
    int wv = tid >> 6, lane = tid & 63;
    int bm, bn;
    if constexpr (SWZM > 0) {
        int lin = blockIdx.y * gridDim.x + blockIdx.x;
        int tot = gridDim.x * gridDim.y;
        int chunk = tot >> 3;
        int e = (lin & 7) * chunk + (lin >> 3);
        bm = (e % SWZM) * BM;
        bn = (e / SWZM) * BN;
    } else {
        bm = blockIdx.y * BM; bn = blockIdx.x * BN;
    }
    const bf16_t* Ab = (bn < aSplit) ? A : A2;
    int wr = wv >> 1, wc = wv & 1;

    f32x4 acc[MR][NR];
    #pragma unroll
    for (int i = 0; i < MR; i++)
        #pragma unroll
        for (int j = 0; j < NR; j++)
            acc[i][j] = (f32x4){0.f, 0.f, 0.f, 0.f};

    constexpr int RPW = 512 / BK;
    constexpr int RPP = 2048 / BK;
    const int sr  = lane / LPR;
    const int sc8 = ((lane % LPR) ^ (sr & (LPR - 1))) * 8;
    const int r16 = lane & 15, g4 = lane >> 4;

    auto stage = [&](int k0, bf16_t (&Asb)[BM * BK], bf16_t (&Bsb)[BN * BK]) {
        #pragma unroll
        for (int p = 0; p < BM * BK / 2048; p++) {
            int rb = p * RPP + wv * RPW;
            const bf16_t* g = Ab + (long)(bm + rb + sr) * lda + (k0 + sc8);
            __builtin_amdgcn_global_load_lds(
                (const __attribute__((address_space(1))) void*)g,
                (__attribute__((address_space(3))) void*)&Asb[rb * BK],
                16, 0, 0);
        }
        #pragma unroll
        for (int p = 0; p < BN * BK / 2048; p++) {
            int rb = p * RPP + wv * RPW;
            const bf16_t* g = Bt + (long)(bn + rb + sr) * ldb + (k0 + sc8);
            __builtin_amdgcn_global_load_lds(
                (const __attribute__((address_space(1))) void*)g,
                (__attribute__((address_space(3))) void*)&Bsb[rb * BK],
                16, 0, 0);
        }
    };
    auto compute = [&](bf16_t (&Asb)[BM * BK], bf16_t (&Bsb)[BN * BK]) {
        #pragma unroll
        for (int kk = 0; kk < KK; kk++) {
            bf16x8 bkk[NR];
            #pragma unroll
            for (int j = 0; j < NR; j++) {
                int row = wc * (BN / 2) + j * 16 + r16;
                bkk[j] = *(const bf16x8*)&Bsb[row * BK + (((kk * 4 + g4) ^ (row & (LPR - 1))) * 8)];
            }
            #pragma unroll
            for (int i = 0; i < MR; i++) {
                int row = wr * (BM / 2) + i * 16 + r16;
                bf16x8 a = *(const bf16x8*)&Asb[row * BK + (((kk * 4 + g4) ^ (row & (LPR - 1))) * 8)];
                #pragma unroll
                for (int j = 0; j < NR; j++)
                    acc[i][j] = __builtin_amdgcn_mfma_f32_16x16x32_bf16(a, bkk[j], acc[i][j], 0, 0, 0);
            }
        }
    };

    int nIt = K / BK;
    stage(0, As0, Bs0);
    for (int it = 0; it < nIt; it += 2) {
        __syncthreads();                               // As0/Bs0 staged; prior reads done
        if (it + 1 < nIt) stage((it + 1) * BK, As1, Bs1);
        compute(As0, Bs0);
        __syncthreads();                               // As1/Bs1 staged; As0 reads done
        if (it + 2 < nIt) stage((it + 2) * BK, As0, Bs0);
        if (it + 1 < nIt) compute(As1, Bs1);
    }

    if constexpr (COAL) {
        // ---- coalesced epilogue via per-wave LDS bounce ----
        #pragma unroll
        for (int i = 0; i < MR; i++) {
            int gr0 = bm + wr * (BM / 2) + i * 16;
            #pragma unroll
            for (int hh = 0; hh < NR / 2; hh++) {
                #pragma unroll
                for (int jj = 0; jj < 2; jj++) {
                    int j = hh * 2 + jj;
                    int gc = bn + wc * (BN / 2) + j * 16 + r16;
                    float bv = BIAS ? bias[gc] : 0.f;
                    #pragma unroll
                    for (int q = 0; q < 4; q++) {
                        float v = acc[i][j][q];
                        if (BIAS) v += bv;
                        if (RELU) v = fmaxf(v, 0.f);
                        cws[(wv * 16 + g4 * 4 + q) * 36 + jj * 16 + r16] = v;
                    }
                }
                int gcb = bn + wc * (BN / 2) + hh * 32;
                if constexpr (OBF) {
                    int row = lane >> 2, c8 = (lane & 3) * 8;
                    f32x4 v0 = *(f32x4*)&cws[(wv * 16 + row) * 36 + c8];
                    f32x4 v1 = *(f32x4*)&cws[(wv * 16 + row) * 36 + c8 + 4];
                    long oidx = (long)(gr0 + row) * ldc + gcb + c8;
                    bf16x8 o;
                    #pragma unroll
                    for (int k = 0; k < 4; k++) { o[k] = (bf16_t)v0[k]; o[4 + k] = (bf16_t)v1[k]; }
                    *(bf16x8*)&((bf16_t*)Cout)[oidx] = o;
                } else {
                    #pragma unroll
                    for (int ps = 0; ps < 2; ps++) {
                        int row = (lane >> 3) + 8 * ps, c4 = (lane & 7) * 4;
                        f32x4 v = *(f32x4*)&cws[(wv * 16 + row) * 36 + c4];
                        long oidx = (long)(gr0 + row) * ldc + gcb + c4;
                        if (RES) v += *(const f32x4*)&res[oidx];
                        *(f32x4*)&((float*)Cout)[oidx] = v;
                        if (XOUT) {
                            bf16x4 o;
                            #pragma unroll
                            for (int k = 0; k < 4; k++) o[k] = (bf16_t)v[k];
                            *(bf16x4*)&xout[oidx] = o;
                        }
                    }
                }
            }
        }
    } else {
        // ---- scalar epilogue (VOUT scatter path) ----
        #pragma unroll
        for (int i = 0; i < MR; i++) {
            #pragma unroll
            for (int j = 0; j < NR; j++) {
                int gr = bm + wr * (BM / 2) + i * 16 + g4 * 4;
                int gc = bn + wc * (BN / 2) + j * 16 + r16;
                float bv = BIAS ? bias[gc] : 0.f;
                #pragma unroll
                for (int q = 0; q < 4; q++) {
                    float v = acc[i][j][q];
                    if (BIAS) v += bv;
                    if (RELU) v = fmaxf(v, 0.f);
                    if (VOUT && gc >= vSplit) {
                        int row = gr + q;
                        int b = row >> 10, t = row & (Tn - 1);
                        vtout[((long)b * 512 + (gc - vSplit)) * Tn + t] = (bf16_t)v;
                    } else {
                        long oidx = (long)(gr + q) * ldc + gc;
                        if (RES)  v += res[oidx];
                        if (OBF) ((bf16_t*)Cout)[oidx] = (bf16_t)v;
                        else     ((float*) Cout)[oidx] = v;
                        if (XOUT) xout[oidx] = (bf16_t)v;
                    }
                }
            }
        }
    }
}

// ================= fused flash attention (8 waves, KV-split, dbuf LDS, 1 barrier/iter) =========
template<bool CAUSAL, bool HASMASK>
__global__ __launch_bounds__(512, 2) void flash_k(
    const bf16_t* __restrict__ qkv, const bf16_t* __restrict__ vt,
    const int* __restrict__ mask, bf16_t* __restrict__ ao)
{
    __shared__ bf16_t Kl[2][2][64][72];
    __shared__ bf16_t Vl[2][2][64][72];
    __shared__ bf16_t Pl[8][16][72];

    int qt = blockIdx.x, bh = blockIdx.y;
    int b = bh >> 3, h = bh & 7;
    int tid = threadIdx.x, wv = tid >> 6, lane = tid & 63;
    int wg = wv >> 2, wq4 = wv & 3;
    int r16 = lane & 15, g4 = lane >> 4;
    int gtid = tid & 255;

    const bf16_t* qb = qkv + ((long)(b * Tn + qt * 64 + wq4 * 16 + r16)) * 1536 + h * 64;
    bf16x8 aq0 = *(const bf16x8*)&qb[g4 * 8];
    bf16x8 aq1 = *(const bf16x8*)&qb[32 + g4 * 8];

    f32x4 acc[4];
    #pragma unroll
    for (int j = 0; j < 4; j++) acc[j] = (f32x4){0.f, 0.f, 0.f, 0.f};
    float m_[4], l_[4];
    #pragma unroll
    for (int q = 0; q < 4; q++) { m_[q] = -1e30f; l_[q] = 0.f; }

    int lastT = CAUSAL ? qt : (Tn / 64 - 1);
    int niter = CAUSAL ? (qt / 2 + 1) : (Tn / 128);
    int krow = gtid >> 3, kcol = (gtid & 7) * 8;

    bf16x8 kr[2], vr[2];
    int mv = 0;
    {
        int t0 = wg;
        if (t0 <= lastT) {
            int s0 = t0 * 64;
            #pragma unroll
            for (int i = 0; i < 2; i++)
                kr[i] = *(const bf16x8*)&qkv[((long)(b * Tn + s0 + krow + i * 32)) * 1536 + 512 + h * 64 + kcol];
            #pragma unroll
            for (int i = 0; i < 2; i++)
                vr[i] = *(const bf16x8*)&vt[((long)(bh * 64 + krow + i * 32)) * Tn + s0 + kcol];
            if (HASMASK) mv = mask[b * Tn + s0 + lane];
        }
    }

    for (int it = 0; it < niter; it++) {
        int cur = it & 1;
        int t = 2 * it + wg;
        bool active = t <= lastT;
        if (active) {
            #pragma unroll
            for (int i = 0; i < 2; i++) *(bf16x8*)&Kl[cur][wg][krow + i * 32][kcol] = kr[i];
            #pragma unroll
            for (int i = 0; i < 2; i++) *(bf16x8*)&Vl[cur][wg][krow + i * 32][kcol] = vr[i];
        }
        int mv_use = mv;
        __syncthreads();
        int tn = t + 2;
        if (it + 1 < niter && tn <= lastT) {
            int sn = tn * 64;
            #pragma unroll
            for (int i = 0; i < 2; i++)
                kr[i] = *(const bf16x8*)&qkv[((long)(b * Tn + sn + krow + i * 32)) * 1536 + 512 + h * 64 + kcol];
            #pragma unroll
            for (int i = 0; i < 2; i++)
                vr[i] = *(const bf16x8*)&vt[((long)(bh * 64 + krow + i * 32)) * Tn + sn + kcol];
            if (HASMASK) mv = mask[b * Tn + sn + lane];
        }
        if (!active) continue;

        f32x4 scv[4];
        __builtin_amdgcn_s_setprio(1);
        #pragma unroll
        for (int j = 0; j < 4; j++) {
            scv[j] = (f32x4){0.f, 0.f, 0.f, 0.f};
            bf16x8 bk0 = *(const bf16x8*)&Kl[cur][wg][j * 16 + r16][g4 * 8];
            bf16x8 bk1 = *(const bf16x8*)&Kl[cur][wg][j * 16 + r16][32 + g4 * 8];
            scv[j] = __builtin_amdgcn_mfma_f32_16x16x32_bf16(aq0, bk0, scv[j], 0, 0, 0);
            scv[j] = __builtin_amdgcn_mfma_f32_16x16x32_bf16(aq1, bk1, scv[j], 0, 0, 0);
        }
        __builtin_amdgcn_s_setprio(0);

        bool diag = CAUSAL && (t == qt);
        #pragma unroll
        for (int j = 0; j < 4; j++) {
            int col = j * 16 + r16;
            int mm = 1;
            if (HASMASK) mm = __shfl(mv_use, col, 64);
            #pragma unroll
            for (int q = 0; q < 4; q++) {
                float v = scv[j][q] * 0.125f;
                if (diag && col > wq4 * 16 + g4 * 4 + q) v = -1e30f;
                if (HASMASK && mm == 0) v = -1e30f;
                scv[j][q] = v;
            }
        }

        float pmax[4];
        #pragma unroll
        for (int q = 0; q < 4; q++) {
            float v = fmaxf(fmaxf(scv[0][q], scv[1][q]), fmaxf(scv[2][q], scv[3][q]));
            v = fmaxf(v, __shfl_xor(v, 1, 64));
            v = fmaxf(v, __shfl_xor(v, 2, 64));
            v = fmaxf(v, __shfl_xor(v, 4, 64));
            v = fmaxf(v, __shfl_xor(v, 8, 64));
            pmax[q] = v;
        }
        bool skip = __all(pmax[0] <= m_[0] + 8.f && pmax[1] <= m_[1] + 8.f &&
                          pmax[2] <= m_[2] + 8.f && pmax[3] <= m_[3] + 8.f);
        if (!skip) {
            #pragma unroll
            for (int q = 0; q < 4; q++) {
                float mnew = fmaxf(m_[q], pmax[q]);
                float rf = __expf(m_[q] - mnew);
                l_[q] *= rf;
                #pragma unroll
                for (int j = 0; j < 4; j++) acc[j][q] *= rf;
                m_[q] = mnew;
            }
        }
        #pragma unroll
        for (int q = 0; q < 4; q++) {
            float rs = 0.f;
            #pragma unroll
            for (int j = 0; j < 4; j++) {
                float pv = __expf(scv[j][q] - m_[q]);
                scv[j][q] = pv;
                rs += pv;
            }
            rs += __shfl_xor(rs, 1, 64);
            rs += __shfl_xor(rs, 2, 64);
            rs += __shfl_xor(rs, 4, 64);
            rs += __shfl_xor(rs, 8, 64);
            l_[q] += rs;
        }

        #pragma unroll
        for (int j = 0; j < 4; j++)
            #pragma unroll
            for (int q = 0; q < 4; q++)
                Pl[wv][g4 * 4 + q][j * 16 + r16] = (bf16_t)scv[j][q];
        asm volatile("s_waitcnt lgkmcnt(0)" ::: "memory");
        __builtin_amdgcn_sched_barrier(0);

        __builtin_amdgcn_s_setprio(1);
        #pragma unroll
        for (int c = 0; c < 2; c++) {
            bf16x8 pa = *(const bf16x8*)&Pl[wv][r16][c * 32 + g4 * 8];
            #pragma unroll
            for (int j = 0; j < 4; j++) {
                bf16x8 bv = *(const bf16x8*)&Vl[cur][wg][j * 16 + r16][c * 32 + g4 * 8];
                acc[j] = __builtin_amdgcn_mfma_f32_16x16x32_bf16(pa, bv, acc[j], 0, 0, 0);
            }
        }
        __builtin_amdgcn_s_setprio(0);
    }

    float* accS = (float*)&Kl[0][0][0][0];
    float* mlS  = accS + 64 * 64;
    __syncthreads();
    if (wg == 1) {
        #pragma unroll
        for (int j = 0; j < 4; j++)
            #pragma unroll
            for (int q = 0; q < 4; q++)
                accS[(wq4 * 16 + g4 * 4 + q) * 64 + j * 16 + r16] = acc[j][q];
        if (r16 == 0)
            #pragma unroll
            for (int q = 0; q < 4; q++) {
                mlS[(wq4 * 16 + g4 * 4 + q) * 2 + 0] = m_[q];
                mlS[(wq4 * 16 + g4 * 4 + q) * 2 + 1] = l_[q];
            }
    }
    __syncthreads();
    if (wg == 0) {
        bf16_t* aob = ao + ((long)(b * Tn + qt * 64 + wq4 * 16 + g4 * 4)) * Cdim + h * 64;
        #pragma unroll
        for (int q = 0; q < 4; q++) {
            int row = wq4 * 16 + g4 * 4 + q;
            float mB = mlS[row * 2], lB = mlS[row * 2 + 1];
            float mS = fmaxf(m_[q], mB);
            float fA = __expf(m_[q] - mS), fB = __expf(mB - mS);
            float lS = l_[q] * fA + lB * fB;
            float inv = 1.f / lS;
            #pragma unroll
            for (int j = 0; j < 4; j++) {
                float o = (acc[j][q] * fA + accS[row * 64 + j * 16 + r16] * fB) * inv;
                aob[(long)q * Cdim + j * 16 + r16] = (bf16_t)o;
            }
        }
    }
}

// ================================ host orchestration ================================
static void run_attn(hipStream_t stream, const bf16_t* hq, const bf16_t* hkv,
    const bf16_t* wqkv, const float* bo, const bf16_t* wo_t,
    float* xres, const int* mask, bool causal,
    bf16_t* qkv, bf16_t* vt, bf16_t* ao)
{
    dim3 blk(256);
    // fused qkv projection: N=1536 (cols<512 read hq, else hkv); v-part -> vt
    mgemm_k<64,128,64,false,false,false,true,true,0,false,false><<<dim3(12, 32, 1), blk, 0, stream>>>(
        hq, hkv, 512, wqkv, nullptr, nullptr, qkv, nullptr, vt, 1024,
        Cdim, Cdim, Cdim, 1536);
    if (causal)
        flash_k<true,false><<<dim3(Tn / 64, Bn * Hn), dim3(512), 0, stream>>>(qkv, vt, nullptr, ao);
    else
        flash_k<false,true><<<dim3(Tn / 64, Bn * Hn), dim3(512), 0, stream>>>(qkv, vt, mask, ao);
    // out projection + bias + residual (f32, in place on xres) — coalesced epilogue
    mgemm_k<64,64,64,true,false,true,false,false,0,false,true><<<dim3(8, 32, 1), blk, 0, stream>>>(
        ao, ao, 1 << 30, wo_t, bo, xres, xres, nullptr, nullptr, 1 << 30,
        Cdim, Cdim, Cdim, Cdim);
}

extern "C" void kernel_launch(void* const* d_in, const int* in_sizes, int n_in,
                              void* d_out, int out_size, void* d_ws, size_t ws_size,
                              hipStream_t stream)
{
    (void)in_sizes; (void)n_in; (void)out_size; (void)ws_size;
    const int*   enc_inp  = (const int*)d_in[0];
    const int*   dec_inp  = (const int*)d_in[1];
    const int*   enc_mask = (const int*)d_in[2];
    const float* tok_emb  = (const float*)d_in[3];
    const float* pos_emb  = (const float*)d_in[4];
    const float* e_wq  = (const float*)d_in[5];
    const float* e_wk  = (const float*)d_in[6];
    const float* e_wv  = (const float*)d_in[7];
    const float* e_wo  = (const float*)d_in[8];
    const float* e_bo  = (const float*)d_in[9];
    const float* dsa_wq = (const float*)d_in[10];
    const float* dsa_wk = (const float*)d_in[11];
    const float* dsa_wv = (const float*)d_in[12];
    const float* dsa_wo = (const float*)d_in[13];
    const float* dsa_bo = (const float*)d_in[14];
    const float* dca_wq = (const float*)d_in[15];
    const float* dca_wk = (const float*)d_in[16];
    const float* dca_wv = (const float*)d_in[17];
    const float* dca_wo = (const float*)d_in[18];
    const float* dca_bo = (const float*)d_in[19];
    const float* e_ln1_g = (const float*)d_in[20];
    const float* e_ln1_b = (const float*)d_in[21];
    const float* e_ln2_g = (const float*)d_in[22];
    const float* e_ln2_b = (const float*)d_in[23];
    const float* d_ln1_g = (const float*)d_in[24];
    const float* d_ln1_b = (const float*)d_in[25];
    const float* d_ln2_g = (const float*)d_in[26];
    const float* d_ln2_b = (const float*)d_in[27];
    const float* d_ln3_g = (const float*)d_in[28];
    const float* d_ln3_b = (const float*)d_in[29];
    const float* e_w1 = (const float*)d_in[30];
    const float* e_b1 = (const float*)d_in[31];
    const float* e_w2 = (const float*)d_in[32];
    const float* e_b2 = (const float*)d_in[33];
    const float* d_w1 = (const float*)d_in[34];
    const float* d_b1 = (const float*)d_in[35];
    const float* d_w2 = (const float*)d_in[36];
    const float* d_b2 = (const float*)d_in[37];
    const float* out_w = (const float*)d_in[38];
    const float* out_b = (const float*)d_in[39];
    float* out = (float*)d_out;

    // -------- workspace carve (bytes) --------
    char* p = (char*)d_ws;
    auto takeB = [&](size_t bytes) { char* r = p; p += (bytes + 255) & ~(size_t)255; return r; };
    float*  x_enc = (float*)takeB(1048576ull * 4);
    float*  x_dec = (float*)takeB(1048576ull * 4);
    bf16_t* h     = (bf16_t*)takeB(1048576ull * 2);
    bf16_t* hk    = (bf16_t*)takeB(1048576ull * 2);
    bf16_t* qkv   = (bf16_t*)takeB(3145728ull * 2);
    bf16_t* vt    = (bf16_t*)takeB(1048576ull * 2);
    bf16_t* ao    = (bf16_t*)takeB(1048576ull * 2);
    bf16_t* xdb   = (bf16_t*)takeB(1048576ull * 2);
    bf16_t* mid   = (bf16_t*)takeB(4194304ull * 2);
    bf16_t* wqkv_t = (bf16_t*)takeB(12ull * 786432 * 2);
    bf16_t* wo_t   = (bf16_t*)takeB(12ull * 262144 * 2);
    bf16_t* w1_t   = (bf16_t*)takeB(8ull * 1048576 * 2);
    bf16_t* w2_t   = (bf16_t*)takeB(8ull * 1048576 * 2);
    bf16_t* outw_t = (bf16_t*)takeB(16384000ull * 2);

    dim3 blk(256);
    const long LQKV = 1536L * Cdim;

    // ================= weight prep (5 launches) =================
    QkvSrc qs;
    qs.p[0] = e_wq;   qs.p[1] = e_wk;   qs.p[2] = e_wv;
    qs.p[3] = dsa_wq; qs.p[4] = dsa_wk; qs.p[5] = dsa_wv;
    qs.p[6] = dca_wq; qs.p[7] = dca_wk; qs.p[8] = dca_wv;
    tcvt_qkv_k<<<dim3(1, 8, 288), blk, 0, stream>>>(qs, wqkv_t);
    Ptr3 pw;
    pw.p[0] = e_wo; pw.p[1] = dsa_wo; pw.p[2] = dca_wo;
    tcvt_b_k<<<dim3(8, 8, 12), blk, 0, stream>>>(pw, wo_t, Cdim, Cdim, 4, (long)Cdim * Cdim);
    pw.p[0] = e_w1; pw.p[1] = d_w1; pw.p[2] = nullptr;
    tcvt_b_k<<<dim3(32, 8, 8), blk, 0, stream>>>(pw, w1_t, Cdim, FF, 4, (long)Cdim * FF);
    pw.p[0] = e_w2; pw.p[1] = d_w2; pw.p[2] = nullptr;
    tcvt_b_k<<<dim3(8, 32, 8), blk, 0, stream>>>(pw, w2_t, FF, Cdim, 4, (long)FF * Cdim);
    pw.p[0] = out_w; pw.p[1] = nullptr; pw.p[2] = nullptr;
    tcvt_b_k<<<dim3(500, 8, 1), blk, 0, stream>>>(pw, outw_t, Cdim, Vn, 1, 0);

    // ================= encoder =================
    embed_ln_k<<<NTOK / 4, blk, 0, stream>>>(enc_inp, tok_emb, pos_emb, e_ln1_g, e_ln1_b, x_enc, h);
    for (int l = 0; l < Ld; l++) {
        if (l) ln_k<<<NTOK / 4, blk, 0, stream>>>(x_enc, e_ln1_g + l * Cdim, e_ln1_b + l * Cdim, h);
        run_attn(stream, h, h,
                 wqkv_t + (long)l * LQKV, e_bo + l * Cdim, wo_t + (long)l * Cdim * Cdim,
                 x_enc, enc_mask, /*causal=*/false, qkv, vt, ao);
        ln_k<<<NTOK / 4, blk, 0, stream>>>(x_enc, e_ln2_g + l * Cdim, e_ln2_b + l * Cdim, h);
        mgemm_k<128,128,64,true,true,false,true,false,0,false,true><<<dim3(16, 16, 1), blk, 0, stream>>>(
            h, h, 1 << 30, w1_t + (long)l * Cdim * FF, e_b1 + l * FF, nullptr, mid,
            nullptr, nullptr, 1 << 30, Cdim, Cdim, Cdim, FF);
        mgemm_k<64,64,64,true,false,true,false,false,0,false,true><<<dim3(8, 32, 1), blk, 0, stream>>>(
            mid, mid, 1 << 30, w2_t + (long)l * FF * Cdim, e_b2 + l * Cdim, x_enc, x_enc,
            nullptr, nullptr, 1 << 30, FF, FF, FF, Cdim);
    }
    // x_enc now holds enc_out

    // ================= decoder =================
    embed_ln_k<<<NTOK / 4, blk, 0, stream>>>(dec_inp, tok_emb, pos_emb, d_ln1_g, d_ln1_b, x_dec, h);
    for (int l = 0; l < Ld; l++) {
        // causal self-attention
        if (l) ln_k<<<NTOK / 4, blk, 0, stream>>>(x_dec, d_ln1_g + l * Cdim, d_ln1_b + l * Cdim, h);
        run_attn(stream, h, h,
                 wqkv_t + (long)(Ld + l) * LQKV, dsa_bo + l * Cdim,
                 wo_t + (long)(Ld + l) * Cdim * Cdim,
                 x_dec, nullptr, /*causal=*/true, qkv, vt, ao);
        // cross-attention (same LN applied to x and enc_out) — one fused launch
        ln2_k<<<2 * NTOK / 4, blk, 0, stream>>>(x_dec, x_enc,
            d_ln2_g + l * Cdim, d_ln2_b + l * Cdim, h, hk);
        run_attn(stream, h, hk,
                 wqkv_t + (long)(2 * Ld + l) * LQKV, dca_bo + l * Cdim,
                 wo_t + (long)(2 * Ld + l) * Cdim * Cdim,
                 x_dec, enc_mask, /*causal=*/false, qkv, vt, ao);
        // FFN
        ln_k<<<NTOK / 4, blk, 0, stream>>>(x_dec, d_ln3_g + l * Cdim, d_ln3_b + l * Cdim, h);
        mgemm_k<128,128,64,true,true,false,true,false,0,false,true><<<dim3(16, 16, 1), blk, 0, stream>>>(
            h, h, 1 << 30, w1_t + (long)(Ld + l) * Cdim * FF, d_b1 + l * FF, nullptr, mid,
            nullptr, nullptr, 1 << 30, Cdim, Cdim, Cdim, FF);
        if (l < Ld - 1)
            mgemm_k<64,64,64,true,false,true,false,false,0,false,true><<<dim3(8, 32, 1), blk, 0, stream>>>(
                mid, mid, 1 << 30, w2_t + (long)(Ld + l) * FF * Cdim, d_b2 + l * Cdim, x_dec, x_dec,
                nullptr, nullptr, 1 << 30, FF, FF, FF, Cdim);
        else  // last layer: also emit bf16 copy for logits GEMM
            mgemm_k<64,64,64,true,false,true,false,false,0,true,true><<<dim3(8, 32, 1), blk, 0, stream>>>(
                mid, mid, 1 << 30, w2_t + (long)(Ld + l) * FF * Cdim, d_b2 + l * Cdim, x_dec, x_dec,
                xdb, nullptr, 1 << 30, FF, FF, FF, Cdim);
    }

    // ================= final logits (f32 out, 128x128, BK=32 for 3 blocks/CU) ==========
    mgemm_k<128,128,32,true,false,false,false,false,16,false,true><<<dim3(250, 16, 1), blk, 0, stream>>>(
        xdb, xdb, 1 << 30, outw_t, out_b, nullptr, out, nullptr, nullptr, 1 << 30,
        Cdim, Cdim, Cdim, Vn);
}

// Round 13
// 981.110 us; speedup vs baseline: 1.2822x; 1.0320x over previous
//
#include <hip/hip_runtime.h>
#include <hip/hip_bf16.h>
#include <math.h>

#define Cdim 512
#define Hn   8
#define HDim 64
#define Ld   4
#define Tn   1024
#define Bn   2
#define NTOK 2048   // B*T
#define FF   2048   // 4*C
#define Vn   32000

typedef __bf16 bf16_t;
typedef __bf16 bf16x8 __attribute__((ext_vector_type(8)));
typedef __bf16 bf16x4 __attribute__((ext_vector_type(4)));
typedef float  f32x4  __attribute__((ext_vector_type(4)));

// ---------------- layernorm: one wave per row, 4 rows/block, no barriers ----------------
__device__ __forceinline__ void ln_wave(const float* __restrict__ xr,
    const float* __restrict__ g, const float* __restrict__ bb,
    bf16_t* __restrict__ yr, int lane)
{
    f32x4 a = *(const f32x4*)&xr[lane * 8];
    f32x4 c = *(const f32x4*)&xr[lane * 8 + 4];
    float s = a[0] + a[1] + a[2] + a[3] + c[0] + c[1] + c[2] + c[3];
    #pragma unroll
    for (int o = 1; o < 64; o <<= 1) s += __shfl_xor(s, o, 64);
    float mean = s * (1.f / Cdim);
    float d[8], qv = 0.f;
    #pragma unroll
    for (int k = 0; k < 4; k++) { d[k] = a[k] - mean; d[4 + k] = c[k] - mean; }
    #pragma unroll
    for (int k = 0; k < 8; k++) qv += d[k] * d[k];
    #pragma unroll
    for (int o = 1; o < 64; o <<= 1) qv += __shfl_xor(qv, o, 64);
    float inv = rsqrtf(qv * (1.f / Cdim) + 1e-5f);
    f32x4 g0 = *(const f32x4*)&g[lane * 8],  g1 = *(const f32x4*)&g[lane * 8 + 4];
    f32x4 b0 = *(const f32x4*)&bb[lane * 8], b1 = *(const f32x4*)&bb[lane * 8 + 4];
    bf16x8 o;
    #pragma unroll
    for (int k = 0; k < 4; k++) {
        o[k]     = (bf16_t)(d[k]     * inv * g0[k] + b0[k]);
        o[4 + k] = (bf16_t)(d[4 + k] * inv * g1[k] + b1[k]);
    }
    *(bf16x8*)&yr[lane * 8] = o;
}

__global__ __launch_bounds__(256) void ln_k(const float* __restrict__ x,
    const float* __restrict__ g, const float* __restrict__ bb, bf16_t* __restrict__ y)
{
    int wid = threadIdx.x >> 6, lane = threadIdx.x & 63;
    int row = blockIdx.x * 4 + wid;
    ln_wave(x + (long)row * Cdim, g, bb, y + (long)row * Cdim, lane);
}

// two-source LN (cross-attention): rows < NTOK from x1->y1, else x2->y2 (same g,b)
__global__ __launch_bounds__(256) void ln2_k(const float* __restrict__ x1,
    const float* __restrict__ x2, const float* __restrict__ g,
    const float* __restrict__ bb, bf16_t* __restrict__ y1, bf16_t* __restrict__ y2)
{
    int wid = threadIdx.x >> 6, lane = threadIdx.x & 63;
    int row = blockIdx.x * 4 + wid;
    const float* x = (row < NTOK) ? x1 : x2;
    bf16_t*      y = (row < NTOK) ? y1 : y2;
    int r = row & (NTOK - 1);
    ln_wave(x + (long)r * Cdim, g, bb, y + (long)r * Cdim, lane);
}

// ---------------- fused embedding + first-layer LN (wave per row) ----------------
__global__ __launch_bounds__(256) void embed_ln_k(const int* __restrict__ inp,
    const float* __restrict__ tok, const float* __restrict__ pos,
    const float* __restrict__ g, const float* __restrict__ bb,
    float* __restrict__ x, bf16_t* __restrict__ y)
{
    int wid = threadIdx.x >> 6, lane = threadIdx.x & 63;
    int bt = blockIdx.x * 4 + wid;
    int t = bt & (Tn - 1);
    long toff = (long)inp[bt] * Cdim;
    f32x4 a = *(const f32x4*)&tok[toff + lane * 8];
    f32x4 c = *(const f32x4*)&tok[toff + lane * 8 + 4];
    f32x4 pa = *(const f32x4*)&pos[(long)t * Cdim + lane * 8];
    f32x4 pc = *(const f32x4*)&pos[(long)t * Cdim + lane * 8 + 4];
    a += pa; c += pc;
    float* xr = x + (long)bt * Cdim;
    *(f32x4*)&xr[lane * 8] = a;
    *(f32x4*)&xr[lane * 8 + 4] = c;
    float s = a[0] + a[1] + a[2] + a[3] + c[0] + c[1] + c[2] + c[3];
    #pragma unroll
    for (int o = 1; o < 64; o <<= 1) s += __shfl_xor(s, o, 64);
    float mean = s * (1.f / Cdim);
    float d[8], qv = 0.f;
    #pragma unroll
    for (int k = 0; k < 4; k++) { d[k] = a[k] - mean; d[4 + k] = c[k] - mean; }
    #pragma unroll
    for (int k = 0; k < 8; k++) qv += d[k] * d[k];
    #pragma unroll
    for (int o = 1; o < 64; o <<= 1) qv += __shfl_xor(qv, o, 64);
    float inv = rsqrtf(qv * (1.f / Cdim) + 1e-5f);
    f32x4 g0 = *(const f32x4*)&g[lane * 8],  g1 = *(const f32x4*)&g[lane * 8 + 4];
    f32x4 b0 = *(const f32x4*)&bb[lane * 8], b1 = *(const f32x4*)&bb[lane * 8 + 4];
    bf16x8 o;
    #pragma unroll
    for (int k = 0; k < 4; k++) {
        o[k]     = (bf16_t)(d[k]     * inv * g0[k] + b0[k]);
        o[4 + k] = (bf16_t)(d[4 + k] * inv * g1[k] + b1[k]);
    }
    *(bf16x8*)&y[(long)bt * Cdim + lane * 8] = o;
}

// ------- batched tiled transpose+convert: f32 [R,Cc] -> bf16 [Cc,R] over z sources/layers -------
struct Ptr3 { const float* p[3]; };
__global__ __launch_bounds__(256) void tcvt_b_k(Ptr3 srcs, bf16_t* __restrict__ dst,
    int R, int Cc, int lps, long dstStride)
{
    int z = blockIdx.z; int s = z / lps, l = z - s * lps;
    const float* in = srcs.p[s] + (long)l * R * Cc;
    bf16_t* op = dst + (long)z * dstStride;
    __shared__ float t[64][65];
    int r0 = blockIdx.y * 64, c0 = blockIdx.x * 64;
    int tx = threadIdx.x & 63, ty = threadIdx.x >> 6;
    #pragma unroll
    for (int i = 0; i < 16; i++)
        t[ty + i * 4][tx] = in[(long)(r0 + ty + i * 4) * Cc + c0 + tx];
    __syncthreads();
    #pragma unroll
    for (int i = 0; i < 16; i++) {
        int cc = ty + i * 4;
        op[(long)(c0 + cc) * R + r0 + tx] = (bf16_t)t[tx][cc];
    }
}

// ------- fused QKV weight prep: 9 (set,part) sources in one launch -------
struct QkvSrc { const float* p[9]; };
__global__ __launch_bounds__(256) void tcvt_qkv_k(QkvSrc srcs, bf16_t* __restrict__ outp)
{
    int z = blockIdx.z;
    int si = z >> 5, zb = (z >> 3) & 3, zh = z & 7;
    int set = si / 3, part = si - set * 3;
    const float* in = srcs.p[si] + (long)zb * (Hn * Cdim * HDim) + (long)zh * (Cdim * HDim);
    bf16_t* op = outp + ((long)set * Ld + zb) * (1536L * Cdim)
                      + (long)part * 512 * Cdim + (long)zh * 64 * Cdim;
    __shared__ float t[64][65];
    int r0 = blockIdx.y * 64;
    int tx = threadIdx.x & 63, ty = threadIdx.x >> 6;
    #pragma unroll
    for (int i = 0; i < 16; i++)
        t[ty + i * 4][tx] = in[(long)(r0 + ty + i * 4) * HDim + tx];
    __syncthreads();
    #pragma unroll
    for (int i = 0; i < 16; i++) {
        int cc = ty + i * 4;
        op[(long)cc * Cdim + r0 + tx] = (bf16_t)t[tx][cc];
    }
}

// ================= bf16 MFMA GEMM, double-buffered K pipeline =================
// WAVES=4 (2x2) or WAVES=8 (2x4, 512 thr, 256^2 tiles). Chunk-XOR LDS swizzle.
// Separate As0/As1/Bs0/Bs1 arrays so in-flight global_load_lds of the next
// tile provably doesn't alias current ds_reads -> stage latency hides.
// COAL epilogue bounce: dedicated cws for WAVES=4; aliased into As0 (post-
// barrier) for WAVES=8 to stay under the LDS cap.
template<int BM, int BN, int BK, int WAVES, bool BIAS, bool RELU, bool RES, bool OBF,
         bool VOUT, int SWZM, bool XOUT, bool COAL>
__global__ __launch_bounds__(WAVES * 64) void mgemm_k(
    const bf16_t* __restrict__ A, const bf16_t* __restrict__ A2, int aSplit,
    const bf16_t* __restrict__ Bt, const float* __restrict__ bias,
    const float* __restrict__ res, void* __restrict__ Cout,
    bf16_t* __restrict__ xout, bf16_t* __restrict__ vtout, int vSplit,
    int K, int lda, int ldb, int ldc)
{
    constexpr int NT  = WAVES * 64;
    constexpr int WC_ = WAVES / 2;          // wave grid: 2 x WC_
    constexpr int BNW = BN / WC_;           // per-wave N extent
    constexpr int MR = BM / 32;             // (BM/2)/16
    constexpr int NR = BNW / 16;
    constexpr int KK = BK / 32;
    constexpr int LPR = BK / 8;             // 16B chunks per LDS row
    constexpr int RW  = 64 / LPR;           // rows staged per wave per pass
    constexpr int RPASS = NT / LPR;         // rows staged per pass (all waves)
    constexpr bool ALIAS = (WAVES == 8);
    __shared__ bf16_t As0[BM * BK];
    __shared__ bf16_t As1[BM * BK];
    __shared__ bf16_t Bs0[BN * BK];
    __shared__ bf16_t Bs1[BN * BK];
    __shared__ float cws[(COAL && !ALIAS) ? WAVES * 16 * 36 : 1];

    int tid = threadIdx.x;
    int wv = tid >> 6, lane = tid & 63;
    int bm, bn;
    if constexpr (SWZM > 0) {
        int lin = blockIdx.y * gridDim.x + blockIdx.x;
        int tot = gridDim.x * gridDim.y;
        int chunk = tot >> 3;
        int e = (lin & 7) * chunk + (lin >> 3);
        bm = (e % SWZM) * BM;
        bn = (e / SWZM) * BN;
    } else {
        bm = blockIdx.y * BM; bn = blockIdx.x * BN;
    }
    const bf16_t* Ab = (bn < aSplit) ? A : A2;
    int wr = wv / WC_, wc = wv % WC_;

    f32x4 acc[MR][NR];
    #pragma unroll
    for (int i = 0; i < MR; i++)
        #pragma unroll
        for (int j = 0; j < NR; j++)
            acc[i][j] = (f32x4){0.f, 0.f, 0.f, 0.f};

    const int sr  = lane / LPR;
    const int sc8 = ((lane % LPR) ^ (sr & (LPR - 1))) * 8;
    const int r16 = lane & 15, g4 = lane >> 4;

    auto stage = [&](int k0, bf16_t (&Asb)[BM * BK], bf16_t (&Bsb)[BN * BK]) {
        #pragma unroll
        for (int p = 0; p < BM / RPASS; p++) {
            int rb = p * RPASS + wv * RW;
            const bf16_t* g = Ab + (long)(bm + rb + sr) * lda + (k0 + sc8);
            __builtin_amdgcn_global_load_lds(
                (const __attribute__((address_space(1))) void*)g,
                (__attribute__((address_space(3))) void*)&Asb[rb * BK],
                16, 0, 0);
        }
        #pragma unroll
        for (int p = 0; p < BN / RPASS; p++) {
            int rb = p * RPASS + wv * RW;
            const bf16_t* g = Bt + (long)(bn + rb + sr) * ldb + (k0 + sc8);
            __builtin_amdgcn_global_load_lds(
                (const __attribute__((address_space(1))) void*)g,
                (__attribute__((address_space(3))) void*)&Bsb[rb * BK],
                16, 0, 0);
        }
    };
    auto compute = [&](bf16_t (&Asb)[BM * BK], bf16_t (&Bsb)[BN * BK]) {
        #pragma unroll
        for (int kk = 0; kk < KK; kk++) {
            bf16x8 bkk[NR];
            #pragma unroll
            for (int j = 0; j < NR; j++) {
                int row = wc * BNW + j * 16 + r16;
                bkk[j] = *(const bf16x8*)&Bsb[row * BK + (((kk * 4 + g4) ^ (row & (LPR - 1))) * 8)];
            }
            #pragma unroll
            for (int i = 0; i < MR; i++) {
                int row = wr * (BM / 2) + i * 16 + r16;
                bf16x8 a = *(const bf16x8*)&Asb[row * BK + (((kk * 4 + g4) ^ (row & (LPR - 1))) * 8)];
                #pragma unroll
                for (int j = 0; j < NR; j++)
                    acc[i][j] = __builtin_amdgcn_mfma_f32_16x16x32_bf16(a, bkk[j], acc[i][j], 0, 0, 0);
            }
        }
    };

    int nIt = K / BK;
    stage(0, As0, Bs0);
    for (int it = 0; it < nIt; it += 2) {
        __syncthreads();                               // As0/Bs0 staged; prior reads done
        if (it + 1 < nIt) stage((it + 1) * BK, As1, Bs1);
        compute(As0, Bs0);
        __syncthreads();                               // As1/Bs1 staged; As0 reads done
        if (it + 2 < nIt) stage((it + 2) * BK, As0, Bs0);
        if (it + 1 < nIt) compute(As1, Bs1);
    }

    if constexpr (COAL) {
        __syncthreads();                               // safe to reuse LDS for bounce
        float* cb = ALIAS ? (float*)As0 : cws;
        // ---- coalesced epilogue via per-wave LDS bounce ----
        #pragma unroll
        for (int i = 0; i < MR; i++) {
            int gr0 = bm + wr * (BM / 2) + i * 16;
            #pragma unroll
            for (int hh = 0; hh < NR / 2; hh++) {
                #pragma unroll
                for (int jj = 0; jj < 2; jj++) {
                    int j = hh * 2 + jj;
                    int gc = bn + wc * BNW + j * 16 + r16;
                    float bv = BIAS ? bias[gc] : 0.f;
                    #pragma unroll
                    for (int q = 0; q < 4; q++) {
                        float v = acc[i][j][q];
                        if (BIAS) v += bv;
                        if (RELU) v = fmaxf(v, 0.f);
                        cb[(wv * 16 + g4 * 4 + q) * 36 + jj * 16 + r16] = v;
                    }
                }
                int gcb = bn + wc * BNW + hh * 32;
                if constexpr (OBF) {
                    int row = lane >> 2, c8 = (lane & 3) * 8;
                    f32x4 v0 = *(f32x4*)&cb[(wv * 16 + row) * 36 + c8];
                    f32x4 v1 = *(f32x4*)&cb[(wv * 16 + row) * 36 + c8 + 4];
                    long oidx = (long)(gr0 + row) * ldc + gcb + c8;
                    bf16x8 o;
                    #pragma unroll
                    for (int k = 0; k < 4; k++) { o[k] = (bf16_t)v0[k]; o[4 + k] = (bf16_t)v1[k]; }
                    *(bf16x8*)&((bf16_t*)Cout)[oidx] = o;
                } else {
                    #pragma unroll
                    for (int ps = 0; ps < 2; ps++) {
                        int row = (lane >> 3) + 8 * ps, c4 = (lane & 7) * 4;
                        f32x4 v = *(f32x4*)&cb[(wv * 16 + row) * 36 + c4];
                        long oidx = (long)(gr0 + row) * ldc + gcb + c4;
                        if (RES) v += *(const f32x4*)&res[oidx];
                        *(f32x4*)&((float*)Cout)[oidx] = v;
                        if (XOUT) {
                            bf16x4 o;
                            #pragma unroll
                            for (int k = 0; k < 4; k++) o[k] = (bf16_t)v[k];
                            *(bf16x4*)&xout[oidx] = o;
                        }
                    }
                }
            }
        }
    } else {
        // ---- scalar epilogue (VOUT scatter path) ----
        #pragma unroll
        for (int i = 0; i < MR; i++) {
            #pragma unroll
            for (int j = 0; j < NR; j++) {
                int gr = bm + wr * (BM / 2) + i * 16 + g4 * 4;
                int gc = bn + wc * BNW + j * 16 + r16;
                float bv = BIAS ? bias[gc] : 0.f;
                #pragma unroll
                for (int q = 0; q < 4; q++) {
                    float v = acc[i][j][q];
                    if (BIAS) v += bv;
                    if (RELU) v = fmaxf(v, 0.f);
                    if (VOUT && gc >= vSplit) {
                        int row = gr + q;
                        int b = row >> 10, t = row & (Tn - 1);
                        vtout[((long)b * 512 + (gc - vSplit)) * Tn + t] = (bf16_t)v;
                    } else {
                        long oidx = (long)(gr + q) * ldc + gc;
                        if (RES)  v += res[oidx];
                        if (OBF) ((bf16_t*)Cout)[oidx] = (bf16_t)v;
                        else     ((float*) Cout)[oidx] = v;
                        if (XOUT) xout[oidx] = (bf16_t)v;
                    }
                }
            }
        }
    }
}

// ================= fused flash attention (8 waves, KV-split, dbuf LDS, 1 barrier/iter) =========
template<bool CAUSAL, bool HASMASK>
__global__ __launch_bounds__(512, 2) void flash_k(
    const bf16_t* __restrict__ qkv, const bf16_t* __restrict__ vt,
    const int* __restrict__ mask, bf16_t* __restrict__ ao)
{
    __shared__ bf16_t Kl[2][2][64][72];
    __shared__ bf16_t Vl[2][2][64][72];
    __shared__ bf16_t Pl[8][16][72];

    int qt = blockIdx.x, bh = blockIdx.y;
    int b = bh >> 3, h = bh & 7;
    int tid = threadIdx.x, wv = tid >> 6, lane = tid & 63;
    int wg = wv >> 2, wq4 = wv & 3;
    int r16 = lane & 15, g4 = lane >> 4;
    int gtid = tid & 255;

    const bf16_t* qb = qkv + ((long)(b * Tn + qt * 64 + wq4 * 16 + r16)) * 1536 + h * 64;
    bf16x8 aq0 = *(const bf16x8*)&qb[g4 * 8];
    bf16x8 aq1 = *(const bf16x8*)&qb[32 + g4 * 8];

    f32x4 acc[4];
    #pragma unroll
    for (int j = 0; j < 4; j++) acc[j] = (f32x4){0.f, 0.f, 0.f, 0.f};
    float m_[4], l_[4];
    #pragma unroll
    for (int q = 0; q < 4; q++) { m_[q] = -1e30f; l_[q] = 0.f; }

    int lastT = CAUSAL ? qt : (Tn / 64 - 1);
    int niter = CAUSAL ? (qt / 2 + 1) : (Tn / 128);
    int krow = gtid >> 3, kcol = (gtid & 7) * 8;

    bf16x8 kr[2], vr[2];
    int mv = 0;
    {
        int t0 = wg;
        if (t0 <= lastT) {
            int s0 = t0 * 64;
            #pragma unroll
            for (int i = 0; i < 2; i++)
                kr[i] = *(const bf16x8*)&qkv[((long)(b * Tn + s0 + krow + i * 32)) * 1536 + 512 + h * 64 + kcol];
            #pragma unroll
            for (int i = 0; i < 2; i++)
                vr[i] = *(const bf16x8*)&vt[((long)(bh * 64 + krow + i * 32)) * Tn + s0 + kcol];
            if (HASMASK) mv = mask[b * Tn + s0 + lane];
        }
    }

    for (int it = 0; it < niter; it++) {
        int cur = it & 1;
        int t = 2 * it + wg;
        bool active = t <= lastT;
        if (active) {
            #pragma unroll
            for (int i = 0; i < 2; i++) *(bf16x8*)&Kl[cur][wg][krow + i * 32][kcol] = kr[i];
            #pragma unroll
            for (int i = 0; i < 2; i++) *(bf16x8*)&Vl[cur][wg][krow + i * 32][kcol] = vr[i];
        }
        int mv_use = mv;
        __syncthreads();
        int tn = t + 2;
        if (it + 1 < niter && tn <= lastT) {
            int sn = tn * 64;
            #pragma unroll
            for (int i = 0; i < 2; i++)
                kr[i] = *(const bf16x8*)&qkv[((long)(b * Tn + sn + krow + i * 32)) * 1536 + 512 + h * 64 + kcol];
            #pragma unroll
            for (int i = 0; i < 2; i++)
                vr[i] = *(const bf16x8*)&vt[((long)(bh * 64 + krow + i * 32)) * Tn + sn + kcol];
            if (HASMASK) mv = mask[b * Tn + sn + lane];
        }
        if (!active) continue;

        f32x4 scv[4];
        __builtin_amdgcn_s_setprio(1);
        #pragma unroll
        for (int j = 0; j < 4; j++) {
            scv[j] = (f32x4){0.f, 0.f, 0.f, 0.f};
            bf16x8 bk0 = *(const bf16x8*)&Kl[cur][wg][j * 16 + r16][g4 * 8];
            bf16x8 bk1 = *(const bf16x8*)&Kl[cur][wg][j * 16 + r16][32 + g4 * 8];
            scv[j] = __builtin_amdgcn_mfma_f32_16x16x32_bf16(aq0, bk0, scv[j], 0, 0, 0);
            scv[j] = __builtin_amdgcn_mfma_f32_16x16x32_bf16(aq1, bk1, scv[j], 0, 0, 0);
        }
        __builtin_amdgcn_s_setprio(0);

        bool diag = CAUSAL && (t == qt);
        #pragma unroll
        for (int j = 0; j < 4; j++) {
            int col = j * 16 + r16;
            int mm = 1;
            if (HASMASK) mm = __shfl(mv_use, col, 64);
            #pragma unroll
            for (int q = 0; q < 4; q++) {
                float v = scv[j][q] * 0.125f;
                if (diag && col > wq4 * 16 + g4 * 4 + q) v = -1e30f;
                if (HASMASK && mm == 0) v = -1e30f;
                scv[j][q] = v;
            }
        }

        float pmax[4];
        #pragma unroll
        for (int q = 0; q < 4; q++) {
            float v = fmaxf(fmaxf(scv[0][q], scv[1][q]), fmaxf(scv[2][q], scv[3][q]));
            v = fmaxf(v, __shfl_xor(v, 1, 64));
            v = fmaxf(v, __shfl_xor(v, 2, 64));
            v = fmaxf(v, __shfl_xor(v, 4, 64));
            v = fmaxf(v, __shfl_xor(v, 8, 64));
            pmax[q] = v;
        }
        bool skip = __all(pmax[0] <= m_[0] + 8.f && pmax[1] <= m_[1] + 8.f &&
                          pmax[2] <= m_[2] + 8.f && pmax[3] <= m_[3] + 8.f);
        if (!skip) {
            #pragma unroll
            for (int q = 0; q < 4; q++) {
                float mnew = fmaxf(m_[q], pmax[q]);
                float rf = __expf(m_[q] - mnew);
                l_[q] *= rf;
                #pragma unroll
                for (int j = 0; j < 4; j++) acc[j][q] *= rf;
                m_[q] = mnew;
            }
        }
        #pragma unroll
        for (int q = 0; q < 4; q++) {
            float rs = 0.f;
            #pragma unroll
            for (int j = 0; j < 4; j++) {
                float pv = __expf(scv[j][q] - m_[q]);
                scv[j][q] = pv;
                rs += pv;
            }
            rs += __shfl_xor(rs, 1, 64);
            rs += __shfl_xor(rs, 2, 64);
            rs += __shfl_xor(rs, 4, 64);
            rs += __shfl_xor(rs, 8, 64);
            l_[q] += rs;
        }

        #pragma unroll
        for (int j = 0; j < 4; j++)
            #pragma unroll
            for (int q = 0; q < 4; q++)
                Pl[wv][g4 * 4 + q][j * 16 + r16] = (bf16_t)scv[j][q];
        asm volatile("s_waitcnt lgkmcnt(0)" ::: "memory");
        __builtin_amdgcn_sched_barrier(0);

        __builtin_amdgcn_s_setprio(1);
        #pragma unroll
        for (int c = 0; c < 2; c++) {
            bf16x8 pa = *(const bf16x8*)&Pl[wv][r16][c * 32 + g4 * 8];
            #pragma unroll
            for (int j = 0; j < 4; j++) {
                bf16x8 bv = *(const bf16x8*)&Vl[cur][wg][j * 16 + r16][c * 32 + g4 * 8];
                acc[j] = __builtin_amdgcn_mfma_f32_16x16x32_bf16(pa, bv, acc[j], 0, 0, 0);
            }
        }
        __builtin_amdgcn_s_setprio(0);
    }

    float* accS = (float*)&Kl[0][0][0][0];
    float* mlS  = accS + 64 * 64;
    __syncthreads();
    if (wg == 1) {
        #pragma unroll
        for (int j = 0; j < 4; j++)
            #pragma unroll
            for (int q = 0; q < 4; q++)
                accS[(wq4 * 16 + g4 * 4 + q) * 64 + j * 16 + r16] = acc[j][q];
        if (r16 == 0)
            #pragma unroll
            for (int q = 0; q < 4; q++) {
                mlS[(wq4 * 16 + g4 * 4 + q) * 2 + 0] = m_[q];
                mlS[(wq4 * 16 + g4 * 4 + q) * 2 + 1] = l_[q];
            }
    }
    __syncthreads();
    if (wg == 0) {
        bf16_t* aob = ao + ((long)(b * Tn + qt * 64 + wq4 * 16 + g4 * 4)) * Cdim + h * 64;
        #pragma unroll
        for (int q = 0; q < 4; q++) {
            int row = wq4 * 16 + g4 * 4 + q;
            float mB = mlS[row * 2], lB = mlS[row * 2 + 1];
            float mS = fmaxf(m_[q], mB);
            float fA = __expf(m_[q] - mS), fB = __expf(mB - mS);
            float lS = l_[q] * fA + lB * fB;
            float inv = 1.f / lS;
            #pragma unroll
            for (int j = 0; j < 4; j++) {
                float o = (acc[j][q] * fA + accS[row * 64 + j * 16 + r16] * fB) * inv;
                aob[(long)q * Cdim + j * 16 + r16] = (bf16_t)o;
            }
        }
    }
}

// ================================ host orchestration ================================
static void run_attn(hipStream_t stream, const bf16_t* hq, const bf16_t* hkv,
    const bf16_t* wqkv, const float* bo, const bf16_t* wo_t,
    float* xres, const int* mask, bool causal,
    bf16_t* qkv, bf16_t* vt, bf16_t* ao)
{
    dim3 blk(256);
    // fused qkv projection: N=1536 (cols<512 read hq, else hkv); v-part -> vt
    mgemm_k<64,128,64,4,false,false,false,true,true,0,false,false><<<dim3(12, 32, 1), blk, 0, stream>>>(
        hq, hkv, 512, wqkv, nullptr, nullptr, qkv, nullptr, vt, 1024,
        Cdim, Cdim, Cdim, 1536);
    if (causal)
        flash_k<true,false><<<dim3(Tn / 64, Bn * Hn), dim3(512), 0, stream>>>(qkv, vt, nullptr, ao);
    else
        flash_k<false,true><<<dim3(Tn / 64, Bn * Hn), dim3(512), 0, stream>>>(qkv, vt, mask, ao);
    // out projection + bias + residual (f32, in place on xres) — coalesced epilogue
    mgemm_k<64,64,64,4,true,false,true,false,false,0,false,true><<<dim3(8, 32, 1), blk, 0, stream>>>(
        ao, ao, 1 << 30, wo_t, bo, xres, xres, nullptr, nullptr, 1 << 30,
        Cdim, Cdim, Cdim, Cdim);
}

extern "C" void kernel_launch(void* const* d_in, const int* in_sizes, int n_in,
                              void* d_out, int out_size, void* d_ws, size_t ws_size,
                              hipStream_t stream)
{
    (void)in_sizes; (void)n_in; (void)out_size; (void)ws_size;
    const int*   enc_inp  = (const int*)d_in[0];
    const int*   dec_inp  = (const int*)d_in[1];
    const int*   enc_mask = (const int*)d_in[2];
    const float* tok_emb  = (const float*)d_in[3];
    const float* pos_emb  = (const float*)d_in[4];
    const float* e_wq  = (const float*)d_in[5];
    const float* e_wk  = (const float*)d_in[6];
    const float* e_wv  = (const float*)d_in[7];
    const float* e_wo  = (const float*)d_in[8];
    const float* e_bo  = (const float*)d_in[9];
    const float* dsa_wq = (const float*)d_in[10];
    const float* dsa_wk = (const float*)d_in[11];
    const float* dsa_wv = (const float*)d_in[12];
    const float* dsa_wo = (const float*)d_in[13];
    const float* dsa_bo = (const float*)d_in[14];
    const float* dca_wq = (const float*)d_in[15];
    const float* dca_wk = (const float*)d_in[16];
    const float* dca_wv = (const float*)d_in[17];
    const float* dca_wo = (const float*)d_in[18];
    const float* dca_bo = (const float*)d_in[19];
    const float* e_ln1_g = (const float*)d_in[20];
    const float* e_ln1_b = (const float*)d_in[21];
    const float* e_ln2_g = (const float*)d_in[22];
    const float* e_ln2_b = (const float*)d_in[23];
    const float* d_ln1_g = (const float*)d_in[24];
    const float* d_ln1_b = (const float*)d_in[25];
    const float* d_ln2_g = (const float*)d_in[26];
    const float* d_ln2_b = (const float*)d_in[27];
    const float* d_ln3_g = (const float*)d_in[28];
    const float* d_ln3_b = (const float*)d_in[29];
    const float* e_w1 = (const float*)d_in[30];
    const float* e_b1 = (const float*)d_in[31];
    const float* e_w2 = (const float*)d_in[32];
    const float* e_b2 = (const float*)d_in[33];
    const float* d_w1 = (const float*)d_in[34];
    const float* d_b1 = (const float*)d_in[35];
    const float* d_w2 = (const float*)d_in[36];
    const float* d_b2 = (const float*)d_in[37];
    const float* out_w = (const float*)d_in[38];
    const float* out_b = (const float*)d_in[39];
    float* out = (float*)d_out;

    // -------- workspace carve (bytes) --------
    char* p = (char*)d_ws;
    auto takeB = [&](size_t bytes) { char* r = p; p += (bytes + 255) & ~(size_t)255; return r; };
    float*  x_enc = (float*)takeB(1048576ull * 4);
    float*  x_dec = (float*)takeB(1048576ull * 4);
    bf16_t* h     = (bf16_t*)takeB(1048576ull * 2);
    bf16_t* hk    = (bf16_t*)takeB(1048576ull * 2);
    bf16_t* qkv   = (bf16_t*)takeB(3145728ull * 2);
    bf16_t* vt    = (bf16_t*)takeB(1048576ull * 2);
    bf16_t* ao    = (bf16_t*)takeB(1048576ull * 2);
    bf16_t* xdb   = (bf16_t*)takeB(1048576ull * 2);
    bf16_t* mid   = (bf16_t*)takeB(4194304ull * 2);
    bf16_t* wqkv_t = (bf16_t*)takeB(12ull * 786432 * 2);
    bf16_t* wo_t   = (bf16_t*)takeB(12ull * 262144 * 2);
    bf16_t* w1_t   = (bf16_t*)takeB(8ull * 1048576 * 2);
    bf16_t* w2_t   = (bf16_t*)takeB(8ull * 1048576 * 2);
    bf16_t* outw_t = (bf16_t*)takeB(16384000ull * 2);

    dim3 blk(256);
    const long LQKV = 1536L * Cdim;

    // ================= weight prep (5 launches) =================
    QkvSrc qs;
    qs.p[0] = e_wq;   qs.p[1] = e_wk;   qs.p[2] = e_wv;
    qs.p[3] = dsa_wq; qs.p[4] = dsa_wk; qs.p[5] = dsa_wv;
    qs.p[6] = dca_wq; qs.p[7] = dca_wk; qs.p[8] = dca_wv;
    tcvt_qkv_k<<<dim3(1, 8, 288), blk, 0, stream>>>(qs, wqkv_t);
    Ptr3 pw;
    pw.p[0] = e_wo; pw.p[1] = dsa_wo; pw.p[2] = dca_wo;
    tcvt_b_k<<<dim3(8, 8, 12), blk, 0, stream>>>(pw, wo_t, Cdim, Cdim, 4, (long)Cdim * Cdim);
    pw.p[0] = e_w1; pw.p[1] = d_w1; pw.p[2] = nullptr;
    tcvt_b_k<<<dim3(32, 8, 8), blk, 0, stream>>>(pw, w1_t, Cdim, FF, 4, (long)Cdim * FF);
    pw.p[0] = e_w2; pw.p[1] = d_w2; pw.p[2] = nullptr;
    tcvt_b_k<<<dim3(8, 32, 8), blk, 0, stream>>>(pw, w2_t, FF, Cdim, 4, (long)FF * Cdim);
    pw.p[0] = out_w; pw.p[1] = nullptr; pw.p[2] = nullptr;
    tcvt_b_k<<<dim3(500, 8, 1), blk, 0, stream>>>(pw, outw_t, Cdim, Vn, 1, 0);

    // ================= encoder =================
    embed_ln_k<<<NTOK / 4, blk, 0, stream>>>(enc_inp, tok_emb, pos_emb, e_ln1_g, e_ln1_b, x_enc, h);
    for (int l = 0; l < Ld; l++) {
        if (l) ln_k<<<NTOK / 4, blk, 0, stream>>>(x_enc, e_ln1_g + l * Cdim, e_ln1_b + l * Cdim, h);
        run_attn(stream, h, h,
                 wqkv_t + (long)l * LQKV, e_bo + l * Cdim, wo_t + (long)l * Cdim * Cdim,
                 x_enc, enc_mask, /*causal=*/false, qkv, vt, ao);
        ln_k<<<NTOK / 4, blk, 0, stream>>>(x_enc, e_ln2_g + l * Cdim, e_ln2_b + l * Cdim, h);
        mgemm_k<128,128,64,4,true,true,false,true,false,0,false,true><<<dim3(16, 16, 1), blk, 0, stream>>>(
            h, h, 1 << 30, w1_t + (long)l * Cdim * FF, e_b1 + l * FF, nullptr, mid,
            nullptr, nullptr, 1 << 30, Cdim, Cdim, Cdim, FF);
        mgemm_k<64,64,64,4,true,false,true,false,false,0,false,true><<<dim3(8, 32, 1), blk, 0, stream>>>(
            mid, mid, 1 << 30, w2_t + (long)l * FF * Cdim, e_b2 + l * Cdim, x_enc, x_enc,
            nullptr, nullptr, 1 << 30, FF, FF, FF, Cdim);
    }
    // x_enc now holds enc_out

    // ================= decoder =================
    embed_ln_k<<<NTOK / 4, blk, 0, stream>>>(dec_inp, tok_emb, pos_emb, d_ln1_g, d_ln1_b, x_dec, h);
    for (int l = 0; l < Ld; l++) {
        // causal self-attention
        if (l) ln_k<<<NTOK / 4, blk, 0, stream>>>(x_dec, d_ln1_g + l * Cdim, d_ln1_b + l * Cdim, h);
        run_attn(stream, h, h,
                 wqkv_t + (long)(Ld + l) * LQKV, dsa_bo + l * Cdim,
                 wo_t + (long)(Ld + l) * Cdim * Cdim,
                 x_dec, nullptr, /*causal=*/true, qkv, vt, ao);
        // cross-attention (same LN applied to x and enc_out) — one fused launch
        ln2_k<<<2 * NTOK / 4, blk, 0, stream>>>(x_dec, x_enc,
            d_ln2_g + l * Cdim, d_ln2_b + l * Cdim, h, hk);
        run_attn(stream, h, hk,
                 wqkv_t + (long)(2 * Ld + l) * LQKV, dca_bo + l * Cdim,
                 wo_t + (long)(2 * Ld + l) * Cdim * Cdim,
                 x_dec, enc_mask, /*causal=*/false, qkv, vt, ao);
        // FFN
        ln_k<<<NTOK / 4, blk, 0, stream>>>(x_dec, d_ln3_g + l * Cdim, d_ln3_b + l * Cdim, h);
        mgemm_k<128,128,64,4,true,true,false,true,false,0,false,true><<<dim3(16, 16, 1), blk, 0, stream>>>(
            h, h, 1 << 30, w1_t + (long)(Ld + l) * Cdim * FF, d_b1 + l * FF, nullptr, mid,
            nullptr, nullptr, 1 << 30, Cdim, Cdim, Cdim, FF);
        if (l < Ld - 1)
            mgemm_k<64,64,64,4,true,false,true,false,false,0,false,true><<<dim3(8, 32, 1), blk, 0, stream>>>(
                mid, mid, 1 << 30, w2_t + (long)(Ld + l) * FF * Cdim, d_b2 + l * Cdim, x_dec, x_dec,
                nullptr, nullptr, 1 << 30, FF, FF, FF, Cdim);
        else  // last layer: also emit bf16 copy for logits GEMM
            mgemm_k<64,64,64,4,true,false,true,false,false,0,true,true><<<dim3(8, 32, 1), blk, 0, stream>>>(
                mid, mid, 1 << 30, w2_t + (long)(Ld + l) * FF * Cdim, d_b2 + l * Cdim, x_dec, x_dec,
                xdb, nullptr, 1 << 30, FF, FF, FF, Cdim);
    }

    // ================= final logits (f32 out, 256x256 tile, 8 waves, XCD-swizzled) ==========
    mgemm_k<256,256,64,8,true,false,false,false,false,8,false,true><<<dim3(125, 8, 1), dim3(512), 0, stream>>>(
        xdb, xdb, 1 << 30, outw_t, out_b, nullptr, out, nullptr, nullptr, 1 << 30,
        Cdim, Cdim, Cdim, Vn);
}

// Round 14
// 939.917 us; speedup vs baseline: 1.3384x; 1.0438x over previous
//
#include <hip/hip_runtime.h>
#include <hip/hip_bf16.h>
#include <math.h>

#define Cdim 512
#define Hn   8
#define HDim 64
#define Ld   4
#define Tn   1024
#define Bn   2
#define NTOK 2048   // B*T
#define FF   2048   // 4*C
#define Vn   32000

typedef __bf16 bf16_t;
typedef __bf16 bf16x8 __attribute__((ext_vector_type(8)));
typedef __bf16 bf16x4 __attribute__((ext_vector_type(4)));
typedef float  f32x4  __attribute__((ext_vector_type(4)));

// ---------------- layernorm: one wave per row, 4 rows/block, no barriers ----------------
__device__ __forceinline__ void ln_wave(const float* __restrict__ xr,
    const float* __restrict__ g, const float* __restrict__ bb,
    bf16_t* __restrict__ yr, int lane)
{
    f32x4 a = *(const f32x4*)&xr[lane * 8];
    f32x4 c = *(const f32x4*)&xr[lane * 8 + 4];
    float s = a[0] + a[1] + a[2] + a[3] + c[0] + c[1] + c[2] + c[3];
    #pragma unroll
    for (int o = 1; o < 64; o <<= 1) s += __shfl_xor(s, o, 64);
    float mean = s * (1.f / Cdim);
    float d[8], qv = 0.f;
    #pragma unroll
    for (int k = 0; k < 4; k++) { d[k] = a[k] - mean; d[4 + k] = c[k] - mean; }
    #pragma unroll
    for (int k = 0; k < 8; k++) qv += d[k] * d[k];
    #pragma unroll
    for (int o = 1; o < 64; o <<= 1) qv += __shfl_xor(qv, o, 64);
    float inv = rsqrtf(qv * (1.f / Cdim) + 1e-5f);
    f32x4 g0 = *(const f32x4*)&g[lane * 8],  g1 = *(const f32x4*)&g[lane * 8 + 4];
    f32x4 b0 = *(const f32x4*)&bb[lane * 8], b1 = *(const f32x4*)&bb[lane * 8 + 4];
    bf16x8 o;
    #pragma unroll
    for (int k = 0; k < 4; k++) {
        o[k]     = (bf16_t)(d[k]     * inv * g0[k] + b0[k]);
        o[4 + k] = (bf16_t)(d[4 + k] * inv * g1[k] + b1[k]);
    }
    *(bf16x8*)&yr[lane * 8] = o;
}

__global__ __launch_bounds__(256) void ln_k(const float* __restrict__ x,
    const float* __restrict__ g, const float* __restrict__ bb, bf16_t* __restrict__ y)
{
    int wid = threadIdx.x >> 6, lane = threadIdx.x & 63;
    int row = blockIdx.x * 4 + wid;
    ln_wave(x + (long)row * Cdim, g, bb, y + (long)row * Cdim, lane);
}

// two-source LN (cross-attention): rows < NTOK from x1->y1, else x2->y2 (same g,b)
__global__ __launch_bounds__(256) void ln2_k(const float* __restrict__ x1,
    const float* __restrict__ x2, const float* __restrict__ g,
    const float* __restrict__ bb, bf16_t* __restrict__ y1, bf16_t* __restrict__ y2)
{
    int wid = threadIdx.x >> 6, lane = threadIdx.x & 63;
    int row = blockIdx.x * 4 + wid;
    const float* x = (row < NTOK) ? x1 : x2;
    bf16_t*      y = (row < NTOK) ? y1 : y2;
    int r = row & (NTOK - 1);
    ln_wave(x + (long)r * Cdim, g, bb, y + (long)r * Cdim, lane);
}

// ---------------- fused embedding + first-layer LN (wave per row) ----------------
__global__ __launch_bounds__(256) void embed_ln_k(const int* __restrict__ inp,
    const float* __restrict__ tok, const float* __restrict__ pos,
    const float* __restrict__ g, const float* __restrict__ bb,
    float* __restrict__ x, bf16_t* __restrict__ y)
{
    int wid = threadIdx.x >> 6, lane = threadIdx.x & 63;
    int bt = blockIdx.x * 4 + wid;
    int t = bt & (Tn - 1);
    long toff = (long)inp[bt] * Cdim;
    f32x4 a = *(const f32x4*)&tok[toff + lane * 8];
    f32x4 c = *(const f32x4*)&tok[toff + lane * 8 + 4];
    f32x4 pa = *(const f32x4*)&pos[(long)t * Cdim + lane * 8];
    f32x4 pc = *(const f32x4*)&pos[(long)t * Cdim + lane * 8 + 4];
    a += pa; c += pc;
    float* xr = x + (long)bt * Cdim;
    *(f32x4*)&xr[lane * 8] = a;
    *(f32x4*)&xr[lane * 8 + 4] = c;
    float s = a[0] + a[1] + a[2] + a[3] + c[0] + c[1] + c[2] + c[3];
    #pragma unroll
    for (int o = 1; o < 64; o <<= 1) s += __shfl_xor(s, o, 64);
    float mean = s * (1.f / Cdim);
    float d[8], qv = 0.f;
    #pragma unroll
    for (int k = 0; k < 4; k++) { d[k] = a[k] - mean; d[4 + k] = c[k] - mean; }
    #pragma unroll
    for (int k = 0; k < 8; k++) qv += d[k] * d[k];
    #pragma unroll
    for (int o = 1; o < 64; o <<= 1) qv += __shfl_xor(qv, o, 64);
    float inv = rsqrtf(qv * (1.f / Cdim) + 1e-5f);
    f32x4 g0 = *(const f32x4*)&g[lane * 8],  g1 = *(const f32x4*)&g[lane * 8 + 4];
    f32x4 b0 = *(const f32x4*)&bb[lane * 8], b1 = *(const f32x4*)&bb[lane * 8 + 4];
    bf16x8 o;
    #pragma unroll
    for (int k = 0; k < 4; k++) {
        o[k]     = (bf16_t)(d[k]     * inv * g0[k] + b0[k]);
        o[4 + k] = (bf16_t)(d[4 + k] * inv * g1[k] + b1[k]);
    }
    *(bf16x8*)&y[(long)bt * Cdim + lane * 8] = o;
}

// ------- batched tiled transpose+convert: f32 [R,Cc] -> bf16 [Cc,R] over z sources/layers -------
struct Ptr3 { const float* p[3]; };
__global__ __launch_bounds__(256) void tcvt_b_k(Ptr3 srcs, bf16_t* __restrict__ dst,
    int R, int Cc, int lps, long dstStride)
{
    int z = blockIdx.z; int s = z / lps, l = z - s * lps;
    const float* in = srcs.p[s] + (long)l * R * Cc;
    bf16_t* op = dst + (long)z * dstStride;
    __shared__ float t[64][65];
    int r0 = blockIdx.y * 64, c0 = blockIdx.x * 64;
    int tx = threadIdx.x & 63, ty = threadIdx.x >> 6;
    #pragma unroll
    for (int i = 0; i < 16; i++)
        t[ty + i * 4][tx] = in[(long)(r0 + ty + i * 4) * Cc + c0 + tx];
    __syncthreads();
    #pragma unroll
    for (int i = 0; i < 16; i++) {
        int cc = ty + i * 4;
        op[(long)(c0 + cc) * R + r0 + tx] = (bf16_t)t[tx][cc];
    }
}

// ------- fused QKV weight prep: 9 (set,part) sources in one launch -------
struct QkvSrc { const float* p[9]; };
__global__ __launch_bounds__(256) void tcvt_qkv_k(QkvSrc srcs, bf16_t* __restrict__ outp)
{
    int z = blockIdx.z;
    int si = z >> 5, zb = (z >> 3) & 3, zh = z & 7;
    int set = si / 3, part = si - set * 3;
    const float* in = srcs.p[si] + (long)zb * (Hn * Cdim * HDim) + (long)zh * (Cdim * HDim);
    bf16_t* op = outp + ((long)set * Ld + zb) * (1536L * Cdim)
                      + (long)part * 512 * Cdim + (long)zh * 64 * Cdim;
    __shared__ float t[64][65];
    int r0 = blockIdx.y * 64;
    int tx = threadIdx.x & 63, ty = threadIdx.x >> 6;
    #pragma unroll
    for (int i = 0; i < 16; i++)
        t[ty + i * 4][tx] = in[(long)(r0 + ty + i * 4) * HDim + tx];
    __syncthreads();
    #pragma unroll
    for (int i = 0; i < 16; i++) {
        int cc = ty + i * 4;
        op[(long)cc * Cdim + r0 + tx] = (bf16_t)t[tx][cc];
    }
}

// ================= bf16 MFMA GEMM, double-buffered K pipeline =================
// WAVES=4 (2x2) or WAVES=8 (2x4, 512 thr, 256^2 tiles). Chunk-XOR LDS swizzle.
// Separate As0/As1/Bs0/Bs1 arrays so in-flight global_load_lds of the next
// tile provably doesn't alias current ds_reads -> stage latency hides.
// COAL epilogue bounce: dedicated cws for WAVES=4; aliased into As0 (post-
// barrier) for WAVES=8 to stay under the LDS cap.
template<int BM, int BN, int BK, int WAVES, bool BIAS, bool RELU, bool RES, bool OBF,
         bool VOUT, int SWZM, bool XOUT, bool COAL>
__global__ __launch_bounds__(WAVES * 64) void mgemm_k(
    const bf16_t* __restrict__ A, const bf16_t* __restrict__ A2, int aSplit,
    const bf16_t* __restrict__ Bt, const float* __restrict__ bias,
    const float* __restrict__ res, void* __restrict__ Cout,
    bf16_t* __restrict__ xout, bf16_t* __restrict__ vtout, int vSplit,
    int K, int lda, int ldb, int ldc)
{
    constexpr int NT  = WAVES * 64;
    constexpr int WC_ = WAVES / 2;          // wave grid: 2 x WC_
    constexpr int BNW = BN / WC_;           // per-wave N extent
    constexpr int MR = BM / 32;             // (BM/2)/16
    constexpr int NR = BNW / 16;
    constexpr int KK = BK / 32;
    constexpr int LPR = BK / 8;             // 16B chunks per LDS row
    constexpr int RW  = 64 / LPR;           // rows staged per wave per pass
    constexpr int RPASS = NT / LPR;         // rows staged per pass (all waves)
    constexpr bool ALIAS = (WAVES == 8);
    __shared__ bf16_t As0[BM * BK];
    __shared__ bf16_t As1[BM * BK];
    __shared__ bf16_t Bs0[BN * BK];
    __shared__ bf16_t Bs1[BN * BK];
    __shared__ float cws[(COAL && !ALIAS) ? WAVES * 16 * 36 : 1];

    int tid = threadIdx.x;
    int wv = tid >> 6, lane = tid & 63;
    int bm, bn;
    if constexpr (SWZM > 0) {
        int lin = blockIdx.y * gridDim.x + blockIdx.x;
        int tot = gridDim.x * gridDim.y;
        int chunk = tot >> 3;
        int e = (lin & 7) * chunk + (lin >> 3);
        bm = (e % SWZM) * BM;
        bn = (e / SWZM) * BN;
    } else {
        bm = blockIdx.y * BM; bn = blockIdx.x * BN;
    }
    const bf16_t* Ab = (bn < aSplit) ? A : A2;
    int wr = wv / WC_, wc = wv % WC_;

    f32x4 acc[MR][NR];
    #pragma unroll
    for (int i = 0; i < MR; i++)
        #pragma unroll
        for (int j = 0; j < NR; j++)
            acc[i][j] = (f32x4){0.f, 0.f, 0.f, 0.f};

    const int sr  = lane / LPR;
    const int sc8 = ((lane % LPR) ^ (sr & (LPR - 1))) * 8;
    const int r16 = lane & 15, g4 = lane >> 4;

    auto stage = [&](int k0, bf16_t (&Asb)[BM * BK], bf16_t (&Bsb)[BN * BK]) {
        #pragma unroll
        for (int p = 0; p < BM / RPASS; p++) {
            int rb = p * RPASS + wv * RW;
            const bf16_t* g = Ab + (long)(bm + rb + sr) * lda + (k0 + sc8);
            __builtin_amdgcn_global_load_lds(
                (const __attribute__((address_space(1))) void*)g,
                (__attribute__((address_space(3))) void*)&Asb[rb * BK],
                16, 0, 0);
        }
        #pragma unroll
        for (int p = 0; p < BN / RPASS; p++) {
            int rb = p * RPASS + wv * RW;
            const bf16_t* g = Bt + (long)(bn + rb + sr) * ldb + (k0 + sc8);
            __builtin_amdgcn_global_load_lds(
                (const __attribute__((address_space(1))) void*)g,
                (__attribute__((address_space(3))) void*)&Bsb[rb * BK],
                16, 0, 0);
        }
    };
    auto compute = [&](bf16_t (&Asb)[BM * BK], bf16_t (&Bsb)[BN * BK]) {
        #pragma unroll
        for (int kk = 0; kk < KK; kk++) {
            bf16x8 bkk[NR];
            #pragma unroll
            for (int j = 0; j < NR; j++) {
                int row = wc * BNW + j * 16 + r16;
                bkk[j] = *(const bf16x8*)&Bsb[row * BK + (((kk * 4 + g4) ^ (row & (LPR - 1))) * 8)];
            }
            #pragma unroll
            for (int i = 0; i < MR; i++) {
                int row = wr * (BM / 2) + i * 16 + r16;
                bf16x8 a = *(const bf16x8*)&Asb[row * BK + (((kk * 4 + g4) ^ (row & (LPR - 1))) * 8)];
                #pragma unroll
                for (int j = 0; j < NR; j++)
                    acc[i][j] = __builtin_amdgcn_mfma_f32_16x16x32_bf16(a, bkk[j], acc[i][j], 0, 0, 0);
            }
        }
    };

    int nIt = K / BK;
    stage(0, As0, Bs0);
    for (int it = 0; it < nIt; it += 2) {
        __syncthreads();                               // As0/Bs0 staged; prior reads done
        if (it + 1 < nIt) stage((it + 1) * BK, As1, Bs1);
        compute(As0, Bs0);
        __syncthreads();                               // As1/Bs1 staged; As0 reads done
        if (it + 2 < nIt) stage((it + 2) * BK, As0, Bs0);
        if (it + 1 < nIt) compute(As1, Bs1);
    }

    if constexpr (COAL) {
        __syncthreads();                               // safe to reuse LDS for bounce
        float* cb = ALIAS ? (float*)As0 : cws;
        // ---- coalesced epilogue via per-wave LDS bounce ----
        #pragma unroll
        for (int i = 0; i < MR; i++) {
            int gr0 = bm + wr * (BM / 2) + i * 16;
            #pragma unroll
            for (int hh = 0; hh < NR / 2; hh++) {
                #pragma unroll
                for (int jj = 0; jj < 2; jj++) {
                    int j = hh * 2 + jj;
                    int gc = bn + wc * BNW + j * 16 + r16;
                    float bv = BIAS ? bias[gc] : 0.f;
                    #pragma unroll
                    for (int q = 0; q < 4; q++) {
                        float v = acc[i][j][q];
                        if (BIAS) v += bv;
                        if (RELU) v = fmaxf(v, 0.f);
                        cb[(wv * 16 + g4 * 4 + q) * 36 + jj * 16 + r16] = v;
                    }
                }
                int gcb = bn + wc * BNW + hh * 32;
                if constexpr (OBF) {
                    int row = lane >> 2, c8 = (lane & 3) * 8;
                    f32x4 v0 = *(f32x4*)&cb[(wv * 16 + row) * 36 + c8];
                    f32x4 v1 = *(f32x4*)&cb[(wv * 16 + row) * 36 + c8 + 4];
                    long oidx = (long)(gr0 + row) * ldc + gcb + c8;
                    bf16x8 o;
                    #pragma unroll
                    for (int k = 0; k < 4; k++) { o[k] = (bf16_t)v0[k]; o[4 + k] = (bf16_t)v1[k]; }
                    *(bf16x8*)&((bf16_t*)Cout)[oidx] = o;
                } else {
                    #pragma unroll
                    for (int ps = 0; ps < 2; ps++) {
                        int row = (lane >> 3) + 8 * ps, c4 = (lane & 7) * 4;
                        f32x4 v = *(f32x4*)&cb[(wv * 16 + row) * 36 + c4];
                        long oidx = (long)(gr0 + row) * ldc + gcb + c4;
                        if (RES) v += *(const f32x4*)&res[oidx];
                        *(f32x4*)&((float*)Cout)[oidx] = v;
                        if (XOUT) {
                            bf16x4 o;
                            #pragma unroll
                            for (int k = 0; k < 4; k++) o[k] = (bf16_t)v[k];
                            *(bf16x4*)&xout[oidx] = o;
                        }
                    }
                }
            }
        }
    } else {
        // ---- scalar epilogue (VOUT scatter path) ----
        #pragma unroll
        for (int i = 0; i < MR; i++) {
            #pragma unroll
            for (int j = 0; j < NR; j++) {
                int gr = bm + wr * (BM / 2) + i * 16 + g4 * 4;
                int gc = bn + wc * BNW + j * 16 + r16;
                float bv = BIAS ? bias[gc] : 0.f;
                #pragma unroll
                for (int q = 0; q < 4; q++) {
                    float v = acc[i][j][q];
                    if (BIAS) v += bv;
                    if (RELU) v = fmaxf(v, 0.f);
                    if (VOUT && gc >= vSplit) {
                        int row = gr + q;
                        int b = row >> 10, t = row & (Tn - 1);
                        vtout[((long)b * 512 + (gc - vSplit)) * Tn + t] = (bf16_t)v;
                    } else {
                        long oidx = (long)(gr + q) * ldc + gc;
                        if (RES)  v += res[oidx];
                        if (OBF) ((bf16_t*)Cout)[oidx] = (bf16_t)v;
                        else     ((float*) Cout)[oidx] = v;
                        if (XOUT) xout[oidx] = (bf16_t)v;
                    }
                }
            }
        }
    }
}

// ======= fused flash attention, swapped-QK^T (S^T = K·Q^T) ==========
// 8 waves, KV-split even/odd, dbuf LDS, 1 barrier/iter. Swapping the QK mfma
// operands (A/B frag layouts are identical) makes each lane hold 16 S values
// all for ONE q-row (its lane&15): softmax becomes in-lane + 2 shfl_xor,
// m/l state is a scalar, P writes to LDS A-frag layout as packed bf16x4,
// and the enc-mask becomes a ballot bit-test. PV/acc/merge layout unchanged.
template<bool CAUSAL, bool HASMASK>
__global__ __launch_bounds__(512, 2) void flash_k(
    const bf16_t* __restrict__ qkv, const bf16_t* __restrict__ vt,
    const int* __restrict__ mask, bf16_t* __restrict__ ao)
{
    __shared__ bf16_t Kl[2][2][64][72];
    __shared__ bf16_t Vl[2][2][64][72];
    __shared__ bf16_t Pl[8][16][72];

    int qt = blockIdx.x, bh = blockIdx.y;
    int b = bh >> 3, h = bh & 7;
    int tid = threadIdx.x, wv = tid >> 6, lane = tid & 63;
    int wg = wv >> 2, wq4 = wv & 3;
    int r16 = lane & 15, g4 = lane >> 4;
    int gtid = tid & 255;

    const bf16_t* qb = qkv + ((long)(b * Tn + qt * 64 + wq4 * 16 + r16)) * 1536 + h * 64;
    bf16x8 aq0 = *(const bf16x8*)&qb[g4 * 8];
    bf16x8 aq1 = *(const bf16x8*)&qb[32 + g4 * 8];

    f32x4 acc[4];
    #pragma unroll
    for (int j = 0; j < 4; j++) acc[j] = (f32x4){0.f, 0.f, 0.f, 0.f};
    float m_ = -1e30f, l_ = 0.f;       // state for q-col = r16

    int lastT = CAUSAL ? qt : (Tn / 64 - 1);
    int niter = CAUSAL ? (qt / 2 + 1) : (Tn / 128);
    int krow = gtid >> 3, kcol = (gtid & 7) * 8;

    bf16x8 kr[2], vr[2];
    unsigned long long mvb = 0;
    {
        int t0 = wg;
        if (t0 <= lastT) {
            int s0 = t0 * 64;
            #pragma unroll
            for (int i = 0; i < 2; i++)
                kr[i] = *(const bf16x8*)&qkv[((long)(b * Tn + s0 + krow + i * 32)) * 1536 + 512 + h * 64 + kcol];
            #pragma unroll
            for (int i = 0; i < 2; i++)
                vr[i] = *(const bf16x8*)&vt[((long)(bh * 64 + krow + i * 32)) * Tn + s0 + kcol];
            if (HASMASK) mvb = __ballot(mask[b * Tn + s0 + lane] != 0);
        }
    }

    for (int it = 0; it < niter; it++) {
        int cur = it & 1;
        int t = 2 * it + wg;
        bool active = t <= lastT;
        if (active) {
            #pragma unroll
            for (int i = 0; i < 2; i++) *(bf16x8*)&Kl[cur][wg][krow + i * 32][kcol] = kr[i];
            #pragma unroll
            for (int i = 0; i < 2; i++) *(bf16x8*)&Vl[cur][wg][krow + i * 32][kcol] = vr[i];
        }
        unsigned long long mvb_use = mvb;
        __syncthreads();
        int tn = t + 2;
        if (it + 1 < niter && tn <= lastT) {
            int sn = tn * 64;
            #pragma unroll
            for (int i = 0; i < 2; i++)
                kr[i] = *(const bf16x8*)&qkv[((long)(b * Tn + sn + krow + i * 32)) * 1536 + 512 + h * 64 + kcol];
            #pragma unroll
            for (int i = 0; i < 2; i++)
                vr[i] = *(const bf16x8*)&vt[((long)(bh * 64 + krow + i * 32)) * Tn + sn + kcol];
            if (HASMASK) mvb = __ballot(mask[b * Tn + sn + lane] != 0);
        }
        if (!active) continue;

        // ---- S^T = K · Q^T : 8 MFMA (operands swapped; frag loads unchanged) ----
        f32x4 scv[4];
        __builtin_amdgcn_s_setprio(1);
        #pragma unroll
        for (int j = 0; j < 4; j++) {
            scv[j] = (f32x4){0.f, 0.f, 0.f, 0.f};
            bf16x8 bk0 = *(const bf16x8*)&Kl[cur][wg][j * 16 + r16][g4 * 8];
            bf16x8 bk1 = *(const bf16x8*)&Kl[cur][wg][j * 16 + r16][32 + g4 * 8];
            scv[j] = __builtin_amdgcn_mfma_f32_16x16x32_bf16(bk0, aq0, scv[j], 0, 0, 0);
            scv[j] = __builtin_amdgcn_mfma_f32_16x16x32_bf16(bk1, aq1, scv[j], 0, 0, 0);
        }
        __builtin_amdgcn_s_setprio(0);

        // ---- scale + mask: element (j,q) is S[kv = j*16+g4*4+q][qcol = r16] ----
        bool diag = CAUSAL && (t == qt);
        int qloc = wq4 * 16 + r16;
        #pragma unroll
        for (int j = 0; j < 4; j++) {
            #pragma unroll
            for (int q = 0; q < 4; q++) {
                float v = scv[j][q] * 0.125f;
                int kv = j * 16 + g4 * 4 + q;
                if (diag && kv > qloc) v = -1e30f;
                if (HASMASK && !((mvb_use >> kv) & 1ull)) v = -1e30f;
                scv[j][q] = v;
            }
        }

        // ---- online softmax: in-lane over 16 + 2 shfl_xor; defer-max THR=8 ----
        float pmax = scv[0][0];
        #pragma unroll
        for (int j = 0; j < 4; j++)
            #pragma unroll
            for (int q = 0; q < 4; q++) pmax = fmaxf(pmax, scv[j][q]);
        pmax = fmaxf(pmax, __shfl_xor(pmax, 16, 64));
        pmax = fmaxf(pmax, __shfl_xor(pmax, 32, 64));
        bool skip = __all(pmax <= m_ + 8.f);
        if (!skip) {
            float mnew = fmaxf(m_, pmax);
            float rf = __expf(m_ - mnew);
            l_ *= rf;
            m_ = mnew;
            #pragma unroll
            for (int q = 0; q < 4; q++) {
                float rfr = __shfl(rf, g4 * 4 + q, 64);   // rescale for O-row g4*4+q
                #pragma unroll
                for (int j = 0; j < 4; j++) acc[j][q] *= rfr;
            }
        }
        float rs = 0.f;
        #pragma unroll
        for (int j = 0; j < 4; j++)
            #pragma unroll
            for (int q = 0; q < 4; q++) {
                float pv = __expf(scv[j][q] - m_);
                scv[j][q] = pv;
                rs += pv;
            }
        rs += __shfl_xor(rs, 16, 64);
        rs += __shfl_xor(rs, 32, 64);
        l_ += rs;

        // ---- P -> LDS in A-frag layout directly: row=r16(q), col=kv; bf16x4 packs ----
        #pragma unroll
        for (int j = 0; j < 4; j++) {
            bf16x4 pk;
            #pragma unroll
            for (int q = 0; q < 4; q++) pk[q] = (bf16_t)scv[j][q];
            *(bf16x4*)&Pl[wv][r16][j * 16 + g4 * 4] = pk;
        }
        asm volatile("s_waitcnt lgkmcnt(0)" ::: "memory");
        __builtin_amdgcn_sched_barrier(0);

        // ---- PV: 8 MFMA (unchanged) ----
        __builtin_amdgcn_s_setprio(1);
        #pragma unroll
        for (int c = 0; c < 2; c++) {
            bf16x8 pa = *(const bf16x8*)&Pl[wv][r16][c * 32 + g4 * 8];
            #pragma unroll
            for (int j = 0; j < 4; j++) {
                bf16x8 bv = *(const bf16x8*)&Vl[cur][wg][j * 16 + r16][c * 32 + g4 * 8];
                acc[j] = __builtin_amdgcn_mfma_f32_16x16x32_bf16(pa, bv, acc[j], 0, 0, 0);
            }
        }
        __builtin_amdgcn_s_setprio(0);
    }

    // ---- merge group 1 state into group 0 via LDS, write output ----
    float* accS = (float*)&Kl[0][0][0][0];
    float* mlS  = accS + 64 * 64;
    __syncthreads();
    if (wg == 1) {
        #pragma unroll
        for (int j = 0; j < 4; j++)
            #pragma unroll
            for (int q = 0; q < 4; q++)
                accS[(wq4 * 16 + g4 * 4 + q) * 64 + j * 16 + r16] = acc[j][q];
        if (g4 == 0) {
            mlS[(wq4 * 16 + r16) * 2 + 0] = m_;
            mlS[(wq4 * 16 + r16) * 2 + 1] = l_;
        }
    }
    __syncthreads();
    if (wg == 0) {
        bf16_t* aob = ao + ((long)(b * Tn + qt * 64 + wq4 * 16 + g4 * 4)) * Cdim + h * 64;
        #pragma unroll
        for (int q = 0; q < 4; q++) {
            int row = wq4 * 16 + g4 * 4 + q;
            float mA = __shfl(m_, g4 * 4 + q, 64);   // own state for this O-row
            float lA = __shfl(l_, g4 * 4 + q, 64);
            float mB = mlS[row * 2], lB = mlS[row * 2 + 1];
            float mS = fmaxf(mA, mB);
            float fA = __expf(mA - mS), fB = __expf(mB - mS);
            float lS = lA * fA + lB * fB;
            float inv = 1.f / lS;
            #pragma unroll
            for (int j = 0; j < 4; j++) {
                float o = (acc[j][q] * fA + accS[row * 64 + j * 16 + r16] * fB) * inv;
                aob[(long)q * Cdim + j * 16 + r16] = (bf16_t)o;
            }
        }
    }
}

// ================================ host orchestration ================================
static void run_attn(hipStream_t stream, const bf16_t* hq, const bf16_t* hkv,
    const bf16_t* wqkv, const float* bo, const bf16_t* wo_t,
    float* xres, const int* mask, bool causal,
    bf16_t* qkv, bf16_t* vt, bf16_t* ao)
{
    dim3 blk(256);
    // fused qkv projection: N=1536 (cols<512 read hq, else hkv); v-part -> vt
    mgemm_k<64,128,64,4,false,false,false,true,true,0,false,false><<<dim3(12, 32, 1), blk, 0, stream>>>(
        hq, hkv, 512, wqkv, nullptr, nullptr, qkv, nullptr, vt, 1024,
        Cdim, Cdim, Cdim, 1536);
    if (causal)
        flash_k<true,false><<<dim3(Tn / 64, Bn * Hn), dim3(512), 0, stream>>>(qkv, vt, nullptr, ao);
    else
        flash_k<false,true><<<dim3(Tn / 64, Bn * Hn), dim3(512), 0, stream>>>(qkv, vt, mask, ao);
    // out projection + bias + residual (f32, in place on xres) — coalesced epilogue
    mgemm_k<64,64,64,4,true,false,true,false,false,0,false,true><<<dim3(8, 32, 1), blk, 0, stream>>>(
        ao, ao, 1 << 30, wo_t, bo, xres, xres, nullptr, nullptr, 1 << 30,
        Cdim, Cdim, Cdim, Cdim);
}

extern "C" void kernel_launch(void* const* d_in, const int* in_sizes, int n_in,
                              void* d_out, int out_size, void* d_ws, size_t ws_size,
                              hipStream_t stream)
{
    (void)in_sizes; (void)n_in; (void)out_size; (void)ws_size;
    const int*   enc_inp  = (const int*)d_in[0];
    const int*   dec_inp  = (const int*)d_in[1];
    const int*   enc_mask = (const int*)d_in[2];
    const float* tok_emb  = (const float*)d_in[3];
    const float* pos_emb  = (const float*)d_in[4];
    const float* e_wq  = (const float*)d_in[5];
    const float* e_wk  = (const float*)d_in[6];
    const float* e_wv  = (const float*)d_in[7];
    const float* e_wo  = (const float*)d_in[8];
    const float* e_bo  = (const float*)d_in[9];
    const float* dsa_wq = (const float*)d_in[10];
    const float* dsa_wk = (const float*)d_in[11];
    const float* dsa_wv = (const float*)d_in[12];
    const float* dsa_wo = (const float*)d_in[13];
    const float* dsa_bo = (const float*)d_in[14];
    const float* dca_wq = (const float*)d_in[15];
    const float* dca_wk = (const float*)d_in[16];
    const float* dca_wv = (const float*)d_in[17];
    const float* dca_wo = (const float*)d_in[18];
    const float* dca_bo = (const float*)d_in[19];
    const float* e_ln1_g = (const float*)d_in[20];
    const float* e_ln1_b = (const float*)d_in[21];
    const float* e_ln2_g = (const float*)d_in[22];
    const float* e_ln2_b = (const float*)d_in[23];
    const float* d_ln1_g = (const float*)d_in[24];
    const float* d_ln1_b = (const float*)d_in[25];
    const float* d_ln2_g = (const float*)d_in[26];
    const float* d_ln2_b = (const float*)d_in[27];
    const float* d_ln3_g = (const float*)d_in[28];
    const float* d_ln3_b = (const float*)d_in[29];
    const float* e_w1 = (const float*)d_in[30];
    const float* e_b1 = (const float*)d_in[31];
    const float* e_w2 = (const float*)d_in[32];
    const float* e_b2 = (const float*)d_in[33];
    const float* d_w1 = (const float*)d_in[34];
    const float* d_b1 = (const float*)d_in[35];
    const float* d_w2 = (const float*)d_in[36];
    const float* d_b2 = (const float*)d_in[37];
    const float* out_w = (const float*)d_in[38];
    const float* out_b = (const float*)d_in[39];
    float* out = (float*)d_out;

    // -------- workspace carve (bytes) --------
    char* p = (char*)d_ws;
    auto takeB = [&](size_t bytes) { char* r = p; p += (bytes + 255) & ~(size_t)255; return r; };
    float*  x_enc = (float*)takeB(1048576ull * 4);
    float*  x_dec = (float*)takeB(1048576ull * 4);
    bf16_t* h     = (bf16_t*)takeB(1048576ull * 2);
    bf16_t* hk    = (bf16_t*)takeB(1048576ull * 2);
    bf16_t* qkv   = (bf16_t*)takeB(3145728ull * 2);
    bf16_t* vt    = (bf16_t*)takeB(1048576ull * 2);
    bf16_t* ao    = (bf16_t*)takeB(1048576ull * 2);
    bf16_t* xdb   = (bf16_t*)takeB(1048576ull * 2);
    bf16_t* mid   = (bf16_t*)takeB(4194304ull * 2);
    bf16_t* wqkv_t = (bf16_t*)takeB(12ull * 786432 * 2);
    bf16_t* wo_t   = (bf16_t*)takeB(12ull * 262144 * 2);
    bf16_t* w1_t   = (bf16_t*)takeB(8ull * 1048576 * 2);
    bf16_t* w2_t   = (bf16_t*)takeB(8ull * 1048576 * 2);
    bf16_t* outw_t = (bf16_t*)takeB(16384000ull * 2);

    dim3 blk(256);
    const long LQKV = 1536L * Cdim;

    // ================= weight prep (5 launches) =================
    QkvSrc qs;
    qs.p[0] = e_wq;   qs.p[1] = e_wk;   qs.p[2] = e_wv;
    qs.p[3] = dsa_wq; qs.p[4] = dsa_wk; qs.p[5] = dsa_wv;
    qs.p[6] = dca_wq; qs.p[7] = dca_wk; qs.p[8] = dca_wv;
    tcvt_qkv_k<<<dim3(1, 8, 288), blk, 0, stream>>>(qs, wqkv_t);
    Ptr3 pw;
    pw.p[0] = e_wo; pw.p[1] = dsa_wo; pw.p[2] = dca_wo;
    tcvt_b_k<<<dim3(8, 8, 12), blk, 0, stream>>>(pw, wo_t, Cdim, Cdim, 4, (long)Cdim * Cdim);
    pw.p[0] = e_w1; pw.p[1] = d_w1; pw.p[2] = nullptr;
    tcvt_b_k<<<dim3(32, 8, 8), blk, 0, stream>>>(pw, w1_t, Cdim, FF, 4, (long)Cdim * FF);
    pw.p[0] = e_w2; pw.p[1] = d_w2; pw.p[2] = nullptr;
    tcvt_b_k<<<dim3(8, 32, 8), blk, 0, stream>>>(pw, w2_t, FF, Cdim, 4, (long)FF * Cdim);
    pw.p[0] = out_w; pw.p[1] = nullptr; pw.p[2] = nullptr;
    tcvt_b_k<<<dim3(500, 8, 1), blk, 0, stream>>>(pw, outw_t, Cdim, Vn, 1, 0);

    // ================= encoder =================
    embed_ln_k<<<NTOK / 4, blk, 0, stream>>>(enc_inp, tok_emb, pos_emb, e_ln1_g, e_ln1_b, x_enc, h);
    for (int l = 0; l < Ld; l++) {
        if (l) ln_k<<<NTOK / 4, blk, 0, stream>>>(x_enc, e_ln1_g + l * Cdim, e_ln1_b + l * Cdim, h);
        run_attn(stream, h, h,
                 wqkv_t + (long)l * LQKV, e_bo + l * Cdim, wo_t + (long)l * Cdim * Cdim,
                 x_enc, enc_mask, /*causal=*/false, qkv, vt, ao);
        ln_k<<<NTOK / 4, blk, 0, stream>>>(x_enc, e_ln2_g + l * Cdim, e_ln2_b + l * Cdim, h);
        mgemm_k<128,128,64,4,true,true,false,true,false,0,false,true><<<dim3(16, 16, 1), blk, 0, stream>>>(
            h, h, 1 << 30, w1_t + (long)l * Cdim * FF, e_b1 + l * FF, nullptr, mid,
            nullptr, nullptr, 1 << 30, Cdim, Cdim, Cdim, FF);
        mgemm_k<64,64,64,4,true,false,true,false,false,0,false,true><<<dim3(8, 32, 1), blk, 0, stream>>>(
            mid, mid, 1 << 30, w2_t + (long)l * FF * Cdim, e_b2 + l * Cdim, x_enc, x_enc,
            nullptr, nullptr, 1 << 30, FF, FF, FF, Cdim);
    }
    // x_enc now holds enc_out

    // ================= decoder =================
    embed_ln_k<<<NTOK / 4, blk, 0, stream>>>(dec_inp, tok_emb, pos_emb, d_ln1_g, d_ln1_b, x_dec, h);
    for (int l = 0; l < Ld; l++) {
        // causal self-attention
        if (l) ln_k<<<NTOK / 4, blk, 0, stream>>>(x_dec, d_ln1_g + l * Cdim, d_ln1_b + l * Cdim, h);
        run_attn(stream, h, h,
                 wqkv_t + (long)(Ld + l) * LQKV, dsa_bo + l * Cdim,
                 wo_t + (long)(Ld + l) * Cdim * Cdim,
                 x_dec, nullptr, /*causal=*/true, qkv, vt, ao);
        // cross-attention (same LN applied to x and enc_out) — one fused launch
        ln2_k<<<2 * NTOK / 4, blk, 0, stream>>>(x_dec, x_enc,
            d_ln2_g + l * Cdim, d_ln2_b + l * Cdim, h, hk);
        run_attn(stream, h, hk,
                 wqkv_t + (long)(2 * Ld + l) * LQKV, dca_bo + l * Cdim,
                 wo_t + (long)(2 * Ld + l) * Cdim * Cdim,
                 x_dec, enc_mask, /*causal=*/false, qkv, vt, ao);
        // FFN
        ln_k<<<NTOK / 4, blk, 0, stream>>>(x_dec, d_ln3_g + l * Cdim, d_ln3_b + l * Cdim, h);
        mgemm_k<128,128,64,4,true,true,false,true,false,0,false,true><<<dim3(16, 16, 1), blk, 0, stream>>>(
            h, h, 1 << 30, w1_t + (long)(Ld + l) * Cdim * FF, d_b1 + l * FF, nullptr, mid,
            nullptr, nullptr, 1 << 30, Cdim, Cdim, Cdim, FF);
        if (l < Ld - 1)
            mgemm_k<64,64,64,4,true,false,true,false,false,0,false,true><<<dim3(8, 32, 1), blk, 0, stream>>>(
                mid, mid, 1 << 30, w2_t + (long)(Ld + l) * FF * Cdim, d_b2 + l * Cdim, x_dec, x_dec,
                nullptr, nullptr, 1 << 30, FF, FF, FF, Cdim);
        else  // last layer: also emit bf16 copy for logits GEMM
            mgemm_k<64,64,64,4,true,false,true,false,false,0,true,true><<<dim3(8, 32, 1), blk, 0, stream>>>(
                mid, mid, 1 << 30, w2_t + (long)(Ld + l) * FF * Cdim, d_b2 + l * Cdim, x_dec, x_dec,
                xdb, nullptr, 1 << 30, FF, FF, FF, Cdim);
    }

    // ================= final logits (f32 out, 256x256 tile, 8 waves, XCD-swizzled) ==========
    mgemm_k<256,256,64,8,true,false,false,false,false,8,false,true><<<dim3(125, 8, 1), dim3(512), 0, stream>>>(
        xdb, xdb, 1 << 30, outw_t, out_b, nullptr, out, nullptr, nullptr, 1 << 30,
        Cdim, Cdim, Cdim, Vn);
}

// Round 15
// 930.069 us; speedup vs baseline: 1.3525x; 1.0106x over previous
//
#include <hip/hip_runtime.h>
#include <hip/hip_bf16.h>
#include <math.h>

#define Cdim 512
#define Hn   8
#define HDim 64
#define Ld   4
#define Tn   1024
#define Bn   2
#define NTOK 2048   // B*T
#define FF   2048   // 4*C
#define Vn   32000

typedef __bf16 bf16_t;
typedef __bf16 bf16x8 __attribute__((ext_vector_type(8)));
typedef __bf16 bf16x4 __attribute__((ext_vector_type(4)));
typedef float  f32x4  __attribute__((ext_vector_type(4)));

// ---------------- layernorm: one wave per row, 4 rows/block, no barriers ----------------
__device__ __forceinline__ void ln_wave(const float* __restrict__ xr,
    const float* __restrict__ g, const float* __restrict__ bb,
    bf16_t* __restrict__ yr, int lane)
{
    f32x4 a = *(const f32x4*)&xr[lane * 8];
    f32x4 c = *(const f32x4*)&xr[lane * 8 + 4];
    float s = a[0] + a[1] + a[2] + a[3] + c[0] + c[1] + c[2] + c[3];
    #pragma unroll
    for (int o = 1; o < 64; o <<= 1) s += __shfl_xor(s, o, 64);
    float mean = s * (1.f / Cdim);
    float d[8], qv = 0.f;
    #pragma unroll
    for (int k = 0; k < 4; k++) { d[k] = a[k] - mean; d[4 + k] = c[k] - mean; }
    #pragma unroll
    for (int k = 0; k < 8; k++) qv += d[k] * d[k];
    #pragma unroll
    for (int o = 1; o < 64; o <<= 1) qv += __shfl_xor(qv, o, 64);
    float inv = rsqrtf(qv * (1.f / Cdim) + 1e-5f);
    f32x4 g0 = *(const f32x4*)&g[lane * 8],  g1 = *(const f32x4*)&g[lane * 8 + 4];
    f32x4 b0 = *(const f32x4*)&bb[lane * 8], b1 = *(const f32x4*)&bb[lane * 8 + 4];
    bf16x8 o;
    #pragma unroll
    for (int k = 0; k < 4; k++) {
        o[k]     = (bf16_t)(d[k]     * inv * g0[k] + b0[k]);
        o[4 + k] = (bf16_t)(d[4 + k] * inv * g1[k] + b1[k]);
    }
    *(bf16x8*)&yr[lane * 8] = o;
}

__global__ __launch_bounds__(256) void ln_k(const float* __restrict__ x,
    const float* __restrict__ g, const float* __restrict__ bb, bf16_t* __restrict__ y)
{
    int wid = threadIdx.x >> 6, lane = threadIdx.x & 63;
    int row = blockIdx.x * 4 + wid;
    ln_wave(x + (long)row * Cdim, g, bb, y + (long)row * Cdim, lane);
}

// two-source LN (cross-attention): rows < NTOK from x1->y1, else x2->y2 (same g,b)
__global__ __launch_bounds__(256) void ln2_k(const float* __restrict__ x1,
    const float* __restrict__ x2, const float* __restrict__ g,
    const float* __restrict__ bb, bf16_t* __restrict__ y1, bf16_t* __restrict__ y2)
{
    int wid = threadIdx.x >> 6, lane = threadIdx.x & 63;
    int row = blockIdx.x * 4 + wid;
    const float* x = (row < NTOK) ? x1 : x2;
    bf16_t*      y = (row < NTOK) ? y1 : y2;
    int r = row & (NTOK - 1);
    ln_wave(x + (long)r * Cdim, g, bb, y + (long)r * Cdim, lane);
}

// ---------------- fused embedding + first-layer LN (wave per row) ----------------
__global__ __launch_bounds__(256) void embed_ln_k(const int* __restrict__ inp,
    const float* __restrict__ tok, const float* __restrict__ pos,
    const float* __restrict__ g, const float* __restrict__ bb,
    float* __restrict__ x, bf16_t* __restrict__ y)
{
    int wid = threadIdx.x >> 6, lane = threadIdx.x & 63;
    int bt = blockIdx.x * 4 + wid;
    int t = bt & (Tn - 1);
    long toff = (long)inp[bt] * Cdim;
    f32x4 a = *(const f32x4*)&tok[toff + lane * 8];
    f32x4 c = *(const f32x4*)&tok[toff + lane * 8 + 4];
    f32x4 pa = *(const f32x4*)&pos[(long)t * Cdim + lane * 8];
    f32x4 pc = *(const f32x4*)&pos[(long)t * Cdim + lane * 8 + 4];
    a += pa; c += pc;
    float* xr = x + (long)bt * Cdim;
    *(f32x4*)&xr[lane * 8] = a;
    *(f32x4*)&xr[lane * 8 + 4] = c;
    float s = a[0] + a[1] + a[2] + a[3] + c[0] + c[1] + c[2] + c[3];
    #pragma unroll
    for (int o = 1; o < 64; o <<= 1) s += __shfl_xor(s, o, 64);
    float mean = s * (1.f / Cdim);
    float d[8], qv = 0.f;
    #pragma unroll
    for (int k = 0; k < 4; k++) { d[k] = a[k] - mean; d[4 + k] = c[k] - mean; }
    #pragma unroll
    for (int k = 0; k < 8; k++) qv += d[k] * d[k];
    #pragma unroll
    for (int o = 1; o < 64; o <<= 1) qv += __shfl_xor(qv, o, 64);
    float inv = rsqrtf(qv * (1.f / Cdim) + 1e-5f);
    f32x4 g0 = *(const f32x4*)&g[lane * 8],  g1 = *(const f32x4*)&g[lane * 8 + 4];
    f32x4 b0 = *(const f32x4*)&bb[lane * 8], b1 = *(const f32x4*)&bb[lane * 8 + 4];
    bf16x8 o;
    #pragma unroll
    for (int k = 0; k < 4; k++) {
        o[k]     = (bf16_t)(d[k]     * inv * g0[k] + b0[k]);
        o[4 + k] = (bf16_t)(d[4 + k] * inv * g1[k] + b1[k]);
    }
    *(bf16x8*)&y[(long)bt * Cdim + lane * 8] = o;
}

// ------- batched tiled transpose+convert: f32 [R,Cc] -> bf16 [Cc,R] over z sources/layers -------
struct Ptr3 { const float* p[3]; };
__global__ __launch_bounds__(256) void tcvt_b_k(Ptr3 srcs, bf16_t* __restrict__ dst,
    int R, int Cc, int lps, long dstStride)
{
    int z = blockIdx.z; int s = z / lps, l = z - s * lps;
    const float* in = srcs.p[s] + (long)l * R * Cc;
    bf16_t* op = dst + (long)z * dstStride;
    __shared__ float t[64][65];
    int r0 = blockIdx.y * 64, c0 = blockIdx.x * 64;
    int tx = threadIdx.x & 63, ty = threadIdx.x >> 6;
    #pragma unroll
    for (int i = 0; i < 16; i++)
        t[ty + i * 4][tx] = in[(long)(r0 + ty + i * 4) * Cc + c0 + tx];
    __syncthreads();
    #pragma unroll
    for (int i = 0; i < 16; i++) {
        int cc = ty + i * 4;
        op[(long)(c0 + cc) * R + r0 + tx] = (bf16_t)t[tx][cc];
    }
}

// ------- fused QKV weight prep: 9 (set,part) sources in one launch -------
struct QkvSrc { const float* p[9]; };
__global__ __launch_bounds__(256) void tcvt_qkv_k(QkvSrc srcs, bf16_t* __restrict__ outp)
{
    int z = blockIdx.z;
    int si = z >> 5, zb = (z >> 3) & 3, zh = z & 7;
    int set = si / 3, part = si - set * 3;
    const float* in = srcs.p[si] + (long)zb * (Hn * Cdim * HDim) + (long)zh * (Cdim * HDim);
    bf16_t* op = outp + ((long)set * Ld + zb) * (1536L * Cdim)
                      + (long)part * 512 * Cdim + (long)zh * 64 * Cdim;
    __shared__ float t[64][65];
    int r0 = blockIdx.y * 64;
    int tx = threadIdx.x & 63, ty = threadIdx.x >> 6;
    #pragma unroll
    for (int i = 0; i < 16; i++)
        t[ty + i * 4][tx] = in[(long)(r0 + ty + i * 4) * HDim + tx];
    __syncthreads();
    #pragma unroll
    for (int i = 0; i < 16; i++) {
        int cc = ty + i * 4;
        op[(long)cc * Cdim + r0 + tx] = (bf16_t)t[tx][cc];
    }
}

// ================= bf16 MFMA GEMM, double-buffered K pipeline =================
// WAVES=4 (2x2) or WAVES=8 (2x4, 512 thr, 256^2 tiles). Chunk-XOR LDS swizzle.
// Separate As0/As1/Bs0/Bs1 arrays (compile-time distinct -> stage latency hides).
// COAL epilogue bounce aliases into Bs0 when it fits (post-barrier), else cws.
// VOUT+COAL: v-tiles (bn>=vSplit, tile-aligned) use vectorized bf16x4 scatter.
template<int BM, int BN, int BK, int WAVES, bool BIAS, bool RELU, bool RES, bool OBF,
         bool VOUT, int SWZM, bool XOUT, bool COAL>
__global__ __launch_bounds__(WAVES * 64) void mgemm_k(
    const bf16_t* __restrict__ A, const bf16_t* __restrict__ A2, int aSplit,
    const bf16_t* __restrict__ Bt, const float* __restrict__ bias,
    const float* __restrict__ res, void* __restrict__ Cout,
    bf16_t* __restrict__ xout, bf16_t* __restrict__ vtout, int vSplit,
    int K, int lda, int ldb, int ldc)
{
    constexpr int NT  = WAVES * 64;
    constexpr int WC_ = WAVES / 2;          // wave grid: 2 x WC_
    constexpr int BNW = BN / WC_;           // per-wave N extent
    constexpr int MR = BM / 32;             // (BM/2)/16
    constexpr int NR = BNW / 16;
    constexpr int KK = BK / 32;
    constexpr int LPR = BK / 8;             // 16B chunks per LDS row
    constexpr int RW  = 64 / LPR;           // rows staged per wave per pass
    constexpr int RPASS = NT / LPR;         // rows staged per pass (all waves)
    constexpr bool ALIAS = COAL && (BN * BK * 2 >= WAVES * 16 * 36 * 4);
    __shared__ bf16_t As0[BM * BK];
    __shared__ bf16_t As1[BM * BK];
    __shared__ bf16_t Bs0[BN * BK];
    __shared__ bf16_t Bs1[BN * BK];
    __shared__ float cws[(COAL && !ALIAS) ? WAVES * 16 * 36 : 1];

    int tid = threadIdx.x;
    int wv = tid >> 6, lane = tid & 63;
    int bm, bn;
    if constexpr (SWZM > 0) {
        int lin = blockIdx.y * gridDim.x + blockIdx.x;
        int tot = gridDim.x * gridDim.y;
        int chunk = tot >> 3;
        int e = (lin & 7) * chunk + (lin >> 3);
        bm = (e % SWZM) * BM;
        bn = (e / SWZM) * BN;
    } else {
        bm = blockIdx.y * BM; bn = blockIdx.x * BN;
    }
    const bf16_t* Ab = (bn < aSplit) ? A : A2;
    int wr = wv / WC_, wc = wv % WC_;

    f32x4 acc[MR][NR];
    #pragma unroll
    for (int i = 0; i < MR; i++)
        #pragma unroll
        for (int j = 0; j < NR; j++)
            acc[i][j] = (f32x4){0.f, 0.f, 0.f, 0.f};

    const int sr  = lane / LPR;
    const int sc8 = ((lane % LPR) ^ (sr & (LPR - 1))) * 8;
    const int r16 = lane & 15, g4 = lane >> 4;

    auto stage = [&](int k0, bf16_t (&Asb)[BM * BK], bf16_t (&Bsb)[BN * BK]) {
        #pragma unroll
        for (int p = 0; p < BM / RPASS; p++) {
            int rb = p * RPASS + wv * RW;
            const bf16_t* g = Ab + (long)(bm + rb + sr) * lda + (k0 + sc8);
            __builtin_amdgcn_global_load_lds(
                (const __attribute__((address_space(1))) void*)g,
                (__attribute__((address_space(3))) void*)&Asb[rb * BK],
                16, 0, 0);
        }
        #pragma unroll
        for (int p = 0; p < BN / RPASS; p++) {
            int rb = p * RPASS + wv * RW;
            const bf16_t* g = Bt + (long)(bn + rb + sr) * ldb + (k0 + sc8);
            __builtin_amdgcn_global_load_lds(
                (const __attribute__((address_space(1))) void*)g,
                (__attribute__((address_space(3))) void*)&Bsb[rb * BK],
                16, 0, 0);
        }
    };
    auto compute = [&](bf16_t (&Asb)[BM * BK], bf16_t (&Bsb)[BN * BK]) {
        #pragma unroll
        for (int kk = 0; kk < KK; kk++) {
            bf16x8 bkk[NR];
            #pragma unroll
            for (int j = 0; j < NR; j++) {
                int row = wc * BNW + j * 16 + r16;
                bkk[j] = *(const bf16x8*)&Bsb[row * BK + (((kk * 4 + g4) ^ (row & (LPR - 1))) * 8)];
            }
            #pragma unroll
            for (int i = 0; i < MR; i++) {
                int row = wr * (BM / 2) + i * 16 + r16;
                bf16x8 a = *(const bf16x8*)&Asb[row * BK + (((kk * 4 + g4) ^ (row & (LPR - 1))) * 8)];
                #pragma unroll
                for (int j = 0; j < NR; j++)
                    acc[i][j] = __builtin_amdgcn_mfma_f32_16x16x32_bf16(a, bkk[j], acc[i][j], 0, 0, 0);
            }
        }
    };

    int nIt = K / BK;
    stage(0, As0, Bs0);
    for (int it = 0; it < nIt; it += 2) {
        __syncthreads();                               // As0/Bs0 staged; prior reads done
        if (it + 1 < nIt) stage((it + 1) * BK, As1, Bs1);
        compute(As0, Bs0);
        __syncthreads();                               // As1/Bs1 staged; As0 reads done
        if (it + 2 < nIt) stage((it + 2) * BK, As0, Bs0);
        if (it + 1 < nIt) compute(As1, Bs1);
    }

    if constexpr (COAL) {
        if (VOUT && bn >= vSplit) {
            // ---- vectorized V^T scatter: 4 consecutive t per lane -> bf16x4 ----
            #pragma unroll
            for (int i = 0; i < MR; i++) {
                int gr = bm + wr * (BM / 2) + i * 16 + g4 * 4;
                int b = gr >> 10, t0 = gr & (Tn - 1);
                #pragma unroll
                for (int j = 0; j < NR; j++) {
                    int dcol = bn + wc * BNW + j * 16 + r16 - vSplit;
                    bf16x4 pk;
                    #pragma unroll
                    for (int q = 0; q < 4; q++) pk[q] = (bf16_t)acc[i][j][q];
                    *(bf16x4*)&vtout[((long)b * 512 + dcol) * Tn + t0] = pk;
                }
            }
        } else {
            __syncthreads();                           // safe to reuse LDS for bounce
            float* cb = ALIAS ? (float*)Bs0 : cws;
            #pragma unroll
            for (int i = 0; i < MR; i++) {
                int gr0 = bm + wr * (BM / 2) + i * 16;
                #pragma unroll
                for (int hh = 0; hh < NR / 2; hh++) {
                    #pragma unroll
                    for (int jj = 0; jj < 2; jj++) {
                        int j = hh * 2 + jj;
                        int gc = bn + wc * BNW + j * 16 + r16;
                        float bv = BIAS ? bias[gc] : 0.f;
                        #pragma unroll
                        for (int q = 0; q < 4; q++) {
                            float v = acc[i][j][q];
                            if (BIAS) v += bv;
                            if (RELU) v = fmaxf(v, 0.f);
                            cb[(wv * 16 + g4 * 4 + q) * 36 + jj * 16 + r16] = v;
                        }
                    }
                    int gcb = bn + wc * BNW + hh * 32;
                    if constexpr (OBF) {
                        int row = lane >> 2, c8 = (lane & 3) * 8;
                        f32x4 v0 = *(f32x4*)&cb[(wv * 16 + row) * 36 + c8];
                        f32x4 v1 = *(f32x4*)&cb[(wv * 16 + row) * 36 + c8 + 4];
                        long oidx = (long)(gr0 + row) * ldc + gcb + c8;
                        bf16x8 o;
                        #pragma unroll
                        for (int k = 0; k < 4; k++) { o[k] = (bf16_t)v0[k]; o[4 + k] = (bf16_t)v1[k]; }
                        *(bf16x8*)&((bf16_t*)Cout)[oidx] = o;
                    } else {
                        #pragma unroll
                        for (int ps = 0; ps < 2; ps++) {
                            int row = (lane >> 3) + 8 * ps, c4 = (lane & 7) * 4;
                            f32x4 v = *(f32x4*)&cb[(wv * 16 + row) * 36 + c4];
                            long oidx = (long)(gr0 + row) * ldc + gcb + c4;
                            if (RES) v += *(const f32x4*)&res[oidx];
                            *(f32x4*)&((float*)Cout)[oidx] = v;
                            if (XOUT) {
                                bf16x4 o;
                                #pragma unroll
                                for (int k = 0; k < 4; k++) o[k] = (bf16_t)v[k];
                                *(bf16x4*)&xout[oidx] = o;
                            }
                        }
                    }
                }
            }
        }
    } else {
        // ---- scalar epilogue (fallback) ----
        #pragma unroll
        for (int i = 0; i < MR; i++) {
            #pragma unroll
            for (int j = 0; j < NR; j++) {
                int gr = bm + wr * (BM / 2) + i * 16 + g4 * 4;
                int gc = bn + wc * BNW + j * 16 + r16;
                float bv = BIAS ? bias[gc] : 0.f;
                #pragma unroll
                for (int q = 0; q < 4; q++) {
                    float v = acc[i][j][q];
                    if (BIAS) v += bv;
                    if (RELU) v = fmaxf(v, 0.f);
                    if (VOUT && gc >= vSplit) {
                        int row = gr + q;
                        int b = row >> 10, t = row & (Tn - 1);
                        vtout[((long)b * 512 + (gc - vSplit)) * Tn + t] = (bf16_t)v;
                    } else {
                        long oidx = (long)(gr + q) * ldc + gc;
                        if (RES)  v += res[oidx];
                        if (OBF) ((bf16_t*)Cout)[oidx] = (bf16_t)v;
                        else     ((float*) Cout)[oidx] = v;
                        if (XOUT) xout[oidx] = (bf16_t)v;
                    }
                }
            }
        }
    }
}

// ======= fused flash attention, swapped-QK^T, single-buffer K/V, 2 blocks/CU ==========
// 8 waves, KV-split even/odd. Single-buffered K/V LDS (55 KB) with register
// prefetch: loads for tile i+1 issue right after barrier (A), land during
// compute; writes to LDS happen at top of next iter after barrier (B) proves
// all reads done. 2 resident blocks/CU -> causal imbalance averages via
// dynamic dispatch; one block's softmax overlaps the other's MFMA.
template<bool CAUSAL, bool HASMASK>
__global__ __launch_bounds__(512, 4) void flash_k(
    const bf16_t* __restrict__ qkv, const bf16_t* __restrict__ vt,
    const int* __restrict__ mask, bf16_t* __restrict__ ao)
{
    __shared__ bf16_t Kl[2][64][72];
    __shared__ bf16_t Vl[2][64][72];
    __shared__ bf16_t Pl[8][16][72];

    int qt = blockIdx.x, bh = blockIdx.y;
    int b = bh >> 3, h = bh & 7;
    int tid = threadIdx.x, wv = tid >> 6, lane = tid & 63;
    int wg = wv >> 2, wq4 = wv & 3;
    int r16 = lane & 15, g4 = lane >> 4;
    int gtid = tid & 255;

    const bf16_t* qb = qkv + ((long)(b * Tn + qt * 64 + wq4 * 16 + r16)) * 1536 + h * 64;
    bf16x8 aq0 = *(const bf16x8*)&qb[g4 * 8];
    bf16x8 aq1 = *(const bf16x8*)&qb[32 + g4 * 8];

    f32x4 acc[4];
    #pragma unroll
    for (int j = 0; j < 4; j++) acc[j] = (f32x4){0.f, 0.f, 0.f, 0.f};
    float m_ = -1e30f, l_ = 0.f;       // state for q-col = r16

    int lastT = CAUSAL ? qt : (Tn / 64 - 1);
    int niter = CAUSAL ? (qt / 2 + 1) : (Tn / 128);
    int krow = gtid >> 3, kcol = (gtid & 7) * 8;

    bf16x8 kr[2], vr[2];
    unsigned long long mvb = 0;
    {
        int t0 = wg;
        if (t0 <= lastT) {
            int s0 = t0 * 64;
            #pragma unroll
            for (int i = 0; i < 2; i++)
                kr[i] = *(const bf16x8*)&qkv[((long)(b * Tn + s0 + krow + i * 32)) * 1536 + 512 + h * 64 + kcol];
            #pragma unroll
            for (int i = 0; i < 2; i++)
                vr[i] = *(const bf16x8*)&vt[((long)(bh * 64 + krow + i * 32)) * Tn + s0 + kcol];
            if (HASMASK) mvb = __ballot(mask[b * Tn + s0 + lane] != 0);
        }
    }

    for (int it = 0; it < niter; it++) {
        int t = 2 * it + wg;
        bool active = t <= lastT;
        if (active) {
            #pragma unroll
            for (int i = 0; i < 2; i++) *(bf16x8*)&Kl[wg][krow + i * 32][kcol] = kr[i];
            #pragma unroll
            for (int i = 0; i < 2; i++) *(bf16x8*)&Vl[wg][krow + i * 32][kcol] = vr[i];
        }
        unsigned long long mvb_use = mvb;
        __syncthreads();                      // (A) tiles visible
        int tn = t + 2;
        if (it + 1 < niter && tn <= lastT) {  // prefetch next tile into regs
            int sn = tn * 64;
            #pragma unroll
            for (int i = 0; i < 2; i++)
                kr[i] = *(const bf16x8*)&qkv[((long)(b * Tn + sn + krow + i * 32)) * 1536 + 512 + h * 64 + kcol];
            #pragma unroll
            for (int i = 0; i < 2; i++)
                vr[i] = *(const bf16x8*)&vt[((long)(bh * 64 + krow + i * 32)) * Tn + sn + kcol];
            if (HASMASK) mvb = __ballot(mask[b * Tn + sn + lane] != 0);
        }
        if (active) {
            // ---- S^T = K · Q^T : 8 MFMA ----
            f32x4 scv[4];
            __builtin_amdgcn_s_setprio(1);
            #pragma unroll
            for (int j = 0; j < 4; j++) {
                scv[j] = (f32x4){0.f, 0.f, 0.f, 0.f};
                bf16x8 bk0 = *(const bf16x8*)&Kl[wg][j * 16 + r16][g4 * 8];
                bf16x8 bk1 = *(const bf16x8*)&Kl[wg][j * 16 + r16][32 + g4 * 8];
                scv[j] = __builtin_amdgcn_mfma_f32_16x16x32_bf16(bk0, aq0, scv[j], 0, 0, 0);
                scv[j] = __builtin_amdgcn_mfma_f32_16x16x32_bf16(bk1, aq1, scv[j], 0, 0, 0);
            }
            __builtin_amdgcn_s_setprio(0);

            // ---- scale + mask: element (j,q) is S[kv = j*16+g4*4+q][qcol = r16] ----
            bool diag = CAUSAL && (t == qt);
            int qloc = wq4 * 16 + r16;
            #pragma unroll
            for (int j = 0; j < 4; j++) {
                #pragma unroll
                for (int q = 0; q < 4; q++) {
                    float v = scv[j][q] * 0.125f;
                    int kv = j * 16 + g4 * 4 + q;
                    if (diag && kv > qloc) v = -1e30f;
                    if (HASMASK && !((mvb_use >> kv) & 1ull)) v = -1e30f;
                    scv[j][q] = v;
                }
            }

            // ---- online softmax: in-lane + 2 shfl_xor; defer-max THR=8 ----
            float pmax = scv[0][0];
            #pragma unroll
            for (int j = 0; j < 4; j++)
                #pragma unroll
                for (int q = 0; q < 4; q++) pmax = fmaxf(pmax, scv[j][q]);
            pmax = fmaxf(pmax, __shfl_xor(pmax, 16, 64));
            pmax = fmaxf(pmax, __shfl_xor(pmax, 32, 64));
            bool skip = __all(pmax <= m_ + 8.f);
            if (!skip) {
                float mnew = fmaxf(m_, pmax);
                float rf = __expf(m_ - mnew);
                l_ *= rf;
                m_ = mnew;
                #pragma unroll
                for (int q = 0; q < 4; q++) {
                    float rfr = __shfl(rf, g4 * 4 + q, 64);
                    #pragma unroll
                    for (int j = 0; j < 4; j++) acc[j][q] *= rfr;
                }
            }
            float rs = 0.f;
            #pragma unroll
            for (int j = 0; j < 4; j++)
                #pragma unroll
                for (int q = 0; q < 4; q++) {
                    float pv = __expf(scv[j][q] - m_);
                    scv[j][q] = pv;
                    rs += pv;
                }
            rs += __shfl_xor(rs, 16, 64);
            rs += __shfl_xor(rs, 32, 64);
            l_ += rs;

            // ---- P -> LDS in A-frag layout (bf16x4 packs) ----
            #pragma unroll
            for (int j = 0; j < 4; j++) {
                bf16x4 pk;
                #pragma unroll
                for (int q = 0; q < 4; q++) pk[q] = (bf16_t)scv[j][q];
                *(bf16x4*)&Pl[wv][r16][j * 16 + g4 * 4] = pk;
            }
            asm volatile("s_waitcnt lgkmcnt(0)" ::: "memory");
            __builtin_amdgcn_sched_barrier(0);

            // ---- PV: 8 MFMA ----
            __builtin_amdgcn_s_setprio(1);
            #pragma unroll
            for (int c = 0; c < 2; c++) {
                bf16x8 pa = *(const bf16x8*)&Pl[wv][r16][c * 32 + g4 * 8];
                #pragma unroll
                for (int j = 0; j < 4; j++) {
                    bf16x8 bv = *(const bf16x8*)&Vl[wg][j * 16 + r16][c * 32 + g4 * 8];
                    acc[j] = __builtin_amdgcn_mfma_f32_16x16x32_bf16(pa, bv, acc[j], 0, 0, 0);
                }
            }
            __builtin_amdgcn_s_setprio(0);
        }
        __syncthreads();                      // (B) all reads done -> next writes safe
    }

    // ---- merge group 1 state into group 0 via LDS (reuses Kl region) ----
    float* accS = (float*)&Kl[0][0][0];
    float* mlS  = accS + 64 * 64;
    if (wg == 1) {
        #pragma unroll
        for (int j = 0; j < 4; j++)
            #pragma unroll
            for (int q = 0; q < 4; q++)
                accS[(wq4 * 16 + g4 * 4 + q) * 64 + j * 16 + r16] = acc[j][q];
        if (g4 == 0) {
            mlS[(wq4 * 16 + r16) * 2 + 0] = m_;
            mlS[(wq4 * 16 + r16) * 2 + 1] = l_;
        }
    }
    __syncthreads();
    if (wg == 0) {
        bf16_t* aob = ao + ((long)(b * Tn + qt * 64 + wq4 * 16 + g4 * 4)) * Cdim + h * 64;
        #pragma unroll
        for (int q = 0; q < 4; q++) {
            int row = wq4 * 16 + g4 * 4 + q;
            float mA = __shfl(m_, g4 * 4 + q, 64);
            float lA = __shfl(l_, g4 * 4 + q, 64);
            float mB = mlS[row * 2], lB = mlS[row * 2 + 1];
            float mS = fmaxf(mA, mB);
            float fA = __expf(mA - mS), fB = __expf(mB - mS);
            float lS = lA * fA + lB * fB;
            float inv = 1.f / lS;
            #pragma unroll
            for (int j = 0; j < 4; j++) {
                float o = (acc[j][q] * fA + accS[row * 64 + j * 16 + r16] * fB) * inv;
                aob[(long)q * Cdim + j * 16 + r16] = (bf16_t)o;
            }
        }
    }
}

// ================================ host orchestration ================================
static void run_attn(hipStream_t stream, const bf16_t* hq, const bf16_t* hkv,
    const bf16_t* wqkv, const float* bo, const bf16_t* wo_t,
    float* xres, const int* mask, bool causal,
    bf16_t* qkv, bf16_t* vt, bf16_t* ao)
{
    dim3 blk(256);
    // fused qkv projection: N=1536 (cols<512 read hq, else hkv); v-part -> vt.
    // COAL epilogue (bounce for q/k tiles, vectorized scatter for v tiles), XCD swizzle.
    mgemm_k<64,128,64,4,false,false,false,true,true,32,false,true><<<dim3(12, 32, 1), blk, 0, stream>>>(
        hq, hkv, 512, wqkv, nullptr, nullptr, qkv, nullptr, vt, 1024,
        Cdim, Cdim, Cdim, 1536);
    if (causal)
        flash_k<true,false><<<dim3(Tn / 64, Bn * Hn), dim3(512), 0, stream>>>(qkv, vt, nullptr, ao);
    else
        flash_k<false,true><<<dim3(Tn / 64, Bn * Hn), dim3(512), 0, stream>>>(qkv, vt, mask, ao);
    // out projection + bias + residual (f32, in place on xres) — coalesced epilogue
    mgemm_k<64,64,64,4,true,false,true,false,false,0,false,true><<<dim3(8, 32, 1), blk, 0, stream>>>(
        ao, ao, 1 << 30, wo_t, bo, xres, xres, nullptr, nullptr, 1 << 30,
        Cdim, Cdim, Cdim, Cdim);
}

extern "C" void kernel_launch(void* const* d_in, const int* in_sizes, int n_in,
                              void* d_out, int out_size, void* d_ws, size_t ws_size,
                              hipStream_t stream)
{
    (void)in_sizes; (void)n_in; (void)out_size; (void)ws_size;
    const int*   enc_inp  = (const int*)d_in[0];
    const int*   dec_inp  = (const int*)d_in[1];
    const int*   enc_mask = (const int*)d_in[2];
    const float* tok_emb  = (const float*)d_in[3];
    const float* pos_emb  = (const float*)d_in[4];
    const float* e_wq  = (const float*)d_in[5];
    const float* e_wk  = (const float*)d_in[6];
    const float* e_wv  = (const float*)d_in[7];
    const float* e_wo  = (const float*)d_in[8];
    const float* e_bo  = (const float*)d_in[9];
    const float* dsa_wq = (const float*)d_in[10];
    const float* dsa_wk = (const float*)d_in[11];
    const float* dsa_wv = (const float*)d_in[12];
    const float* dsa_wo = (const float*)d_in[13];
    const float* dsa_bo = (const float*)d_in[14];
    const float* dca_wq = (const float*)d_in[15];
    const float* dca_wk = (const float*)d_in[16];
    const float* dca_wv = (const float*)d_in[17];
    const float* dca_wo = (const float*)d_in[18];
    const float* dca_bo = (const float*)d_in[19];
    const float* e_ln1_g = (const float*)d_in[20];
    const float* e_ln1_b = (const float*)d_in[21];
    const float* e_ln2_g = (const float*)d_in[22];
    const float* e_ln2_b = (const float*)d_in[23];
    const float* d_ln1_g = (const float*)d_in[24];
    const float* d_ln1_b = (const float*)d_in[25];
    const float* d_ln2_g = (const float*)d_in[26];
    const float* d_ln2_b = (const float*)d_in[27];
    const float* d_ln3_g = (const float*)d_in[28];
    const float* d_ln3_b = (const float*)d_in[29];
    const float* e_w1 = (const float*)d_in[30];
    const float* e_b1 = (const float*)d_in[31];
    const float* e_w2 = (const float*)d_in[32];
    const float* e_b2 = (const float*)d_in[33];
    const float* d_w1 = (const float*)d_in[34];
    const float* d_b1 = (const float*)d_in[35];
    const float* d_w2 = (const float*)d_in[36];
    const float* d_b2 = (const float*)d_in[37];
    const float* out_w = (const float*)d_in[38];
    const float* out_b = (const float*)d_in[39];
    float* out = (float*)d_out;

    // -------- workspace carve (bytes) --------
    char* p = (char*)d_ws;
    auto takeB = [&](size_t bytes) { char* r = p; p += (bytes + 255) & ~(size_t)255; return r; };
    float*  x_enc = (float*)takeB(1048576ull * 4);
    float*  x_dec = (float*)takeB(1048576ull * 4);
    bf16_t* h     = (bf16_t*)takeB(1048576ull * 2);
    bf16_t* hk    = (bf16_t*)takeB(1048576ull * 2);
    bf16_t* qkv   = (bf16_t*)takeB(3145728ull * 2);
    bf16_t* vt    = (bf16_t*)takeB(1048576ull * 2);
    bf16_t* ao    = (bf16_t*)takeB(1048576ull * 2);
    bf16_t* xdb   = (bf16_t*)takeB(1048576ull * 2);
    bf16_t* mid   = (bf16_t*)takeB(4194304ull * 2);
    bf16_t* wqkv_t = (bf16_t*)takeB(12ull * 786432 * 2);
    bf16_t* wo_t   = (bf16_t*)takeB(12ull * 262144 * 2);
    bf16_t* w1_t   = (bf16_t*)takeB(8ull * 1048576 * 2);
    bf16_t* w2_t   = (bf16_t*)takeB(8ull * 1048576 * 2);
    bf16_t* outw_t = (bf16_t*)takeB(16384000ull * 2);

    dim3 blk(256);
    const long LQKV = 1536L * Cdim;

    // ================= weight prep (5 launches) =================
    QkvSrc qs;
    qs.p[0] = e_wq;   qs.p[1] = e_wk;   qs.p[2] = e_wv;
    qs.p[3] = dsa_wq; qs.p[4] = dsa_wk; qs.p[5] = dsa_wv;
    qs.p[6] = dca_wq; qs.p[7] = dca_wk; qs.p[8] = dca_wv;
    tcvt_qkv_k<<<dim3(1, 8, 288), blk, 0, stream>>>(qs, wqkv_t);
    Ptr3 pw;
    pw.p[0] = e_wo; pw.p[1] = dsa_wo; pw.p[2] = dca_wo;
    tcvt_b_k<<<dim3(8, 8, 12), blk, 0, stream>>>(pw, wo_t, Cdim, Cdim, 4, (long)Cdim * Cdim);
    pw.p[0] = e_w1; pw.p[1] = d_w1; pw.p[2] = nullptr;
    tcvt_b_k<<<dim3(32, 8, 8), blk, 0, stream>>>(pw, w1_t, Cdim, FF, 4, (long)Cdim * FF);
    pw.p[0] = e_w2; pw.p[1] = d_w2; pw.p[2] = nullptr;
    tcvt_b_k<<<dim3(8, 32, 8), blk, 0, stream>>>(pw, w2_t, FF, Cdim, 4, (long)FF * Cdim);
    pw.p[0] = out_w; pw.p[1] = nullptr; pw.p[2] = nullptr;
    tcvt_b_k<<<dim3(500, 8, 1), blk, 0, stream>>>(pw, outw_t, Cdim, Vn, 1, 0);

    // ================= encoder =================
    embed_ln_k<<<NTOK / 4, blk, 0, stream>>>(enc_inp, tok_emb, pos_emb, e_ln1_g, e_ln1_b, x_enc, h);
    for (int l = 0; l < Ld; l++) {
        if (l) ln_k<<<NTOK / 4, blk, 0, stream>>>(x_enc, e_ln1_g + l * Cdim, e_ln1_b + l * Cdim, h);
        run_attn(stream, h, h,
                 wqkv_t + (long)l * LQKV, e_bo + l * Cdim, wo_t + (long)l * Cdim * Cdim,
                 x_enc, enc_mask, /*causal=*/false, qkv, vt, ao);
        ln_k<<<NTOK / 4, blk, 0, stream>>>(x_enc, e_ln2_g + l * Cdim, e_ln2_b + l * Cdim, h);
        mgemm_k<128,128,64,4,true,true,false,true,false,16,false,true><<<dim3(16, 16, 1), blk, 0, stream>>>(
            h, h, 1 << 30, w1_t + (long)l * Cdim * FF, e_b1 + l * FF, nullptr, mid,
            nullptr, nullptr, 1 << 30, Cdim, Cdim, Cdim, FF);
        mgemm_k<64,64,64,4,true,false,true,false,false,0,false,true><<<dim3(8, 32, 1), blk, 0, stream>>>(
            mid, mid, 1 << 30, w2_t + (long)l * FF * Cdim, e_b2 + l * Cdim, x_enc, x_enc,
            nullptr, nullptr, 1 << 30, FF, FF, FF, Cdim);
    }
    // x_enc now holds enc_out

    // ================= decoder =================
    embed_ln_k<<<NTOK / 4, blk, 0, stream>>>(dec_inp, tok_emb, pos_emb, d_ln1_g, d_ln1_b, x_dec, h);
    for (int l = 0; l < Ld; l++) {
        // causal self-attention
        if (l) ln_k<<<NTOK / 4, blk, 0, stream>>>(x_dec, d_ln1_g + l * Cdim, d_ln1_b + l * Cdim, h);
        run_attn(stream, h, h,
                 wqkv_t + (long)(Ld + l) * LQKV, dsa_bo + l * Cdim,
                 wo_t + (long)(Ld + l) * Cdim * Cdim,
                 x_dec, nullptr, /*causal=*/true, qkv, vt, ao);
        // cross-attention (same LN applied to x and enc_out) — one fused launch
        ln2_k<<<2 * NTOK / 4, blk, 0, stream>>>(x_dec, x_enc,
            d_ln2_g + l * Cdim, d_ln2_b + l * Cdim, h, hk);
        run_attn(stream, h, hk,
                 wqkv_t + (long)(2 * Ld + l) * LQKV, dca_bo + l * Cdim,
                 wo_t + (long)(2 * Ld + l) * Cdim * Cdim,
                 x_dec, enc_mask, /*causal=*/false, qkv, vt, ao);
        // FFN
        ln_k<<<NTOK / 4, blk, 0, stream>>>(x_dec, d_ln3_g + l * Cdim, d_ln3_b + l * Cdim, h);
        mgemm_k<128,128,64,4,true,true,false,true,false,16,false,true><<<dim3(16, 16, 1), blk, 0, stream>>>(
            h, h, 1 << 30, w1_t + (long)(Ld + l) * Cdim * FF, d_b1 + l * FF, nullptr, mid,
            nullptr, nullptr, 1 << 30, Cdim, Cdim, Cdim, FF);
        if (l < Ld - 1)
            mgemm_k<64,64,64,4,true,false,true,false,false,0,false,true><<<dim3(8, 32, 1), blk, 0, stream>>>(
                mid, mid, 1 << 30, w2_t + (long)(Ld + l) * FF * Cdim, d_b2 + l * Cdim, x_dec, x_dec,
                nullptr, nullptr, 1 << 30, FF, FF, FF, Cdim);
        else  // last layer: also emit bf16 copy for logits GEMM
            mgemm_k<64,64,64,4,true,false,true,false,false,0,true,true><<<dim3(8, 32, 1), blk, 0, stream>>>(
                mid, mid, 1 << 30, w2_t + (long)(Ld + l) * FF * Cdim, d_b2 + l * Cdim, x_dec, x_dec,
                xdb, nullptr, 1 << 30, FF, FF, FF, Cdim);
    }

    // ================= final logits (f32 out, 256x256 tile, 8 waves, XCD-swizzled) ==========
    mgemm_k<256,256,64,8,true,false,false,false,false,8,false,true><<<dim3(125, 8, 1), dim3(512), 0, stream>>>(
        xdb, xdb, 1 << 30, outw_t, out_b, nullptr, out, nullptr, nullptr, 1 << 30,
        Cdim, Cdim, Cdim, Vn);
}

// Round 16
// 929.254 us; speedup vs baseline: 1.3537x; 1.0009x over previous
//
#include <hip/hip_runtime.h>
#include <hip/hip_bf16.h>
#include <math.h>

#define Cdim 512
#define Hn   8
#define HDim 64
#define Ld   4
#define Tn   1024
#define Bn   2
#define NTOK 2048   // B*T
#define FF   2048   // 4*C
#define Vn   32000

typedef __bf16 bf16_t;
typedef __bf16 bf16x8 __attribute__((ext_vector_type(8)));
typedef __bf16 bf16x4 __attribute__((ext_vector_type(4)));
typedef float  f32x4  __attribute__((ext_vector_type(4)));

// ---------------- layernorm: one wave per row, 4 rows/block, no barriers ----------------
__device__ __forceinline__ void ln_wave(const float* __restrict__ xr,
    const float* __restrict__ g, const float* __restrict__ bb,
    bf16_t* __restrict__ yr, int lane)
{
    f32x4 a = *(const f32x4*)&xr[lane * 8];
    f32x4 c = *(const f32x4*)&xr[lane * 8 + 4];
    float s = a[0] + a[1] + a[2] + a[3] + c[0] + c[1] + c[2] + c[3];
    #pragma unroll
    for (int o = 1; o < 64; o <<= 1) s += __shfl_xor(s, o, 64);
    float mean = s * (1.f / Cdim);
    float d[8], qv = 0.f;
    #pragma unroll
    for (int k = 0; k < 4; k++) { d[k] = a[k] - mean; d[4 + k] = c[k] - mean; }
    #pragma unroll
    for (int k = 0; k < 8; k++) qv += d[k] * d[k];
    #pragma unroll
    for (int o = 1; o < 64; o <<= 1) qv += __shfl_xor(qv, o, 64);
    float inv = rsqrtf(qv * (1.f / Cdim) + 1e-5f);
    f32x4 g0 = *(const f32x4*)&g[lane * 8],  g1 = *(const f32x4*)&g[lane * 8 + 4];
    f32x4 b0 = *(const f32x4*)&bb[lane * 8], b1 = *(const f32x4*)&bb[lane * 8 + 4];
    bf16x8 o;
    #pragma unroll
    for (int k = 0; k < 4; k++) {
        o[k]     = (bf16_t)(d[k]     * inv * g0[k] + b0[k]);
        o[4 + k] = (bf16_t)(d[4 + k] * inv * g1[k] + b1[k]);
    }
    *(bf16x8*)&yr[lane * 8] = o;
}

__global__ __launch_bounds__(256) void ln_k(const float* __restrict__ x,
    const float* __restrict__ g, const float* __restrict__ bb, bf16_t* __restrict__ y)
{
    int wid = threadIdx.x >> 6, lane = threadIdx.x & 63;
    int row = blockIdx.x * 4 + wid;
    ln_wave(x + (long)row * Cdim, g, bb, y + (long)row * Cdim, lane);
}

// two-source LN (cross-attention): rows < NTOK from x1->y1, else x2->y2 (same g,b)
__global__ __launch_bounds__(256) void ln2_k(const float* __restrict__ x1,
    const float* __restrict__ x2, const float* __restrict__ g,
    const float* __restrict__ bb, bf16_t* __restrict__ y1, bf16_t* __restrict__ y2)
{
    int wid = threadIdx.x >> 6, lane = threadIdx.x & 63;
    int row = blockIdx.x * 4 + wid;
    const float* x = (row < NTOK) ? x1 : x2;
    bf16_t*      y = (row < NTOK) ? y1 : y2;
    int r = row & (NTOK - 1);
    ln_wave(x + (long)r * Cdim, g, bb, y + (long)r * Cdim, lane);
}

// ------- fused dual embedding + first-layer LN: enc rows -> (x_enc, h), dec -> (x_dec, hk) -------
__global__ __launch_bounds__(256) void embed2_ln_k(const int* __restrict__ enc_inp,
    const int* __restrict__ dec_inp, const float* __restrict__ tok,
    const float* __restrict__ pos,
    const float* __restrict__ ge, const float* __restrict__ be,
    const float* __restrict__ gd, const float* __restrict__ bd,
    float* __restrict__ x_enc, float* __restrict__ x_dec,
    bf16_t* __restrict__ h, bf16_t* __restrict__ hk)
{
    int wid = threadIdx.x >> 6, lane = threadIdx.x & 63;
    int row = blockIdx.x * 4 + wid;
    bool enc = row < NTOK;
    const int* inp = enc ? enc_inp : dec_inp;
    float* x       = enc ? x_enc   : x_dec;
    bf16_t* y      = enc ? h       : hk;
    const float* g = enc ? ge : gd;
    const float* bb = enc ? be : bd;
    int bt = row & (NTOK - 1);
    int t = bt & (Tn - 1);
    long toff = (long)inp[bt] * Cdim;
    f32x4 a = *(const f32x4*)&tok[toff + lane * 8];
    f32x4 c = *(const f32x4*)&tok[toff + lane * 8 + 4];
    a += *(const f32x4*)&pos[(long)t * Cdim + lane * 8];
    c += *(const f32x4*)&pos[(long)t * Cdim + lane * 8 + 4];
    float* xr = x + (long)bt * Cdim;
    *(f32x4*)&xr[lane * 8] = a;
    *(f32x4*)&xr[lane * 8 + 4] = c;
    float s = a[0] + a[1] + a[2] + a[3] + c[0] + c[1] + c[2] + c[3];
    #pragma unroll
    for (int o = 1; o < 64; o <<= 1) s += __shfl_xor(s, o, 64);
    float mean = s * (1.f / Cdim);
    float d[8], qv = 0.f;
    #pragma unroll
    for (int k = 0; k < 4; k++) { d[k] = a[k] - mean; d[4 + k] = c[k] - mean; }
    #pragma unroll
    for (int k = 0; k < 8; k++) qv += d[k] * d[k];
    #pragma unroll
    for (int o = 1; o < 64; o <<= 1) qv += __shfl_xor(qv, o, 64);
    float inv = rsqrtf(qv * (1.f / Cdim) + 1e-5f);
    f32x4 g0 = *(const f32x4*)&g[lane * 8],  g1 = *(const f32x4*)&g[lane * 8 + 4];
    f32x4 b0 = *(const f32x4*)&bb[lane * 8], b1 = *(const f32x4*)&bb[lane * 8 + 4];
    bf16x8 o;
    #pragma unroll
    for (int k = 0; k < 4; k++) {
        o[k]     = (bf16_t)(d[k]     * inv * g0[k] + b0[k]);
        o[4 + k] = (bf16_t)(d[4 + k] * inv * g1[k] + b1[k]);
    }
    *(bf16x8*)&y[(long)bt * Cdim + lane * 8] = o;
}

// ------- batched tiled transpose+convert: f32 [R,Cc] -> bf16 [Cc,R] over z sources/layers -------
struct Ptr3 { const float* p[3]; };
__global__ __launch_bounds__(256) void tcvt_b_k(Ptr3 srcs, bf16_t* __restrict__ dst,
    int R, int Cc, int lps, long dstStride)
{
    int z = blockIdx.z; int s = z / lps, l = z - s * lps;
    const float* in = srcs.p[s] + (long)l * R * Cc;
    bf16_t* op = dst + (long)z * dstStride;
    __shared__ float t[64][65];
    int r0 = blockIdx.y * 64, c0 = blockIdx.x * 64;
    int tx = threadIdx.x & 63, ty = threadIdx.x >> 6;
    #pragma unroll
    for (int i = 0; i < 16; i++)
        t[ty + i * 4][tx] = in[(long)(r0 + ty + i * 4) * Cc + c0 + tx];
    __syncthreads();
    #pragma unroll
    for (int i = 0; i < 16; i++) {
        int cc = ty + i * 4;
        op[(long)(c0 + cc) * R + r0 + tx] = (bf16_t)t[tx][cc];
    }
}

// ------- fused QKV weight prep: 9 (set,part) sources in one launch -------
struct QkvSrc { const float* p[9]; };
__global__ __launch_bounds__(256) void tcvt_qkv_k(QkvSrc srcs, bf16_t* __restrict__ outp)
{
    int z = blockIdx.z;
    int si = z >> 5, zb = (z >> 3) & 3, zh = z & 7;
    int set = si / 3, part = si - set * 3;
    const float* in = srcs.p[si] + (long)zb * (Hn * Cdim * HDim) + (long)zh * (Cdim * HDim);
    bf16_t* op = outp + ((long)set * Ld + zb) * (1536L * Cdim)
                      + (long)part * 512 * Cdim + (long)zh * 64 * Cdim;
    __shared__ float t[64][65];
    int r0 = blockIdx.y * 64;
    int tx = threadIdx.x & 63, ty = threadIdx.x >> 6;
    #pragma unroll
    for (int i = 0; i < 16; i++)
        t[ty + i * 4][tx] = in[(long)(r0 + ty + i * 4) * HDim + tx];
    __syncthreads();
    #pragma unroll
    for (int i = 0; i < 16; i++) {
        int cc = ty + i * 4;
        op[(long)cc * Cdim + r0 + tx] = (bf16_t)t[tx][cc];
    }
}

// ================= bf16 MFMA GEMM, double-buffered K pipeline =================
// WAVES=4 (2x2) or WAVES=8 (2x4, 512 thr, 256^2 tiles). Chunk-XOR LDS swizzle.
// Separate As0/As1/Bs0/Bs1 arrays (compile-time distinct -> stage latency hides).
// COAL epilogue bounce aliases into Bs0 when it fits (post-barrier), else cws.
// VOUT+COAL: v-tiles (bn>=vSplit, tile-aligned) use vectorized bf16x4 scatter.
template<int BM, int BN, int BK, int WAVES, bool BIAS, bool RELU, bool RES, bool OBF,
         bool VOUT, int SWZM, bool XOUT, bool COAL>
__global__ __launch_bounds__(WAVES * 64) void mgemm_k(
    const bf16_t* __restrict__ A, const bf16_t* __restrict__ A2, int aSplit,
    const bf16_t* __restrict__ Bt, const float* __restrict__ bias,
    const float* __restrict__ res, void* __restrict__ Cout,
    bf16_t* __restrict__ xout, bf16_t* __restrict__ vtout, int vSplit,
    int K, int lda, int ldb, int ldc)
{
    constexpr int NT  = WAVES * 64;
    constexpr int WC_ = WAVES / 2;          // wave grid: 2 x WC_
    constexpr int BNW = BN / WC_;           // per-wave N extent
    constexpr int MR = BM / 32;             // (BM/2)/16
    constexpr int NR = BNW / 16;
    constexpr int KK = BK / 32;
    constexpr int LPR = BK / 8;             // 16B chunks per LDS row
    constexpr int RW  = 64 / LPR;           // rows staged per wave per pass
    constexpr int RPASS = NT / LPR;         // rows staged per pass (all waves)
    constexpr bool ALIAS = COAL && (BN * BK * 2 >= WAVES * 16 * 36 * 4);
    __shared__ bf16_t As0[BM * BK];
    __shared__ bf16_t As1[BM * BK];
    __shared__ bf16_t Bs0[BN * BK];
    __shared__ bf16_t Bs1[BN * BK];
    __shared__ float cws[(COAL && !ALIAS) ? WAVES * 16 * 36 : 1];

    int tid = threadIdx.x;
    int wv = tid >> 6, lane = tid & 63;
    int bm, bn;
    if constexpr (SWZM > 0) {
        int lin = blockIdx.y * gridDim.x + blockIdx.x;
        int tot = gridDim.x * gridDim.y;
        int chunk = tot >> 3;
        int e = (lin & 7) * chunk + (lin >> 3);
        bm = (e % SWZM) * BM;
        bn = (e / SWZM) * BN;
    } else {
        bm = blockIdx.y * BM; bn = blockIdx.x * BN;
    }
    const bf16_t* Ab = (bn < aSplit) ? A : A2;
    int wr = wv / WC_, wc = wv % WC_;

    f32x4 acc[MR][NR];
    #pragma unroll
    for (int i = 0; i < MR; i++)
        #pragma unroll
        for (int j = 0; j < NR; j++)
            acc[i][j] = (f32x4){0.f, 0.f, 0.f, 0.f};

    const int sr  = lane / LPR;
    const int sc8 = ((lane % LPR) ^ (sr & (LPR - 1))) * 8;
    const int r16 = lane & 15, g4 = lane >> 4;

    auto stage = [&](int k0, bf16_t (&Asb)[BM * BK], bf16_t (&Bsb)[BN * BK]) {
        #pragma unroll
        for (int p = 0; p < BM / RPASS; p++) {
            int rb = p * RPASS + wv * RW;
            const bf16_t* g = Ab + (long)(bm + rb + sr) * lda + (k0 + sc8);
            __builtin_amdgcn_global_load_lds(
                (const __attribute__((address_space(1))) void*)g,
                (__attribute__((address_space(3))) void*)&Asb[rb * BK],
                16, 0, 0);
        }
        #pragma unroll
        for (int p = 0; p < BN / RPASS; p++) {
            int rb = p * RPASS + wv * RW;
            const bf16_t* g = Bt + (long)(bn + rb + sr) * ldb + (k0 + sc8);
            __builtin_amdgcn_global_load_lds(
                (const __attribute__((address_space(1))) void*)g,
                (__attribute__((address_space(3))) void*)&Bsb[rb * BK],
                16, 0, 0);
        }
    };
    auto compute = [&](bf16_t (&Asb)[BM * BK], bf16_t (&Bsb)[BN * BK]) {
        #pragma unroll
        for (int kk = 0; kk < KK; kk++) {
            bf16x8 bkk[NR];
            #pragma unroll
            for (int j = 0; j < NR; j++) {
                int row = wc * BNW + j * 16 + r16;
                bkk[j] = *(const bf16x8*)&Bsb[row * BK + (((kk * 4 + g4) ^ (row & (LPR - 1))) * 8)];
            }
            #pragma unroll
            for (int i = 0; i < MR; i++) {
                int row = wr * (BM / 2) + i * 16 + r16;
                bf16x8 a = *(const bf16x8*)&Asb[row * BK + (((kk * 4 + g4) ^ (row & (LPR - 1))) * 8)];
                #pragma unroll
                for (int j = 0; j < NR; j++)
                    acc[i][j] = __builtin_amdgcn_mfma_f32_16x16x32_bf16(a, bkk[j], acc[i][j], 0, 0, 0);
            }
        }
    };

    int nIt = K / BK;
    stage(0, As0, Bs0);
    for (int it = 0; it < nIt; it += 2) {
        __syncthreads();                               // As0/Bs0 staged; prior reads done
        if (it + 1 < nIt) stage((it + 1) * BK, As1, Bs1);
        compute(As0, Bs0);
        __syncthreads();                               // As1/Bs1 staged; As0 reads done
        if (it + 2 < nIt) stage((it + 2) * BK, As0, Bs0);
        if (it + 1 < nIt) compute(As1, Bs1);
    }

    if constexpr (COAL) {
        if (VOUT && bn >= vSplit) {
            // ---- vectorized V^T scatter: 4 consecutive t per lane -> bf16x4 ----
            #pragma unroll
            for (int i = 0; i < MR; i++) {
                int gr = bm + wr * (BM / 2) + i * 16 + g4 * 4;
                int b = gr >> 10, t0 = gr & (Tn - 1);
                #pragma unroll
                for (int j = 0; j < NR; j++) {
                    int dcol = bn + wc * BNW + j * 16 + r16 - vSplit;
                    bf16x4 pk;
                    #pragma unroll
                    for (int q = 0; q < 4; q++) pk[q] = (bf16_t)acc[i][j][q];
                    *(bf16x4*)&vtout[((long)b * 512 + dcol) * Tn + t0] = pk;
                }
            }
        } else {
            __syncthreads();                           // safe to reuse LDS for bounce
            float* cb = ALIAS ? (float*)Bs0 : cws;
            #pragma unroll
            for (int i = 0; i < MR; i++) {
                int gr0 = bm + wr * (BM / 2) + i * 16;
                #pragma unroll
                for (int hh = 0; hh < NR / 2; hh++) {
                    #pragma unroll
                    for (int jj = 0; jj < 2; jj++) {
                        int j = hh * 2 + jj;
                        int gc = bn + wc * BNW + j * 16 + r16;
                        float bv = BIAS ? bias[gc] : 0.f;
                        #pragma unroll
                        for (int q = 0; q < 4; q++) {
                            float v = acc[i][j][q];
                            if (BIAS) v += bv;
                            if (RELU) v = fmaxf(v, 0.f);
                            cb[(wv * 16 + g4 * 4 + q) * 36 + jj * 16 + r16] = v;
                        }
                    }
                    int gcb = bn + wc * BNW + hh * 32;
                    if constexpr (OBF) {
                        int row = lane >> 2, c8 = (lane & 3) * 8;
                        f32x4 v0 = *(f32x4*)&cb[(wv * 16 + row) * 36 + c8];
                        f32x4 v1 = *(f32x4*)&cb[(wv * 16 + row) * 36 + c8 + 4];
                        long oidx = (long)(gr0 + row) * ldc + gcb + c8;
                        bf16x8 o;
                        #pragma unroll
                        for (int k = 0; k < 4; k++) { o[k] = (bf16_t)v0[k]; o[4 + k] = (bf16_t)v1[k]; }
                        *(bf16x8*)&((bf16_t*)Cout)[oidx] = o;
                    } else {
                        #pragma unroll
                        for (int ps = 0; ps < 2; ps++) {
                            int row = (lane >> 3) + 8 * ps, c4 = (lane & 7) * 4;
                            f32x4 v = *(f32x4*)&cb[(wv * 16 + row) * 36 + c4];
                            long oidx = (long)(gr0 + row) * ldc + gcb + c4;
                            if (RES) v += *(const f32x4*)&res[oidx];
                            *(f32x4*)&((float*)Cout)[oidx] = v;
                            if (XOUT) {
                                bf16x4 o;
                                #pragma unroll
                                for (int k = 0; k < 4; k++) o[k] = (bf16_t)v[k];
                                *(bf16x4*)&xout[oidx] = o;
                            }
                        }
                    }
                }
            }
        }
    } else {
        // ---- scalar epilogue (fallback) ----
        #pragma unroll
        for (int i = 0; i < MR; i++) {
            #pragma unroll
            for (int j = 0; j < NR; j++) {
                int gr = bm + wr * (BM / 2) + i * 16 + g4 * 4;
                int gc = bn + wc * BNW + j * 16 + r16;
                float bv = BIAS ? bias[gc] : 0.f;
                #pragma unroll
                for (int q = 0; q < 4; q++) {
                    float v = acc[i][j][q];
                    if (BIAS) v += bv;
                    if (RELU) v = fmaxf(v, 0.f);
                    if (VOUT && gc >= vSplit) {
                        int row = gr + q;
                        int b = row >> 10, t = row & (Tn - 1);
                        vtout[((long)b * 512 + (gc - vSplit)) * Tn + t] = (bf16_t)v;
                    } else {
                        long oidx = (long)(gr + q) * ldc + gc;
                        if (RES)  v += res[oidx];
                        if (OBF) ((bf16_t*)Cout)[oidx] = (bf16_t)v;
                        else     ((float*) Cout)[oidx] = v;
                        if (XOUT) xout[oidx] = (bf16_t)v;
                    }
                }
            }
        }
    }
}

// ======= fused flash attention, swapped-QK^T, single-buffer K/V, 2 blocks/CU ==========
// Scores kept in RAW units (scale folded into exp arg): saves the scale pass.
template<bool CAUSAL, bool HASMASK>
__global__ __launch_bounds__(512, 4) void flash_k(
    const bf16_t* __restrict__ qkv, const bf16_t* __restrict__ vt,
    const int* __restrict__ mask, bf16_t* __restrict__ ao)
{
    __shared__ bf16_t Kl[2][64][72];
    __shared__ bf16_t Vl[2][64][72];
    __shared__ bf16_t Pl[8][16][72];

    int qt = blockIdx.x, bh = blockIdx.y;
    int b = bh >> 3, h = bh & 7;
    int tid = threadIdx.x, wv = tid >> 6, lane = tid & 63;
    int wg = wv >> 2, wq4 = wv & 3;
    int r16 = lane & 15, g4 = lane >> 4;
    int gtid = tid & 255;

    const bf16_t* qb = qkv + ((long)(b * Tn + qt * 64 + wq4 * 16 + r16)) * 1536 + h * 64;
    bf16x8 aq0 = *(const bf16x8*)&qb[g4 * 8];
    bf16x8 aq1 = *(const bf16x8*)&qb[32 + g4 * 8];

    f32x4 acc[4];
    #pragma unroll
    for (int j = 0; j < 4; j++) acc[j] = (f32x4){0.f, 0.f, 0.f, 0.f};
    float m_ = -1e30f, l_ = 0.f;       // raw-units state for q-col = r16

    int lastT = CAUSAL ? qt : (Tn / 64 - 1);
    int niter = CAUSAL ? (qt / 2 + 1) : (Tn / 128);
    int krow = gtid >> 3, kcol = (gtid & 7) * 8;

    bf16x8 kr[2], vr[2];
    unsigned long long mvb = 0;
    {
        int t0 = wg;
        if (t0 <= lastT) {
            int s0 = t0 * 64;
            #pragma unroll
            for (int i = 0; i < 2; i++)
                kr[i] = *(const bf16x8*)&qkv[((long)(b * Tn + s0 + krow + i * 32)) * 1536 + 512 + h * 64 + kcol];
            #pragma unroll
            for (int i = 0; i < 2; i++)
                vr[i] = *(const bf16x8*)&vt[((long)(bh * 64 + krow + i * 32)) * Tn + s0 + kcol];
            if (HASMASK) mvb = __ballot(mask[b * Tn + s0 + lane] != 0);
        }
    }

    for (int it = 0; it < niter; it++) {
        int t = 2 * it + wg;
        bool active = t <= lastT;
        if (active) {
            #pragma unroll
            for (int i = 0; i < 2; i++) *(bf16x8*)&Kl[wg][krow + i * 32][kcol] = kr[i];
            #pragma unroll
            for (int i = 0; i < 2; i++) *(bf16x8*)&Vl[wg][krow + i * 32][kcol] = vr[i];
        }
        unsigned long long mvb_use = mvb;
        __syncthreads();                      // (A) tiles visible
        int tn = t + 2;
        if (it + 1 < niter && tn <= lastT) {  // prefetch next tile into regs
            int sn = tn * 64;
            #pragma unroll
            for (int i = 0; i < 2; i++)
                kr[i] = *(const bf16x8*)&qkv[((long)(b * Tn + sn + krow + i * 32)) * 1536 + 512 + h * 64 + kcol];
            #pragma unroll
            for (int i = 0; i < 2; i++)
                vr[i] = *(const bf16x8*)&vt[((long)(bh * 64 + krow + i * 32)) * Tn + sn + kcol];
            if (HASMASK) mvb = __ballot(mask[b * Tn + sn + lane] != 0);
        }
        if (active) {
            // ---- S^T = K · Q^T : 8 MFMA (raw scores) ----
            f32x4 scv[4];
            __builtin_amdgcn_s_setprio(1);
            #pragma unroll
            for (int j = 0; j < 4; j++) {
                scv[j] = (f32x4){0.f, 0.f, 0.f, 0.f};
                bf16x8 bk0 = *(const bf16x8*)&Kl[wg][j * 16 + r16][g4 * 8];
                bf16x8 bk1 = *(const bf16x8*)&Kl[wg][j * 16 + r16][32 + g4 * 8];
                scv[j] = __builtin_amdgcn_mfma_f32_16x16x32_bf16(bk0, aq0, scv[j], 0, 0, 0);
                scv[j] = __builtin_amdgcn_mfma_f32_16x16x32_bf16(bk1, aq1, scv[j], 0, 0, 0);
            }
            __builtin_amdgcn_s_setprio(0);

            // ---- mask only (raw units): element (j,q) is S[kv = j*16+g4*4+q][qcol = r16] ----
            bool diag = CAUSAL && (t == qt);
            int qloc = wq4 * 16 + r16;
            if (diag || HASMASK) {
                #pragma unroll
                for (int j = 0; j < 4; j++) {
                    #pragma unroll
                    for (int q = 0; q < 4; q++) {
                        int kv = j * 16 + g4 * 4 + q;
                        bool dead = (diag && kv > qloc) ||
                                    (HASMASK && !((mvb_use >> kv) & 1ull));
                        if (dead) scv[j][q] = -1e30f;
                    }
                }
            }

            // ---- online softmax (raw units; scale folded into exp arg) ----
            float pmax = scv[0][0];
            #pragma unroll
            for (int j = 0; j < 4; j++)
                #pragma unroll
                for (int q = 0; q < 4; q++) pmax = fmaxf(pmax, scv[j][q]);
            pmax = fmaxf(pmax, __shfl_xor(pmax, 16, 64));
            pmax = fmaxf(pmax, __shfl_xor(pmax, 32, 64));
            bool skip = __all(pmax <= m_ + 64.f);      // 8 in scaled units
            if (!skip) {
                float mnew = fmaxf(m_, pmax);
                float rf = __expf((m_ - mnew) * 0.125f);
                l_ *= rf;
                m_ = mnew;
                #pragma unroll
                for (int q = 0; q < 4; q++) {
                    float rfr = __shfl(rf, g4 * 4 + q, 64);
                    #pragma unroll
                    for (int j = 0; j < 4; j++) acc[j][q] *= rfr;
                }
            }
            float rs = 0.f;
            #pragma unroll
            for (int j = 0; j < 4; j++)
                #pragma unroll
                for (int q = 0; q < 4; q++) {
                    float pv = __expf((scv[j][q] - m_) * 0.125f);
                    scv[j][q] = pv;
                    rs += pv;
                }
            rs += __shfl_xor(rs, 16, 64);
            rs += __shfl_xor(rs, 32, 64);
            l_ += rs;

            // ---- P -> LDS in A-frag layout (bf16x4 packs) ----
            #pragma unroll
            for (int j = 0; j < 4; j++) {
                bf16x4 pk;
                #pragma unroll
                for (int q = 0; q < 4; q++) pk[q] = (bf16_t)scv[j][q];
                *(bf16x4*)&Pl[wv][r16][j * 16 + g4 * 4] = pk;
            }
            asm volatile("s_waitcnt lgkmcnt(0)" ::: "memory");
            __builtin_amdgcn_sched_barrier(0);

            // ---- PV: 8 MFMA ----
            __builtin_amdgcn_s_setprio(1);
            #pragma unroll
            for (int c = 0; c < 2; c++) {
                bf16x8 pa = *(const bf16x8*)&Pl[wv][r16][c * 32 + g4 * 8];
                #pragma unroll
                for (int j = 0; j < 4; j++) {
                    bf16x8 bv = *(const bf16x8*)&Vl[wg][j * 16 + r16][c * 32 + g4 * 8];
                    acc[j] = __builtin_amdgcn_mfma_f32_16x16x32_bf16(pa, bv, acc[j], 0, 0, 0);
                }
            }
            __builtin_amdgcn_s_setprio(0);
        }
        __syncthreads();                      // (B) all reads done -> next writes safe
    }

    // ---- merge group 1 state into group 0 via LDS (reuses Kl region) ----
    float* accS = (float*)&Kl[0][0][0];
    float* mlS  = accS + 64 * 64;
    if (wg == 1) {
        #pragma unroll
        for (int j = 0; j < 4; j++)
            #pragma unroll
            for (int q = 0; q < 4; q++)
                accS[(wq4 * 16 + g4 * 4 + q) * 64 + j * 16 + r16] = acc[j][q];
        if (g4 == 0) {
            mlS[(wq4 * 16 + r16) * 2 + 0] = m_;
            mlS[(wq4 * 16 + r16) * 2 + 1] = l_;
        }
    }
    __syncthreads();
    if (wg == 0) {
        bf16_t* aob = ao + ((long)(b * Tn + qt * 64 + wq4 * 16 + g4 * 4)) * Cdim + h * 64;
        #pragma unroll
        for (int q = 0; q < 4; q++) {
            int row = wq4 * 16 + g4 * 4 + q;
            float mA = __shfl(m_, g4 * 4 + q, 64);
            float lA = __shfl(l_, g4 * 4 + q, 64);
            float mB = mlS[row * 2], lB = mlS[row * 2 + 1];
            float mS = fmaxf(mA, mB);
            float fA = __expf((mA - mS) * 0.125f), fB = __expf((mB - mS) * 0.125f);
            float lS = lA * fA + lB * fB;
            float inv = 1.f / lS;
            #pragma unroll
            for (int j = 0; j < 4; j++) {
                float o = (acc[j][q] * fA + accS[row * 64 + j * 16 + r16] * fB) * inv;
                aob[(long)q * Cdim + j * 16 + r16] = (bf16_t)o;
            }
        }
    }
}

// ================================ host orchestration ================================
static void run_attn(hipStream_t stream, const bf16_t* hq, const bf16_t* hkv,
    const bf16_t* wqkv, const float* bo, const bf16_t* wo_t,
    float* xres, const int* mask, bool causal,
    bf16_t* qkv, bf16_t* vt, bf16_t* ao)
{
    dim3 blk(256);
    // fused qkv projection: N=1536 (cols<512 read hq, else hkv); v-part -> vt.
    mgemm_k<64,128,64,4,false,false,false,true,true,32,false,true><<<dim3(12, 32, 1), blk, 0, stream>>>(
        hq, hkv, 512, wqkv, nullptr, nullptr, qkv, nullptr, vt, 1024,
        Cdim, Cdim, Cdim, 1536);
    if (causal)
        flash_k<true,false><<<dim3(Tn / 64, Bn * Hn), dim3(512), 0, stream>>>(qkv, vt, nullptr, ao);
    else
        flash_k<false,true><<<dim3(Tn / 64, Bn * Hn), dim3(512), 0, stream>>>(qkv, vt, mask, ao);
    // out projection + bias + residual (f32, in place on xres) — coalesced, XCD-swizzled
    mgemm_k<64,64,64,4,true,false,true,false,false,32,false,true><<<dim3(8, 32, 1), blk, 0, stream>>>(
        ao, ao, 1 << 30, wo_t, bo, xres, xres, nullptr, nullptr, 1 << 30,
        Cdim, Cdim, Cdim, Cdim);
}

extern "C" void kernel_launch(void* const* d_in, const int* in_sizes, int n_in,
                              void* d_out, int out_size, void* d_ws, size_t ws_size,
                              hipStream_t stream)
{
    (void)in_sizes; (void)n_in; (void)out_size; (void)ws_size;
    const int*   enc_inp  = (const int*)d_in[0];
    const int*   dec_inp  = (const int*)d_in[1];
    const int*   enc_mask = (const int*)d_in[2];
    const float* tok_emb  = (const float*)d_in[3];
    const float* pos_emb  = (const float*)d_in[4];
    const float* e_wq  = (const float*)d_in[5];
    const float* e_wk  = (const float*)d_in[6];
    const float* e_wv  = (const float*)d_in[7];
    const float* e_wo  = (const float*)d_in[8];
    const float* e_bo  = (const float*)d_in[9];
    const float* dsa_wq = (const float*)d_in[10];
    const float* dsa_wk = (const float*)d_in[11];
    const float* dsa_wv = (const float*)d_in[12];
    const float* dsa_wo = (const float*)d_in[13];
    const float* dsa_bo = (const float*)d_in[14];
    const float* dca_wq = (const float*)d_in[15];
    const float* dca_wk = (const float*)d_in[16];
    const float* dca_wv = (const float*)d_in[17];
    const float* dca_wo = (const float*)d_in[18];
    const float* dca_bo = (const float*)d_in[19];
    const float* e_ln1_g = (const float*)d_in[20];
    const float* e_ln1_b = (const float*)d_in[21];
    const float* e_ln2_g = (const float*)d_in[22];
    const float* e_ln2_b = (const float*)d_in[23];
    const float* d_ln1_g = (const float*)d_in[24];
    const float* d_ln1_b = (const float*)d_in[25];
    const float* d_ln2_g = (const float*)d_in[26];
    const float* d_ln2_b = (const float*)d_in[27];
    const float* d_ln3_g = (const float*)d_in[28];
    const float* d_ln3_b = (const float*)d_in[29];
    const float* e_w1 = (const float*)d_in[30];
    const float* e_b1 = (const float*)d_in[31];
    const float* e_w2 = (const float*)d_in[32];
    const float* e_b2 = (const float*)d_in[33];
    const float* d_w1 = (const float*)d_in[34];
    const float* d_b1 = (const float*)d_in[35];
    const float* d_w2 = (const float*)d_in[36];
    const float* d_b2 = (const float*)d_in[37];
    const float* out_w = (const float*)d_in[38];
    const float* out_b = (const float*)d_in[39];
    float* out = (float*)d_out;

    // -------- workspace carve (bytes) --------
    char* p = (char*)d_ws;
    auto takeB = [&](size_t bytes) { char* r = p; p += (bytes + 255) & ~(size_t)255; return r; };
    float*  x_enc = (float*)takeB(1048576ull * 4);
    float*  x_dec = (float*)takeB(1048576ull * 4);
    bf16_t* h     = (bf16_t*)takeB(1048576ull * 2);
    bf16_t* hk    = (bf16_t*)takeB(1048576ull * 2);
    bf16_t* qkv   = (bf16_t*)takeB(3145728ull * 2);
    bf16_t* vt    = (bf16_t*)takeB(1048576ull * 2);
    bf16_t* ao    = (bf16_t*)takeB(1048576ull * 2);
    bf16_t* xdb   = (bf16_t*)takeB(1048576ull * 2);
    bf16_t* mid   = (bf16_t*)takeB(4194304ull * 2);
    bf16_t* wqkv_t = (bf16_t*)takeB(12ull * 786432 * 2);
    bf16_t* wo_t   = (bf16_t*)takeB(12ull * 262144 * 2);
    bf16_t* w1_t   = (bf16_t*)takeB(8ull * 1048576 * 2);
    bf16_t* w2_t   = (bf16_t*)takeB(8ull * 1048576 * 2);
    bf16_t* outw_t = (bf16_t*)takeB(16384000ull * 2);

    dim3 blk(256);
    const long LQKV = 1536L * Cdim;

    // ================= weight prep (5 launches) =================
    QkvSrc qs;
    qs.p[0] = e_wq;   qs.p[1] = e_wk;   qs.p[2] = e_wv;
    qs.p[3] = dsa_wq; qs.p[4] = dsa_wk; qs.p[5] = dsa_wv;
    qs.p[6] = dca_wq; qs.p[7] = dca_wk; qs.p[8] = dca_wv;
    tcvt_qkv_k<<<dim3(1, 8, 288), blk, 0, stream>>>(qs, wqkv_t);
    Ptr3 pw;
    pw.p[0] = e_wo; pw.p[1] = dsa_wo; pw.p[2] = dca_wo;
    tcvt_b_k<<<dim3(8, 8, 12), blk, 0, stream>>>(pw, wo_t, Cdim, Cdim, 4, (long)Cdim * Cdim);
    pw.p[0] = e_w1; pw.p[1] = d_w1; pw.p[2] = nullptr;
    tcvt_b_k<<<dim3(32, 8, 8), blk, 0, stream>>>(pw, w1_t, Cdim, FF, 4, (long)Cdim * FF);
    pw.p[0] = e_w2; pw.p[1] = d_w2; pw.p[2] = nullptr;
    tcvt_b_k<<<dim3(8, 32, 8), blk, 0, stream>>>(pw, w2_t, FF, Cdim, 4, (long)FF * Cdim);
    pw.p[0] = out_w; pw.p[1] = nullptr; pw.p[2] = nullptr;
    tcvt_b_k<<<dim3(500, 8, 1), blk, 0, stream>>>(pw, outw_t, Cdim, Vn, 1, 0);

    // ================= embeddings + first LNs (one launch; dec LN -> hk) =================
    embed2_ln_k<<<2 * NTOK / 4, blk, 0, stream>>>(enc_inp, dec_inp, tok_emb, pos_emb,
        e_ln1_g, e_ln1_b, d_ln1_g, d_ln1_b, x_enc, x_dec, h, hk);

    // ================= encoder =================
    for (int l = 0; l < Ld; l++) {
        if (l) ln_k<<<NTOK / 4, blk, 0, stream>>>(x_enc, e_ln1_g + l * Cdim, e_ln1_b + l * Cdim, h);
        run_attn(stream, h, h,
                 wqkv_t + (long)l * LQKV, e_bo + l * Cdim, wo_t + (long)l * Cdim * Cdim,
                 x_enc, enc_mask, /*causal=*/false, qkv, vt, ao);
        ln_k<<<NTOK / 4, blk, 0, stream>>>(x_enc, e_ln2_g + l * Cdim, e_ln2_b + l * Cdim, h);
        mgemm_k<128,128,64,4,true,true,false,true,false,16,false,true><<<dim3(16, 16, 1), blk, 0, stream>>>(
            h, h, 1 << 30, w1_t + (long)l * Cdim * FF, e_b1 + l * FF, nullptr, mid,
            nullptr, nullptr, 1 << 30, Cdim, Cdim, Cdim, FF);
        mgemm_k<64,64,64,4,true,false,true,false,false,32,false,true><<<dim3(8, 32, 1), blk, 0, stream>>>(
            mid, mid, 1 << 30, w2_t + (long)l * FF * Cdim, e_b2 + l * Cdim, x_enc, x_enc,
            nullptr, nullptr, 1 << 30, FF, FF, FF, Cdim);
    }
    // x_enc now holds enc_out

    // ================= decoder =================
    for (int l = 0; l < Ld; l++) {
        // causal self-attention (layer 0 reads hk written by embed2_ln)
        const bf16_t* hs = (l == 0) ? hk : h;
        if (l) ln_k<<<NTOK / 4, blk, 0, stream>>>(x_dec, d_ln1_g + l * Cdim, d_ln1_b + l * Cdim, h);
        run_attn(stream, hs, hs,
                 wqkv_t + (long)(Ld + l) * LQKV, dsa_bo + l * Cdim,
                 wo_t + (long)(Ld + l) * Cdim * Cdim,
                 x_dec, nullptr, /*causal=*/true, qkv, vt, ao);
        // cross-attention (same LN applied to x and enc_out) — one fused launch
        ln2_k<<<2 * NTOK / 4, blk, 0, stream>>>(x_dec, x_enc,
            d_ln2_g + l * Cdim, d_ln2_b + l * Cdim, h, hk);
        run_attn(stream, h, hk,
                 wqkv_t + (long)(2 * Ld + l) * LQKV, dca_bo + l * Cdim,
                 wo_t + (long)(2 * Ld + l) * Cdim * Cdim,
                 x_dec, enc_mask, /*causal=*/false, qkv, vt, ao);
        // FFN
        ln_k<<<NTOK / 4, blk, 0, stream>>>(x_dec, d_ln3_g + l * Cdim, d_ln3_b + l * Cdim, h);
        mgemm_k<128,128,64,4,true,true,false,true,false,16,false,true><<<dim3(16, 16, 1), blk, 0, stream>>>(
            h, h, 1 << 30, w1_t + (long)(Ld + l) * Cdim * FF, d_b1 + l * FF, nullptr, mid,
            nullptr, nullptr, 1 << 30, Cdim, Cdim, Cdim, FF);
        if (l < Ld - 1)
            mgemm_k<64,64,64,4,true,false,true,false,false,32,false,true><<<dim3(8, 32, 1), blk, 0, stream>>>(
                mid, mid, 1 << 30, w2_t + (long)(Ld + l) * FF * Cdim, d_b2 + l * Cdim, x_dec, x_dec,
                nullptr, nullptr, 1 << 30, FF, FF, FF, Cdim);
        else  // last layer: also emit bf16 copy for logits GEMM
            mgemm_k<64,64,64,4,true,false,true,false,false,32,true,true><<<dim3(8, 32, 1), blk, 0, stream>>>(
                mid, mid, 1 << 30, w2_t + (long)(Ld + l) * FF * Cdim, d_b2 + l * Cdim, x_dec, x_dec,
                xdb, nullptr, 1 << 30, FF, FF, FF, Cdim);
    }

    // ================= final logits (f32 out, 256x256 tile, 8 waves, XCD-swizzled) ==========
    mgemm_k<256,256,64,8,true,false,false,false,false,8,false,true><<<dim3(125, 8, 1), dim3(512), 0, stream>>>(
        xdb, xdb, 1 << 30, outw_t, out_b, nullptr, out, nullptr, nullptr, 1 << 30,
        Cdim, Cdim, Cdim, Vn);
}